// Round 4
// baseline (795.490 us; speedup 1.0000x reference)
//
#include <hip/hip_runtime.h>

#define N_NODES 40000
#define M_EDGES 10000
#define NNZ_CNT 400000
#define FT_DIM  128
#define HID     256
#define NCLS    10
#define NG      128
#define EPSV    1e-5f

typedef short s8v __attribute__((ext_vector_type(8)));
typedef float f4v __attribute__((ext_vector_type(4)));
typedef unsigned short u2v __attribute__((ext_vector_type(2)));
typedef unsigned short u4v __attribute__((ext_vector_type(4)));

__device__ __forceinline__ unsigned short f2bf(float x) {
    unsigned int u = __float_as_uint(x);
    u += 0x7fffu + ((u >> 16) & 1u);
    return (unsigned short)(u >> 16);
}
__device__ __forceinline__ float bf2f(unsigned short h) {
    return __uint_as_float(((unsigned int)h) << 16);
}

// ---------------- utility ----------------
__global__ void fzero(float* __restrict__ p, int n) {
    int i = blockIdx.x * 256 + threadIdx.x;
    if (i < n) p[i] = 0.f;
}

// ---------------- CSR build ----------------
__global__ void count_kernel(const int* __restrict__ ni, const int* __restrict__ ei,
                             int* __restrict__ cnt_e, int* __restrict__ cnt_n) {
    int i = blockIdx.x * 256 + threadIdx.x;
    if (i < NNZ_CNT) {
        atomicAdd(&cnt_e[ei[i]], 1);
        atomicAdd(&cnt_n[ni[i]], 1);
    }
}

__global__ __launch_bounds__(1024) void exscan_kernel(const int* __restrict__ in,
                                                      int* __restrict__ out, int n) {
    __shared__ int wsum[16];
    __shared__ int carry_s;
    int tid = threadIdx.x, lane = tid & 63, w = tid >> 6;
    if (tid == 0) carry_s = 0;
    __syncthreads();
    for (int base = 0; base < n; base += 4096) {
        int i0 = base + tid * 4;
        int v[4];
#pragma unroll
        for (int t = 0; t < 4; ++t) v[t] = (i0 + t < n) ? in[i0 + t] : 0;
        int s = v[0] + v[1] + v[2] + v[3];
        int sc = s;
#pragma unroll
        for (int d = 1; d < 64; d <<= 1) {
            int t = __shfl_up(sc, d, 64);
            if (lane >= d) sc += t;
        }
        if (lane == 63) wsum[w] = sc;
        __syncthreads();
        if (tid < 64) {
            int ws = (lane < 16) ? wsum[lane] : 0;
            int wsc = ws;
#pragma unroll
            for (int d = 1; d < 16; d <<= 1) {
                int t = __shfl_up(wsc, d, 64);
                if (lane >= d) wsc += t;
            }
            if (lane < 16) wsum[lane] = wsc - ws;
        }
        __syncthreads();
        int carry = carry_s;
        int ex = carry + wsum[w] + (sc - s);
#pragma unroll
        for (int t = 0; t < 4; ++t) {
            if (i0 + t < n) out[i0 + t] = ex;
            ex += v[t];
        }
        __syncthreads();
        if (tid == 1023) carry_s = ex;
    }
    __syncthreads();
    if (tid == 0) out[n] = carry_s;
}

__global__ void fill_kernel(const int* __restrict__ ni, const int* __restrict__ ei,
                            const int* __restrict__ off_e, const int* __restrict__ off_n,
                            int* __restrict__ cur_e, int* __restrict__ cur_n,
                            int* __restrict__ idx_e, int* __restrict__ idx_n) {
    int i = blockIdx.x * 256 + threadIdx.x;
    if (i < NNZ_CNT) {
        int e = ei[i], n = ni[i];
        int pe = atomicAdd(&cur_e[e], 1);
        idx_e[off_e[e] + pe] = n;
        int pn = atomicAdd(&cur_n[n], 1);
        idx_n[off_n[n] + pn] = e;
    }
}

__global__ void dinv_kernel(const int* __restrict__ off_n, const int* __restrict__ idx_n,
                            const int* __restrict__ cnt_e, float* __restrict__ dinv) {
    int n = blockIdx.x * 256 + threadIdx.x;
    if (n < N_NODES) {
        int s = off_n[n], e = off_n[n + 1];
        float p = 0.f;
        for (int j = s; j < e; ++j) p += (float)cnt_e[idx_n[j]];
        dinv[n] = (p > 0.f) ? 1.0f / p : 1.0f;
    }
}

// ---------------- weight prep: W[K x 256] fp32 -> planes [256 cols][K] bf16 hi/lo ----------------
__global__ void wprep(const float* __restrict__ W, unsigned short* __restrict__ bh,
                      unsigned short* __restrict__ bl, int K) {
    int i = blockIdx.x * 256 + threadIdx.x;
    if (i < K * 256) {
        int k = i >> 8, c = i & 255;
        float x = W[i];
        unsigned short h = f2bf(x);
        bh[c * K + k] = h;
        bl[c * K + k] = f2bf(x - bf2f(h));
    }
}

// ---------------- fp32 -> bf16 plane (round only) ----------------
__global__ void fsplit(const float4* __restrict__ src, u4v* __restrict__ h, int n4) {
    int i = blockIdx.x * 256 + threadIdx.x;
    if (i < n4) {
        float4 v = src[i];
        h[i] = (u4v){f2bf(v.x), f2bf(v.y), f2bf(v.z), f2bf(v.w)};
    }
}

// ---------------- relu(bn(x)) -> bf16 plane(s) ----------------
template<bool DUAL>
__global__ __launch_bounds__(256) void bn_split(const float4* __restrict__ src,
        const float* __restrict__ a, const float* __restrict__ c,
        u4v* __restrict__ hOut, u4v* __restrict__ lOut, int n4) {
    int i = blockIdx.x * 256 + threadIdx.x;
    if (i >= n4) return;
    int col = (i << 2) & (HID - 1);
    float4 av = *(const float4*)(a + col);
    float4 cv = *(const float4*)(c + col);
    float4 v = src[i];
    float x0 = fmaxf(fmaf(av.x, v.x, cv.x), 0.f);
    float x1 = fmaxf(fmaf(av.y, v.y, cv.y), 0.f);
    float x2 = fmaxf(fmaf(av.z, v.z, cv.z), 0.f);
    float x3 = fmaxf(fmaf(av.w, v.w, cv.w), 0.f);
    u4v h = (u4v){f2bf(x0), f2bf(x1), f2bf(x2), f2bf(x3)};
    hOut[i] = h;
    if (DUAL) {
        lOut[i] = (u4v){f2bf(x0 - bf2f(h[0])), f2bf(x1 - bf2f(h[1])),
                        f2bf(x2 - bf2f(h[2])), f2bf(x3 - bf2f(h[3]))};
    }
}

// ---------------- gathers over bf16 source, fp32 accumulation ----------------
template<int VEC> struct SV;
template<> struct SV<2> { typedef u2v T; };
template<> struct SV<4> { typedef u4v T; };

template<int VEC, bool PLANES>
__global__ __launch_bounds__(256) void gather_pool(const int* __restrict__ off,
        const int* __restrict__ idx, const unsigned short* __restrict__ Y,
        unsigned short* __restrict__ outh, unsigned short* __restrict__ outl) {
    typedef typename SV<VEC>::T VT;
    const int D = VEC * 64;
    int lane = threadIdx.x & 63;
    int r = blockIdx.x * 4 + (threadIdx.x >> 6);
    int f0 = lane * VEC;
    int s = off[r], e = off[r + 1];
    float acc0[VEC] = {}, acc1[VEC] = {}, acc2[VEC] = {}, acc3[VEC] = {};
    int j = s;
    for (; j + 4 <= e; j += 4) {
        int i0 = __builtin_amdgcn_readfirstlane(idx[j]);
        int i1 = __builtin_amdgcn_readfirstlane(idx[j + 1]);
        int i2 = __builtin_amdgcn_readfirstlane(idx[j + 2]);
        int i3 = __builtin_amdgcn_readfirstlane(idx[j + 3]);
        VT g0 = *(const VT*)(Y + (long)i0 * D + f0);
        VT g1 = *(const VT*)(Y + (long)i1 * D + f0);
        VT g2 = *(const VT*)(Y + (long)i2 * D + f0);
        VT g3 = *(const VT*)(Y + (long)i3 * D + f0);
#pragma unroll
        for (int v = 0; v < VEC; ++v) {
            acc0[v] += bf2f(g0[v]); acc1[v] += bf2f(g1[v]);
            acc2[v] += bf2f(g2[v]); acc3[v] += bf2f(g3[v]);
        }
    }
    for (; j < e; ++j) {
        int i0 = __builtin_amdgcn_readfirstlane(idx[j]);
        VT g0 = *(const VT*)(Y + (long)i0 * D + f0);
#pragma unroll
        for (int v = 0; v < VEC; ++v) acc0[v] += bf2f(g0[v]);
    }
    VT h, l;
#pragma unroll
    for (int v = 0; v < VEC; ++v) {
        float sum = acc0[v] + acc1[v] + acc2[v] + acc3[v];
        unsigned short hh = f2bf(sum);
        h[v] = hh;
        if (PLANES) l[v] = f2bf(sum - bf2f(hh));
    }
    *(VT*)(outh + (long)r * D + f0) = h;
    if (PLANES) *(VT*)(outl + (long)r * D + f0) = l;
}

template<bool WRITE_P>
__global__ __launch_bounds__(256) void gather_head(const int* __restrict__ off,
        const int* __restrict__ idx, const unsigned short* __restrict__ Y,
        const float* __restrict__ dinv, const float* __restrict__ Wh,
        const float* __restrict__ hb, float* __restrict__ on,
        unsigned short* __restrict__ Ph, unsigned short* __restrict__ Pl) {
    int lane = threadIdx.x & 63;
    int r = blockIdx.x * 4 + (threadIdx.x >> 6);
    int f0 = lane * 4;
    int s = off[r], e = off[r + 1];
    float acc0[4] = {}, acc1[4] = {}, acc2[4] = {}, acc3[4] = {};
    int j = s;
    for (; j + 4 <= e; j += 4) {
        int i0 = __builtin_amdgcn_readfirstlane(idx[j]);
        int i1 = __builtin_amdgcn_readfirstlane(idx[j + 1]);
        int i2 = __builtin_amdgcn_readfirstlane(idx[j + 2]);
        int i3 = __builtin_amdgcn_readfirstlane(idx[j + 3]);
        u4v g0 = *(const u4v*)(Y + (long)i0 * 256 + f0);
        u4v g1 = *(const u4v*)(Y + (long)i1 * 256 + f0);
        u4v g2 = *(const u4v*)(Y + (long)i2 * 256 + f0);
        u4v g3 = *(const u4v*)(Y + (long)i3 * 256 + f0);
#pragma unroll
        for (int v = 0; v < 4; ++v) {
            acc0[v] += bf2f(g0[v]); acc1[v] += bf2f(g1[v]);
            acc2[v] += bf2f(g2[v]); acc3[v] += bf2f(g3[v]);
        }
    }
    for (; j < e; ++j) {
        int i0 = __builtin_amdgcn_readfirstlane(idx[j]);
        u4v g0 = *(const u4v*)(Y + (long)i0 * 256 + f0);
#pragma unroll
        for (int v = 0; v < 4; ++v) acc0[v] += bf2f(g0[v]);
    }
    float sum[4];
#pragma unroll
    for (int v = 0; v < 4; ++v) sum[v] = acc0[v] + acc1[v] + acc2[v] + acc3[v];
    if (WRITE_P) {
        u4v h, l;
#pragma unroll
        for (int v = 0; v < 4; ++v) {
            unsigned short hh = f2bf(sum[v]);
            h[v] = hh;
            l[v] = f2bf(sum[v] - bf2f(hh));
        }
        *(u4v*)(Ph + (long)r * 256 + f0) = h;
        *(u4v*)(Pl + (long)r * 256 + f0) = l;
    }
    float di = dinv[r];
    const float* wp = Wh + (long)f0 * NCLS;
    float p[NCLS];
#pragma unroll
    for (int c = 0; c < NCLS; ++c)
        p[c] = di * (sum[0] * wp[c] + sum[1] * wp[NCLS + c] + sum[2] * wp[2 * NCLS + c]
                   + sum[3] * wp[3 * NCLS + c]);
#pragma unroll
    for (int c = 0; c < NCLS; ++c) {
#pragma unroll
        for (int m = 1; m < 64; m <<= 1) p[c] += __shfl_xor(p[c], m, 64);
    }
    if (lane == 0) {
        if (WRITE_P) {
#pragma unroll
            for (int c = 0; c < NCLS; ++c) on[(long)r * NCLS + c] = p[c] + hb[c];
        } else {
#pragma unroll
            for (int c = 0; c < NCLS; ++c) on[(long)r * NCLS + c] += p[c];
        }
    }
}

// ---------------- split-bf16 MFMA GEMM, DIRECT global fragments (no LDS, no barriers) ----
// C[40000 x 256] = (Ah+Al)[40000 x K] @ (Bh+Bl)[K x 256] + bias.
// A planes row-major [row][K]; B planes [col][K]. Fragment loads are 64B-contiguous
// per row/col per wave (lanes lq=0..3 cover k0..k0+31 shorts), so global loads coalesce
// at 64B granularity; B (<=256KB) is L2-resident across the 625 blocks.
// Tile 64x128, 4 waves: wave w -> rows (w&1)*32, cols (w>>1)*64. Fused column stats.
template<int K>
__global__ __launch_bounds__(256) void gemm_direct(const unsigned short* __restrict__ Ahg,
        const unsigned short* __restrict__ Alg, const unsigned short* __restrict__ Bhg,
        const unsigned short* __restrict__ Blg, const float* __restrict__ bias,
        float* __restrict__ C, float* __restrict__ stats) {
    __shared__ float lsum[128], lsq[128];
    int tid = threadIdx.x;
    int lane = tid & 63, w = tid >> 6;
    long row0 = (long)blockIdx.x * 64;
    int col0 = blockIdx.y * 128;
    int lm = lane & 15, lq = lane >> 4;
    int rw = (w & 1) * 32, cw = (w >> 1) * 64;
    const unsigned short* ah0 = Ahg + (row0 + rw + lm) * (long)K + lq * 8;
    const unsigned short* al0 = Alg + (row0 + rw + lm) * (long)K + lq * 8;
    const unsigned short* bh0 = Bhg + (long)(col0 + cw + lm) * K + lq * 8;
    const unsigned short* bl0 = Blg + (long)(col0 + cw + lm) * K + lq * 8;
    f4v acc[2][4];
#pragma unroll
    for (int i = 0; i < 2; ++i)
#pragma unroll
        for (int j = 0; j < 4; ++j) acc[i][j] = (f4v){0.f, 0.f, 0.f, 0.f};
    if (tid < 128) { lsum[tid] = 0.f; lsq[tid] = 0.f; }

#pragma unroll 2
    for (int k0 = 0; k0 < K; k0 += 32) {
        s8v ah[2], al[2], bh[4], bl[4];
#pragma unroll
        for (int i = 0; i < 2; ++i) {
            ah[i] = *(const s8v*)(ah0 + k0 + i * 16 * K);
            al[i] = *(const s8v*)(al0 + k0 + i * 16 * K);
        }
#pragma unroll
        for (int j = 0; j < 4; ++j) {
            bh[j] = *(const s8v*)(bh0 + k0 + j * 16 * K);
            bl[j] = *(const s8v*)(bl0 + k0 + j * 16 * K);
        }
#pragma unroll
        for (int i = 0; i < 2; ++i)
#pragma unroll
            for (int j = 0; j < 4; ++j) {
                acc[i][j] = __builtin_amdgcn_mfma_f32_16x16x32_bf16(al[i], bh[j], acc[i][j], 0, 0, 0);
                acc[i][j] = __builtin_amdgcn_mfma_f32_16x16x32_bf16(ah[i], bl[j], acc[i][j], 0, 0, 0);
                acc[i][j] = __builtin_amdgcn_mfma_f32_16x16x32_bf16(ah[i], bh[j], acc[i][j], 0, 0, 0);
            }
    }
    __syncthreads();   // lsum/lsq init visible
#pragma unroll
    for (int j = 0; j < 4; ++j) {
        int lc = cw + j * 16 + lm;
        int col = col0 + lc;
        float bsv = bias[col];
        float s = 0.f, sq = 0.f;
#pragma unroll
        for (int i = 0; i < 2; ++i) {
#pragma unroll
            for (int reg = 0; reg < 4; ++reg) {
                long row = row0 + rw + i * 16 + lq * 4 + reg;
                float v = acc[i][j][reg] + bsv;
                C[row * HID + col] = v;
                s += v;
                sq += v * v;
            }
        }
        atomicAdd(&lsum[lc], s);
        atomicAdd(&lsq[lc], sq);
    }
    __syncthreads();
    if (tid < 128) {
        atomicAdd(&stats[col0 + tid], lsum[tid]);
        atomicAdd(&stats[HID + col0 + tid], lsq[tid]);
    }
}

__global__ void bn_finalize(const float* __restrict__ stats, const float* __restrict__ g,
                            const float* __restrict__ be, float rows_inv,
                            float* __restrict__ a, float* __restrict__ c) {
    int f = threadIdx.x;
    float mean = stats[f] * rows_inv;
    float var = stats[HID + f] * rows_inv - mean * mean;
    float av = g[f] * rsqrtf(var + EPSV);
    a[f] = av;
    c[f] = be[f] - mean * av;
}

// ---------------- readout ----------------
__global__ __launch_bounds__(256) void readout_accum(const float* __restrict__ on,
                                                     const int* __restrict__ ab,
                                                     float* __restrict__ racc,
                                                     float* __restrict__ rcnt) {
    __shared__ float lacc[NG * NCLS];
    __shared__ float lcnt[NG];
    int tid = threadIdx.x;
    for (int i = tid; i < NG * NCLS; i += 256) lacc[i] = 0.f;
    if (tid < NG) lcnt[tid] = 0.f;
    __syncthreads();
    int n = blockIdx.x * 256 + tid;
    if (n < N_NODES) {
        int b = ab[n];
        atomicAdd(&lcnt[b], 1.0f);
        for (int c = 0; c < NCLS; ++c) atomicAdd(&lacc[b * NCLS + c], on[(long)n * NCLS + c]);
    }
    __syncthreads();
    if (tid < NG && lcnt[tid] > 0.f) {
        atomicAdd(&rcnt[tid], lcnt[tid]);
        for (int c = 0; c < NCLS; ++c) atomicAdd(&racc[tid * NCLS + c], lacc[tid * NCLS + c]);
    }
}

__global__ void readout_final(const float* __restrict__ racc, const float* __restrict__ rcnt,
                              float* __restrict__ out) {
    int i = blockIdx.x * 256 + threadIdx.x;
    if (i < NG * NCLS) out[i] = racc[i] / fmaxf(rcnt[i / NCLS], 1.0f);
}

// ---------------- launch ----------------
extern "C" void kernel_launch(void* const* d_in, const int* in_sizes, int n_in,
                              void* d_out, int out_size, void* d_ws, size_t ws_size,
                              hipStream_t stream) {
    const float* X         = (const float*)d_in[0];
    const int*   node_idx  = (const int*)d_in[1];
    const int*   edge_idx  = (const int*)d_in[2];
    const int*   all_batch = (const int*)d_in[3];
    const float* W1[2]  = {(const float*)d_in[4],  (const float*)d_in[12]};
    const float* b1[2]  = {(const float*)d_in[5],  (const float*)d_in[13]};
    const float* g1[2]  = {(const float*)d_in[6],  (const float*)d_in[14]};
    const float* be1[2] = {(const float*)d_in[7],  (const float*)d_in[15]};
    const float* W2[2]  = {(const float*)d_in[8],  (const float*)d_in[16]};
    const float* b2[2]  = {(const float*)d_in[9],  (const float*)d_in[17]};
    const float* bng[2] = {(const float*)d_in[10], (const float*)d_in[18]};
    const float* bnb[2] = {(const float*)d_in[11], (const float*)d_in[19]};
    const float* headW  = (const float*)d_in[20];
    const float* headb  = (const float*)d_in[21];
    float* out = (float*)d_out;

    char* base = (char*)d_ws;
    size_t off = 0;
    auto alloc = [&](size_t bytes) -> void* {
        size_t o = (off + 255) & ~(size_t)255;
        off = o + bytes;
        return (void*)(base + o);
    };

    const int ZINTS = 2 * M_EDGES + 2 * N_NODES;
    const int ZTOT  = ZINTS + 4 * 2 * HID + NG * NCLS + NG;
    int* ibase  = (int*)alloc((size_t)ZTOT * 4);
    int* cnt_e  = ibase;
    int* cnt_n  = cnt_e + M_EDGES;
    int* cur_e  = cnt_n + N_NODES;
    int* cur_n  = cur_e + M_EDGES;
    float* statsall = (float*)(ibase + ZINTS);
    float* racc     = statsall + 4 * 2 * HID;
    float* rcnt     = racc + NG * NCLS;

    int* off_e  = (int*)alloc((M_EDGES + 1) * 4);
    int* off_n  = (int*)alloc((N_NODES + 1) * 4);
    int* idx_e  = (int*)alloc((size_t)NNZ_CNT * 4);
    int* idx_n  = (int*)alloc((size_t)NNZ_CNT * 4);
    float* dinv = (float*)alloc((size_t)N_NODES * 4);

    unsigned short* Xb = (unsigned short*)alloc((size_t)N_NODES * FT_DIM * 2);
    unsigned short* Eb = (unsigned short*)alloc((size_t)M_EDGES * HID * 2);
    unsigned short* Ph = (unsigned short*)alloc((size_t)N_NODES * HID * 2);
    unsigned short* Pl = (unsigned short*)alloc((size_t)N_NODES * HID * 2);
    unsigned short* Ahp = (unsigned short*)alloc((size_t)N_NODES * HID * 2);
    unsigned short* Alp = (unsigned short*)alloc((size_t)N_NODES * HID * 2);
    unsigned short* Hb  = (unsigned short*)alloc((size_t)N_NODES * HID * 2);
    float* T      = (float*)alloc((size_t)N_NODES * HID * 4);
    float* onodes = (float*)alloc((size_t)N_NODES * NCLS * 4);
    unsigned short* Wp[4][2];
    int WK[4] = {FT_DIM, HID, HID, HID};
    for (int m = 0; m < 4; ++m) {
        Wp[m][0] = (unsigned short*)alloc((size_t)WK[m] * HID * 2);
        Wp[m][1] = (unsigned short*)alloc((size_t)WK[m] * HID * 2);
    }
    float* bnA = (float*)alloc(4 * HID * 4);
    float* bnC = (float*)alloc(4 * HID * 4);

    const int nnz_blocks = (NNZ_CNT + 255) / 256;
    const float rows_inv = 1.0f / (float)N_NODES;
    const int n4 = N_NODES * HID / 4;
    const dim3 ggrid(N_NODES / 64, 2);

    // --- CSR build + degree norm + weight prep ---
    fzero<<<(ZTOT + 255) / 256, 256, 0, stream>>>((float*)ibase, ZTOT);
    count_kernel<<<nnz_blocks, 256, 0, stream>>>(node_idx, edge_idx, cnt_e, cnt_n);
    exscan_kernel<<<1, 1024, 0, stream>>>(cnt_e, off_e, M_EDGES);
    exscan_kernel<<<1, 1024, 0, stream>>>(cnt_n, off_n, N_NODES);
    fill_kernel<<<nnz_blocks, 256, 0, stream>>>(node_idx, edge_idx, off_e, off_n,
                                                cur_e, cur_n, idx_e, idx_n);
    dinv_kernel<<<(N_NODES + 255) / 256, 256, 0, stream>>>(off_n, idx_n, cnt_e, dinv);
    wprep<<<(FT_DIM * HID + 255) / 256, 256, 0, stream>>>(W1[0], Wp[0][0], Wp[0][1], FT_DIM);
    wprep<<<(HID * HID + 255) / 256, 256, 0, stream>>>(W2[0], Wp[1][0], Wp[1][1], HID);
    wprep<<<(HID * HID + 255) / 256, 256, 0, stream>>>(W1[1], Wp[2][0], Wp[2][1], HID);
    wprep<<<(HID * HID + 255) / 256, 256, 0, stream>>>(W2[1], Wp[3][0], Wp[3][1], HID);
    fsplit<<<(N_NODES * FT_DIM / 4 + 255) / 256, 256, 0, stream>>>((const float4*)X,
                                                                   (u4v*)Xb, N_NODES * FT_DIM / 4);

    // ---------------- layer 0 ----------------
    gather_pool<2, false><<<M_EDGES / 4, 256, 0, stream>>>(off_e, idx_e, Xb, Eb, nullptr);
    gather_pool<2, true><<<N_NODES / 4, 256, 0, stream>>>(off_n, idx_n, Eb, Ph, Pl);
    gemm_direct<FT_DIM><<<ggrid, 256, 0, stream>>>(Ph, Pl, Wp[0][0], Wp[0][1], b1[0], T,
                                                   statsall + 0 * 512);
    bn_finalize<<<1, 256, 0, stream>>>(statsall + 0 * 512, g1[0], be1[0], rows_inv,
                                       bnA + 0 * HID, bnC + 0 * HID);
    bn_split<true><<<(n4 + 255) / 256, 256, 0, stream>>>((const float4*)T, bnA + 0 * HID,
                                                         bnC + 0 * HID, (u4v*)Ahp, (u4v*)Alp, n4);
    gemm_direct<HID><<<ggrid, 256, 0, stream>>>(Ahp, Alp, Wp[1][0], Wp[1][1], b2[0], T,
                                                statsall + 1 * 512);
    bn_finalize<<<1, 256, 0, stream>>>(statsall + 1 * 512, bng[0], bnb[0], rows_inv,
                                       bnA + 1 * HID, bnC + 1 * HID);
    bn_split<false><<<(n4 + 255) / 256, 256, 0, stream>>>((const float4*)T, bnA + 1 * HID,
                                                          bnC + 1 * HID, (u4v*)Hb, nullptr, n4);
    // shared edge pass (layer-0 readout AND layer-1 pooling)
    gather_pool<4, false><<<M_EDGES / 4, 256, 0, stream>>>(off_e, idx_e, Hb, Eb, nullptr);
    gather_head<true><<<N_NODES / 4, 256, 0, stream>>>(off_n, idx_n, Eb, dinv, headW, headb,
                                                       onodes, Ph, Pl);

    // ---------------- layer 1 ----------------
    gemm_direct<HID><<<ggrid, 256, 0, stream>>>(Ph, Pl, Wp[2][0], Wp[2][1], b1[1], T,
                                                statsall + 2 * 512);
    bn_finalize<<<1, 256, 0, stream>>>(statsall + 2 * 512, g1[1], be1[1], rows_inv,
                                       bnA + 2 * HID, bnC + 2 * HID);
    bn_split<true><<<(n4 + 255) / 256, 256, 0, stream>>>((const float4*)T, bnA + 2 * HID,
                                                         bnC + 2 * HID, (u4v*)Ahp, (u4v*)Alp, n4);
    gemm_direct<HID><<<ggrid, 256, 0, stream>>>(Ahp, Alp, Wp[3][0], Wp[3][1], b2[1], T,
                                                statsall + 3 * 512);
    bn_finalize<<<1, 256, 0, stream>>>(statsall + 3 * 512, bng[1], bnb[1], rows_inv,
                                       bnA + 3 * HID, bnC + 3 * HID);
    bn_split<false><<<(n4 + 255) / 256, 256, 0, stream>>>((const float4*)T, bnA + 3 * HID,
                                                          bnC + 3 * HID, (u4v*)Hb, nullptr, n4);
    gather_pool<4, false><<<M_EDGES / 4, 256, 0, stream>>>(off_e, idx_e, Hb, Eb, nullptr);
    gather_head<false><<<N_NODES / 4, 256, 0, stream>>>(off_n, idx_n, Eb, dinv,
                                                        headW + (size_t)HID * NCLS, headb,
                                                        onodes, nullptr, nullptr);

    // ---------------- readout ----------------
    readout_accum<<<(N_NODES + 255) / 256, 256, 0, stream>>>(onodes, all_batch, racc, rcnt);
    readout_final<<<(NG * NCLS + 255) / 256, 256, 0, stream>>>(racc, rcnt, out);
}

// Round 5
// 733.548 us; speedup vs baseline: 1.0844x; 1.0844x over previous
//
#include <hip/hip_runtime.h>

#define N_NODES 40000
#define M_EDGES 10000
#define NNZ_CNT 400000
#define FT_DIM  128
#define HID     256
#define NCLS    10
#define NG      128
#define EPSV    1e-5f

typedef short s8v __attribute__((ext_vector_type(8)));
typedef float f4v __attribute__((ext_vector_type(4)));
typedef unsigned short u2v __attribute__((ext_vector_type(2)));
typedef unsigned short u4v __attribute__((ext_vector_type(4)));

__device__ __forceinline__ unsigned short f2bf(float x) {
    unsigned int u = __float_as_uint(x);
    u += 0x7fffu + ((u >> 16) & 1u);
    return (unsigned short)(u >> 16);
}
__device__ __forceinline__ float bf2f(unsigned short h) {
    return __uint_as_float(((unsigned int)h) << 16);
}

// blocked-chunk address (in shorts) for element (r, k) of an A-activation plane
// layout: [r/64][k/8][r%64] 16B chunks
__device__ __forceinline__ long ablk(int r, int k, int K) {
    return ((long)((r >> 6) * (K >> 3) + (k >> 3)) * 64 + (r & 63)) * 8 + (k & 7);
}

// ---------------- utility ----------------
__global__ void fzero(float* __restrict__ p, int n) {
    int i = blockIdx.x * 256 + threadIdx.x;
    if (i < n) p[i] = 0.f;
}

// ---------------- CSR build ----------------
__global__ void count_kernel(const int* __restrict__ ni, const int* __restrict__ ei,
                             int* __restrict__ cnt_e, int* __restrict__ cnt_n) {
    int i = blockIdx.x * 256 + threadIdx.x;
    if (i < NNZ_CNT) {
        atomicAdd(&cnt_e[ei[i]], 1);
        atomicAdd(&cnt_n[ni[i]], 1);
    }
}

__global__ __launch_bounds__(1024) void exscan_kernel(const int* __restrict__ in,
                                                      int* __restrict__ out, int n) {
    __shared__ int wsum[16];
    __shared__ int carry_s;
    int tid = threadIdx.x, lane = tid & 63, w = tid >> 6;
    if (tid == 0) carry_s = 0;
    __syncthreads();
    for (int base = 0; base < n; base += 4096) {
        int i0 = base + tid * 4;
        int v[4];
#pragma unroll
        for (int t = 0; t < 4; ++t) v[t] = (i0 + t < n) ? in[i0 + t] : 0;
        int s = v[0] + v[1] + v[2] + v[3];
        int sc = s;
#pragma unroll
        for (int d = 1; d < 64; d <<= 1) {
            int t = __shfl_up(sc, d, 64);
            if (lane >= d) sc += t;
        }
        if (lane == 63) wsum[w] = sc;
        __syncthreads();
        if (tid < 64) {
            int ws = (lane < 16) ? wsum[lane] : 0;
            int wsc = ws;
#pragma unroll
            for (int d = 1; d < 16; d <<= 1) {
                int t = __shfl_up(wsc, d, 64);
                if (lane >= d) wsc += t;
            }
            if (lane < 16) wsum[lane] = wsc - ws;
        }
        __syncthreads();
        int carry = carry_s;
        int ex = carry + wsum[w] + (sc - s);
#pragma unroll
        for (int t = 0; t < 4; ++t) {
            if (i0 + t < n) out[i0 + t] = ex;
            ex += v[t];
        }
        __syncthreads();
        if (tid == 1023) carry_s = ex;
    }
    __syncthreads();
    if (tid == 0) out[n] = carry_s;
}

__global__ void fill_kernel(const int* __restrict__ ni, const int* __restrict__ ei,
                            const int* __restrict__ off_e, const int* __restrict__ off_n,
                            int* __restrict__ cur_e, int* __restrict__ cur_n,
                            int* __restrict__ idx_e, int* __restrict__ idx_n) {
    int i = blockIdx.x * 256 + threadIdx.x;
    if (i < NNZ_CNT) {
        int e = ei[i], n = ni[i];
        int pe = atomicAdd(&cur_e[e], 1);
        idx_e[off_e[e] + pe] = n;
        int pn = atomicAdd(&cur_n[n], 1);
        idx_n[off_n[n] + pn] = e;
    }
}

__global__ void dinv_kernel(const int* __restrict__ off_n, const int* __restrict__ idx_n,
                            const int* __restrict__ cnt_e, float* __restrict__ dinv) {
    int n = blockIdx.x * 256 + threadIdx.x;
    if (n < N_NODES) {
        int s = off_n[n], e = off_n[n + 1];
        float p = 0.f;
        for (int j = s; j < e; ++j) p += (float)cnt_e[idx_n[j]];
        dinv[n] = (p > 0.f) ? 1.0f / p : 1.0f;
    }
}

// -------- weight prep: W[K x 256] fp32 -> blocked planes [col/64][k/8][col%64] hi/lo ------
__global__ void wprep(const float* __restrict__ W, unsigned short* __restrict__ bh,
                      unsigned short* __restrict__ bl, int K) {
    int i = blockIdx.x * 256 + threadIdx.x;
    if (i < K * 256) {
        int k = i >> 8, c = i & 255;
        float x = W[i];
        unsigned short h = f2bf(x);
        long o = ((long)((c >> 6) * (K >> 3) + (k >> 3)) * 64 + (c & 63)) * 8 + (k & 7);
        bh[o] = h;
        bl[o] = f2bf(x - bf2f(h));
    }
}

// ---------------- fp32 -> bf16 plane (round only, row-major) ----------------
__global__ void fsplit(const float4* __restrict__ src, u4v* __restrict__ h, int n4) {
    int i = blockIdx.x * 256 + threadIdx.x;
    if (i < n4) {
        float4 v = src[i];
        h[i] = (u4v){f2bf(v.x), f2bf(v.y), f2bf(v.z), f2bf(v.w)};
    }
}

// -------- relu(bn(x)) -> blocked hi/lo planes (GEMM A input), K=256 --------
// grid = N/64 blocks; thread (r = tid>>2, kqg = tid&3), 8 iters over kq
__global__ __launch_bounds__(256) void bn_split_blk(const float* __restrict__ src,
        const float* __restrict__ a, const float* __restrict__ c,
        unsigned short* __restrict__ hOut, unsigned short* __restrict__ lOut) {
    int tid = threadIdx.x;
    int r = tid >> 2, kqg = tid & 3;
    long row = (long)blockIdx.x * 64 + r;
    long cbase = ((long)blockIdx.x * 32) * 64 + r;   // chunk units
#pragma unroll
    for (int t = 0; t < 8; ++t) {
        int kq = kqg * 8 + t;
        const float* sp = src + row * HID + kq * 8;
        float4 v0 = *(const float4*)sp;
        float4 v1 = *(const float4*)(sp + 4);
        float4 a0 = *(const float4*)(a + kq * 8);
        float4 a1 = *(const float4*)(a + kq * 8 + 4);
        float4 c0 = *(const float4*)(c + kq * 8);
        float4 c1 = *(const float4*)(c + kq * 8 + 4);
        float x[8];
        x[0] = fmaxf(fmaf(a0.x, v0.x, c0.x), 0.f);
        x[1] = fmaxf(fmaf(a0.y, v0.y, c0.y), 0.f);
        x[2] = fmaxf(fmaf(a0.z, v0.z, c0.z), 0.f);
        x[3] = fmaxf(fmaf(a0.w, v0.w, c0.w), 0.f);
        x[4] = fmaxf(fmaf(a1.x, v1.x, c1.x), 0.f);
        x[5] = fmaxf(fmaf(a1.y, v1.y, c1.y), 0.f);
        x[6] = fmaxf(fmaf(a1.z, v1.z, c1.z), 0.f);
        x[7] = fmaxf(fmaf(a1.w, v1.w, c1.w), 0.f);
        s8v h, l;
#pragma unroll
        for (int q = 0; q < 8; ++q) {
            unsigned short hh = f2bf(x[q]);
            h[q] = (short)hh;
            l[q] = (short)f2bf(x[q] - bf2f(hh));
        }
        long o = (cbase + (long)kq * 64) * 8;
        *(s8v*)(hOut + o) = h;
        *(s8v*)(lOut + o) = l;
    }
}

// -------- relu(bn(x)) -> row-major bf16 (gather input) --------
__global__ __launch_bounds__(256) void bn_rowmajor(const float4* __restrict__ src,
        const float* __restrict__ a, const float* __restrict__ c,
        u4v* __restrict__ hOut, int n4) {
    int i = blockIdx.x * 256 + threadIdx.x;
    if (i >= n4) return;
    int col = (i << 2) & (HID - 1);
    float4 av = *(const float4*)(a + col);
    float4 cv = *(const float4*)(c + col);
    float4 v = src[i];
    float x0 = fmaxf(fmaf(av.x, v.x, cv.x), 0.f);
    float x1 = fmaxf(fmaf(av.y, v.y, cv.y), 0.f);
    float x2 = fmaxf(fmaf(av.z, v.z, cv.z), 0.f);
    float x3 = fmaxf(fmaf(av.w, v.w, cv.w), 0.f);
    hOut[i] = (u4v){f2bf(x0), f2bf(x1), f2bf(x2), f2bf(x3)};
}

// ---------------- gathers over bf16 source, fp32 accumulation ----------------
template<int VEC> struct SV;
template<> struct SV<2> { typedef u2v T; };
template<> struct SV<4> { typedef u4v T; };

// PLANES: write fp32 sum split to BLOCKED hi/lo planes (GEMM A input, K=D);
// else write row-major rounded bf16.
template<int VEC, bool PLANES>
__global__ __launch_bounds__(256) void gather_pool(const int* __restrict__ off,
        const int* __restrict__ idx, const unsigned short* __restrict__ Y,
        unsigned short* __restrict__ outh, unsigned short* __restrict__ outl) {
    typedef typename SV<VEC>::T VT;
    const int D = VEC * 64;
    int lane = threadIdx.x & 63;
    int r = blockIdx.x * 4 + (threadIdx.x >> 6);
    int f0 = lane * VEC;
    int s = off[r], e = off[r + 1];
    float acc0[VEC] = {}, acc1[VEC] = {}, acc2[VEC] = {}, acc3[VEC] = {};
    int j = s;
    for (; j + 4 <= e; j += 4) {
        int i0 = __builtin_amdgcn_readfirstlane(idx[j]);
        int i1 = __builtin_amdgcn_readfirstlane(idx[j + 1]);
        int i2 = __builtin_amdgcn_readfirstlane(idx[j + 2]);
        int i3 = __builtin_amdgcn_readfirstlane(idx[j + 3]);
        VT g0 = *(const VT*)(Y + (long)i0 * D + f0);
        VT g1 = *(const VT*)(Y + (long)i1 * D + f0);
        VT g2 = *(const VT*)(Y + (long)i2 * D + f0);
        VT g3 = *(const VT*)(Y + (long)i3 * D + f0);
#pragma unroll
        for (int v = 0; v < VEC; ++v) {
            acc0[v] += bf2f(g0[v]); acc1[v] += bf2f(g1[v]);
            acc2[v] += bf2f(g2[v]); acc3[v] += bf2f(g3[v]);
        }
    }
    for (; j < e; ++j) {
        int i0 = __builtin_amdgcn_readfirstlane(idx[j]);
        VT g0 = *(const VT*)(Y + (long)i0 * D + f0);
#pragma unroll
        for (int v = 0; v < VEC; ++v) acc0[v] += bf2f(g0[v]);
    }
    if (PLANES) {
#pragma unroll
        for (int v = 0; v < VEC; ++v) {
            float sum = acc0[v] + acc1[v] + acc2[v] + acc3[v];
            unsigned short hh = f2bf(sum);
            long o = ablk(r, f0 + v, D);
            outh[o] = hh;
            outl[o] = f2bf(sum - bf2f(hh));
        }
    } else {
        VT h;
#pragma unroll
        for (int v = 0; v < VEC; ++v) h[v] = f2bf(acc0[v] + acc1[v] + acc2[v] + acc3[v]);
        *(VT*)(outh + (long)r * D + f0) = h;
    }
}

// node-side: pooled sum (optionally -> blocked P planes, K=256) + head matmul
template<bool WRITE_P>
__global__ __launch_bounds__(256) void gather_head(const int* __restrict__ off,
        const int* __restrict__ idx, const unsigned short* __restrict__ Y,
        const float* __restrict__ dinv, const float* __restrict__ Wh,
        const float* __restrict__ hb, float* __restrict__ on,
        unsigned short* __restrict__ Ph, unsigned short* __restrict__ Pl) {
    int lane = threadIdx.x & 63;
    int r = blockIdx.x * 4 + (threadIdx.x >> 6);
    int f0 = lane * 4;
    int s = off[r], e = off[r + 1];
    float acc0[4] = {}, acc1[4] = {}, acc2[4] = {}, acc3[4] = {};
    int j = s;
    for (; j + 4 <= e; j += 4) {
        int i0 = __builtin_amdgcn_readfirstlane(idx[j]);
        int i1 = __builtin_amdgcn_readfirstlane(idx[j + 1]);
        int i2 = __builtin_amdgcn_readfirstlane(idx[j + 2]);
        int i3 = __builtin_amdgcn_readfirstlane(idx[j + 3]);
        u4v g0 = *(const u4v*)(Y + (long)i0 * 256 + f0);
        u4v g1 = *(const u4v*)(Y + (long)i1 * 256 + f0);
        u4v g2 = *(const u4v*)(Y + (long)i2 * 256 + f0);
        u4v g3 = *(const u4v*)(Y + (long)i3 * 256 + f0);
#pragma unroll
        for (int v = 0; v < 4; ++v) {
            acc0[v] += bf2f(g0[v]); acc1[v] += bf2f(g1[v]);
            acc2[v] += bf2f(g2[v]); acc3[v] += bf2f(g3[v]);
        }
    }
    for (; j < e; ++j) {
        int i0 = __builtin_amdgcn_readfirstlane(idx[j]);
        u4v g0 = *(const u4v*)(Y + (long)i0 * 256 + f0);
#pragma unroll
        for (int v = 0; v < 4; ++v) acc0[v] += bf2f(g0[v]);
    }
    float sum[4];
#pragma unroll
    for (int v = 0; v < 4; ++v) sum[v] = acc0[v] + acc1[v] + acc2[v] + acc3[v];
    if (WRITE_P) {
#pragma unroll
        for (int v = 0; v < 4; ++v) {
            unsigned short hh = f2bf(sum[v]);
            long o = ablk(r, f0 + v, HID);
            Ph[o] = hh;
            Pl[o] = f2bf(sum[v] - bf2f(hh));
        }
    }
    float di = dinv[r];
    const float* wp = Wh + (long)f0 * NCLS;
    float p[NCLS];
#pragma unroll
    for (int c = 0; c < NCLS; ++c)
        p[c] = di * (sum[0] * wp[c] + sum[1] * wp[NCLS + c] + sum[2] * wp[2 * NCLS + c]
                   + sum[3] * wp[3 * NCLS + c]);
#pragma unroll
    for (int c = 0; c < NCLS; ++c) {
#pragma unroll
        for (int m = 1; m < 64; m <<= 1) p[c] += __shfl_xor(p[c], m, 64);
    }
    if (lane == 0) {
        if (WRITE_P) {
#pragma unroll
            for (int c = 0; c < NCLS; ++c) on[(long)r * NCLS + c] = p[c] + hb[c];
        } else {
#pragma unroll
            for (int c = 0; c < NCLS; ++c) on[(long)r * NCLS + c] += p[c];
        }
    }
}

// ---------------- split-bf16 MFMA GEMM: blocked global -> global_load_lds -> LDS ------
// A planes blocked [rowblk][kq][r] (16B chunks), B planes blocked [colblk][kq][c].
// Staging: 6 global_load_lds(16B) per wave per k-step, each fully coalesced (1KB linear).
// LDS layout = chunk-linear, so every fragment ds_read_b128 is 64 lanes x linear 16B
// (zero bank conflicts). Tile 64x128, K-step 32, 4 waves. Fused column stats.
template<int K>
__global__ __launch_bounds__(256) void gemm_lds(const unsigned short* __restrict__ Ahg,
        const unsigned short* __restrict__ Alg, const unsigned short* __restrict__ Bhg,
        const unsigned short* __restrict__ Blg, const float* __restrict__ bias,
        float* __restrict__ C, float* __restrict__ stats) {
    constexpr int KQ = K >> 3;
    __shared__ __align__(16) unsigned short Asl[8 * 512];    // 8KB: region a=p*4+lq, chunk=r
    __shared__ __align__(16) unsigned short Bsl[16 * 512];   // 16KB: region b=(p*2+ch)*4+lq
    __shared__ float lsum[128], lsq[128];
    int tid = threadIdx.x;
    int lane = tid & 63, w = tid >> 6;
    long row0 = (long)blockIdx.x * 64;
    int col0 = blockIdx.y * 128;
    int colblk0 = blockIdx.y * 2;
    int lm = lane & 15, lq = lane >> 4;
    int rw = (w & 1) * 32, cw = (w >> 1) * 64;
    int chw = w >> 1;                 // which 64-col half this wave computes
    f4v acc[2][4];
#pragma unroll
    for (int i = 0; i < 2; ++i)
#pragma unroll
        for (int j = 0; j < 4; ++j) acc[i][j] = (f4v){0.f, 0.f, 0.f, 0.f};
    if (tid < 128) { lsum[tid] = 0.f; lsq[tid] = 0.f; }

    for (int ks = 0; ks < K / 32; ++ks) {
        int kq0 = ks * 4;
        // ---- A: 2 instr/wave; region a = 2w+t -> plane a>>2, lq a&3 ----
#pragma unroll
        for (int t = 0; t < 2; ++t) {
            int a = 2 * w + t;
            const unsigned short* g = ((a >> 2) ? Alg : Ahg)
                + ((long)(blockIdx.x * KQ + kq0 + (a & 3)) * 64 + lane) * 8;
            __builtin_amdgcn_global_load_lds(
                (const __attribute__((address_space(1))) void*)g,
                (__attribute__((address_space(3))) void*)(Asl + a * 512), 16, 0, 0);
        }
        // ---- B: 4 instr/wave; region b = 4w+u -> plane b>>3, ch (b>>2)&1, lq b&3 ----
#pragma unroll
        for (int u = 0; u < 4; ++u) {
            int b = 4 * w + u;
            const unsigned short* g = ((b >> 3) ? Blg : Bhg)
                + ((long)((colblk0 + ((b >> 2) & 1)) * KQ + kq0 + (b & 3)) * 64 + lane) * 8;
            __builtin_amdgcn_global_load_lds(
                (const __attribute__((address_space(1))) void*)g,
                (__attribute__((address_space(3))) void*)(Bsl + b * 512), 16, 0, 0);
        }
        __syncthreads();
        s8v ah[2], al[2], bh[4], bl[4];
#pragma unroll
        for (int i = 0; i < 2; ++i) {
            int r_loc = rw + i * 16 + lm;
            ah[i] = *(const s8v*)&Asl[(lq * 64 + r_loc) * 8];
            al[i] = *(const s8v*)&Asl[((4 + lq) * 64 + r_loc) * 8];
        }
#pragma unroll
        for (int j = 0; j < 4; ++j) {
            int c_loc = j * 16 + lm;
            bh[j] = *(const s8v*)&Bsl[((chw * 4 + lq) * 64 + c_loc) * 8];
            bl[j] = *(const s8v*)&Bsl[(((2 + chw) * 4 + lq) * 64 + c_loc) * 8];
        }
#pragma unroll
        for (int i = 0; i < 2; ++i)
#pragma unroll
            for (int j = 0; j < 4; ++j) {
                acc[i][j] = __builtin_amdgcn_mfma_f32_16x16x32_bf16(al[i], bh[j], acc[i][j], 0, 0, 0);
                acc[i][j] = __builtin_amdgcn_mfma_f32_16x16x32_bf16(ah[i], bl[j], acc[i][j], 0, 0, 0);
                acc[i][j] = __builtin_amdgcn_mfma_f32_16x16x32_bf16(ah[i], bh[j], acc[i][j], 0, 0, 0);
            }
        __syncthreads();
    }
    // ---- epilogue: bias, store, fused column stats ----
#pragma unroll
    for (int j = 0; j < 4; ++j) {
        int lc = cw + j * 16 + lm;
        int col = col0 + lc;
        float bsv = bias[col];
        float s = 0.f, sq = 0.f;
#pragma unroll
        for (int i = 0; i < 2; ++i) {
#pragma unroll
            for (int reg = 0; reg < 4; ++reg) {
                long row = row0 + rw + i * 16 + lq * 4 + reg;
                float v = acc[i][j][reg] + bsv;
                C[row * HID + col] = v;
                s += v;
                sq += v * v;
            }
        }
        atomicAdd(&lsum[lc], s);
        atomicAdd(&lsq[lc], sq);
    }
    __syncthreads();
    if (tid < 128) {
        atomicAdd(&stats[col0 + tid], lsum[tid]);
        atomicAdd(&stats[HID + col0 + tid], lsq[tid]);
    }
}

__global__ void bn_finalize(const float* __restrict__ stats, const float* __restrict__ g,
                            const float* __restrict__ be, float rows_inv,
                            float* __restrict__ a, float* __restrict__ c) {
    int f = threadIdx.x;
    float mean = stats[f] * rows_inv;
    float var = stats[HID + f] * rows_inv - mean * mean;
    float av = g[f] * rsqrtf(var + EPSV);
    a[f] = av;
    c[f] = be[f] - mean * av;
}

// ---------------- readout ----------------
__global__ __launch_bounds__(256) void readout_accum(const float* __restrict__ on,
                                                     const int* __restrict__ ab,
                                                     float* __restrict__ racc,
                                                     float* __restrict__ rcnt) {
    __shared__ float lacc[NG * NCLS];
    __shared__ float lcnt[NG];
    int tid = threadIdx.x;
    for (int i = tid; i < NG * NCLS; i += 256) lacc[i] = 0.f;
    if (tid < NG) lcnt[tid] = 0.f;
    __syncthreads();
    int n = blockIdx.x * 256 + tid;
    if (n < N_NODES) {
        int b = ab[n];
        atomicAdd(&lcnt[b], 1.0f);
        for (int c = 0; c < NCLS; ++c) atomicAdd(&lacc[b * NCLS + c], on[(long)n * NCLS + c]);
    }
    __syncthreads();
    if (tid < NG && lcnt[tid] > 0.f) {
        atomicAdd(&rcnt[tid], lcnt[tid]);
        for (int c = 0; c < NCLS; ++c) atomicAdd(&racc[tid * NCLS + c], lacc[tid * NCLS + c]);
    }
}

__global__ void readout_final(const float* __restrict__ racc, const float* __restrict__ rcnt,
                              float* __restrict__ out) {
    int i = blockIdx.x * 256 + threadIdx.x;
    if (i < NG * NCLS) out[i] = racc[i] / fmaxf(rcnt[i / NCLS], 1.0f);
}

// ---------------- launch ----------------
extern "C" void kernel_launch(void* const* d_in, const int* in_sizes, int n_in,
                              void* d_out, int out_size, void* d_ws, size_t ws_size,
                              hipStream_t stream) {
    const float* X         = (const float*)d_in[0];
    const int*   node_idx  = (const int*)d_in[1];
    const int*   edge_idx  = (const int*)d_in[2];
    const int*   all_batch = (const int*)d_in[3];
    const float* W1[2]  = {(const float*)d_in[4],  (const float*)d_in[12]};
    const float* b1[2]  = {(const float*)d_in[5],  (const float*)d_in[13]};
    const float* g1[2]  = {(const float*)d_in[6],  (const float*)d_in[14]};
    const float* be1[2] = {(const float*)d_in[7],  (const float*)d_in[15]};
    const float* W2[2]  = {(const float*)d_in[8],  (const float*)d_in[16]};
    const float* b2[2]  = {(const float*)d_in[9],  (const float*)d_in[17]};
    const float* bng[2] = {(const float*)d_in[10], (const float*)d_in[18]};
    const float* bnb[2] = {(const float*)d_in[11], (const float*)d_in[19]};
    const float* headW  = (const float*)d_in[20];
    const float* headb  = (const float*)d_in[21];
    float* out = (float*)d_out;

    char* base = (char*)d_ws;
    size_t off = 0;
    auto alloc = [&](size_t bytes) -> void* {
        size_t o = (off + 255) & ~(size_t)255;
        off = o + bytes;
        return (void*)(base + o);
    };

    const int ZINTS = 2 * M_EDGES + 2 * N_NODES;
    const int ZTOT  = ZINTS + 4 * 2 * HID + NG * NCLS + NG;
    int* ibase  = (int*)alloc((size_t)ZTOT * 4);
    int* cnt_e  = ibase;
    int* cnt_n  = cnt_e + M_EDGES;
    int* cur_e  = cnt_n + N_NODES;
    int* cur_n  = cur_e + M_EDGES;
    float* statsall = (float*)(ibase + ZINTS);
    float* racc     = statsall + 4 * 2 * HID;
    float* rcnt     = racc + NG * NCLS;

    int* off_e  = (int*)alloc((M_EDGES + 1) * 4);
    int* off_n  = (int*)alloc((N_NODES + 1) * 4);
    int* idx_e  = (int*)alloc((size_t)NNZ_CNT * 4);
    int* idx_n  = (int*)alloc((size_t)NNZ_CNT * 4);
    float* dinv = (float*)alloc((size_t)N_NODES * 4);

    unsigned short* Xb = (unsigned short*)alloc((size_t)N_NODES * FT_DIM * 2);
    unsigned short* Eb = (unsigned short*)alloc((size_t)M_EDGES * HID * 2);
    unsigned short* Ph = (unsigned short*)alloc((size_t)N_NODES * HID * 2);
    unsigned short* Pl = (unsigned short*)alloc((size_t)N_NODES * HID * 2);
    unsigned short* Ahp = (unsigned short*)alloc((size_t)N_NODES * HID * 2);
    unsigned short* Alp = (unsigned short*)alloc((size_t)N_NODES * HID * 2);
    unsigned short* Hb  = (unsigned short*)alloc((size_t)N_NODES * HID * 2);
    float* T      = (float*)alloc((size_t)N_NODES * HID * 4);
    float* onodes = (float*)alloc((size_t)N_NODES * NCLS * 4);
    unsigned short* Wp[4][2];
    int WK[4] = {FT_DIM, HID, HID, HID};
    for (int m = 0; m < 4; ++m) {
        Wp[m][0] = (unsigned short*)alloc((size_t)WK[m] * HID * 2);
        Wp[m][1] = (unsigned short*)alloc((size_t)WK[m] * HID * 2);
    }
    float* bnA = (float*)alloc(4 * HID * 4);
    float* bnC = (float*)alloc(4 * HID * 4);

    const int nnz_blocks = (NNZ_CNT + 255) / 256;
    const float rows_inv = 1.0f / (float)N_NODES;
    const int n4 = N_NODES * HID / 4;
    const dim3 ggrid(N_NODES / 64, 2);

    // --- CSR build + degree norm + weight prep ---
    fzero<<<(ZTOT + 255) / 256, 256, 0, stream>>>((float*)ibase, ZTOT);
    count_kernel<<<nnz_blocks, 256, 0, stream>>>(node_idx, edge_idx, cnt_e, cnt_n);
    exscan_kernel<<<1, 1024, 0, stream>>>(cnt_e, off_e, M_EDGES);
    exscan_kernel<<<1, 1024, 0, stream>>>(cnt_n, off_n, N_NODES);
    fill_kernel<<<nnz_blocks, 256, 0, stream>>>(node_idx, edge_idx, off_e, off_n,
                                                cur_e, cur_n, idx_e, idx_n);
    dinv_kernel<<<(N_NODES + 255) / 256, 256, 0, stream>>>(off_n, idx_n, cnt_e, dinv);
    wprep<<<(FT_DIM * HID + 255) / 256, 256, 0, stream>>>(W1[0], Wp[0][0], Wp[0][1], FT_DIM);
    wprep<<<(HID * HID + 255) / 256, 256, 0, stream>>>(W2[0], Wp[1][0], Wp[1][1], HID);
    wprep<<<(HID * HID + 255) / 256, 256, 0, stream>>>(W1[1], Wp[2][0], Wp[2][1], HID);
    wprep<<<(HID * HID + 255) / 256, 256, 0, stream>>>(W2[1], Wp[3][0], Wp[3][1], HID);
    fsplit<<<(N_NODES * FT_DIM / 4 + 255) / 256, 256, 0, stream>>>((const float4*)X,
                                                                   (u4v*)Xb, N_NODES * FT_DIM / 4);

    // ---------------- layer 0 ----------------
    gather_pool<2, false><<<M_EDGES / 4, 256, 0, stream>>>(off_e, idx_e, Xb, Eb, nullptr);
    gather_pool<2, true><<<N_NODES / 4, 256, 0, stream>>>(off_n, idx_n, Eb, Ph, Pl);
    gemm_lds<FT_DIM><<<ggrid, 256, 0, stream>>>(Ph, Pl, Wp[0][0], Wp[0][1], b1[0], T,
                                                statsall + 0 * 512);
    bn_finalize<<<1, 256, 0, stream>>>(statsall + 0 * 512, g1[0], be1[0], rows_inv,
                                       bnA + 0 * HID, bnC + 0 * HID);
    bn_split_blk<<<N_NODES / 64, 256, 0, stream>>>(T, bnA + 0 * HID, bnC + 0 * HID, Ahp, Alp);
    gemm_lds<HID><<<ggrid, 256, 0, stream>>>(Ahp, Alp, Wp[1][0], Wp[1][1], b2[0], T,
                                             statsall + 1 * 512);
    bn_finalize<<<1, 256, 0, stream>>>(statsall + 1 * 512, bng[0], bnb[0], rows_inv,
                                       bnA + 1 * HID, bnC + 1 * HID);
    bn_rowmajor<<<(n4 + 255) / 256, 256, 0, stream>>>((const float4*)T, bnA + 1 * HID,
                                                      bnC + 1 * HID, (u4v*)Hb, n4);
    // shared edge pass (layer-0 readout AND layer-1 pooling)
    gather_pool<4, false><<<M_EDGES / 4, 256, 0, stream>>>(off_e, idx_e, Hb, Eb, nullptr);
    gather_head<true><<<N_NODES / 4, 256, 0, stream>>>(off_n, idx_n, Eb, dinv, headW, headb,
                                                       onodes, Ph, Pl);

    // ---------------- layer 1 ----------------
    gemm_lds<HID><<<ggrid, 256, 0, stream>>>(Ph, Pl, Wp[2][0], Wp[2][1], b1[1], T,
                                             statsall + 2 * 512);
    bn_finalize<<<1, 256, 0, stream>>>(statsall + 2 * 512, g1[1], be1[1], rows_inv,
                                       bnA + 2 * HID, bnC + 2 * HID);
    bn_split_blk<<<N_NODES / 64, 256, 0, stream>>>(T, bnA + 2 * HID, bnC + 2 * HID, Ahp, Alp);
    gemm_lds<HID><<<ggrid, 256, 0, stream>>>(Ahp, Alp, Wp[3][0], Wp[3][1], b2[1], T,
                                             statsall + 3 * 512);
    bn_finalize<<<1, 256, 0, stream>>>(statsall + 3 * 512, bng[1], bnb[1], rows_inv,
                                       bnA + 3 * HID, bnC + 3 * HID);
    bn_rowmajor<<<(n4 + 255) / 256, 256, 0, stream>>>((const float4*)T, bnA + 3 * HID,
                                                      bnC + 3 * HID, (u4v*)Hb, n4);
    gather_pool<4, false><<<M_EDGES / 4, 256, 0, stream>>>(off_e, idx_e, Hb, Eb, nullptr);
    gather_head<false><<<N_NODES / 4, 256, 0, stream>>>(off_n, idx_n, Eb, dinv,
                                                        headW + (size_t)HID * NCLS, headb,
                                                        onodes, nullptr, nullptr);

    // ---------------- readout ----------------
    readout_accum<<<(N_NODES + 255) / 256, 256, 0, stream>>>(onodes, all_batch, racc, rcnt);
    readout_final<<<(NG * NCLS + 255) / 256, 256, 0, stream>>>(racc, rcnt, out);
}

// Round 6
// 710.984 us; speedup vs baseline: 1.1189x; 1.0317x over previous
//
#include <hip/hip_runtime.h>

#define N_NODES 40000
#define M_EDGES 10000
#define NNZ_CNT 400000
#define FT_DIM  128
#define HID     256
#define NCLS    10
#define NG      128
#define EPSV    1e-5f
#define ROWSINV (1.0f / 40000.0f)

typedef short s8v __attribute__((ext_vector_type(8)));
typedef unsigned short u8v __attribute__((ext_vector_type(8)));
typedef float f4v __attribute__((ext_vector_type(4)));
typedef unsigned short u4v __attribute__((ext_vector_type(4)));

__device__ __forceinline__ unsigned short f2bf(float x) {
    unsigned int u = __float_as_uint(x);
    u += 0x7fffu + ((u >> 16) & 1u);
    return (unsigned short)(u >> 16);
}
__device__ __forceinline__ float bf2f(unsigned short h) {
    return __uint_as_float(((unsigned int)h) << 16);
}

// blocked-chunk element address (in shorts) for (r, k) of an A-activation plane
// layout: [r/64][k/8][r%64] 16B chunks
__device__ __forceinline__ long ablk(int r, int k, int K) {
    return ((long)((r >> 6) * (K >> 3) + (k >> 3)) * 64 + (r & 63)) * 8 + (k & 7);
}

// ---------------- utility ----------------
__global__ void fzero(float* __restrict__ p, int n) {
    int i = blockIdx.x * 256 + threadIdx.x;
    if (i < n) p[i] = 0.f;
}

// ---------------- CSR build ----------------
__global__ void count_kernel(const int* __restrict__ ni, const int* __restrict__ ei,
                             int* __restrict__ cnt_e, int* __restrict__ cnt_n) {
    int i = blockIdx.x * 256 + threadIdx.x;
    if (i < NNZ_CNT) {
        atomicAdd(&cnt_e[ei[i]], 1);
        atomicAdd(&cnt_n[ni[i]], 1);
    }
}

__device__ void exscan_body(const int* __restrict__ in, int* __restrict__ out, int n) {
    __shared__ int wsum[16];
    __shared__ int carry_s;
    int tid = threadIdx.x, lane = tid & 63, w = tid >> 6;
    if (tid == 0) carry_s = 0;
    __syncthreads();
    for (int base = 0; base < n; base += 4096) {
        int i0 = base + tid * 4;
        int v[4];
#pragma unroll
        for (int t = 0; t < 4; ++t) v[t] = (i0 + t < n) ? in[i0 + t] : 0;
        int s = v[0] + v[1] + v[2] + v[3];
        int sc = s;
#pragma unroll
        for (int d = 1; d < 64; d <<= 1) {
            int t = __shfl_up(sc, d, 64);
            if (lane >= d) sc += t;
        }
        if (lane == 63) wsum[w] = sc;
        __syncthreads();
        if (tid < 64) {
            int ws = (lane < 16) ? wsum[lane] : 0;
            int wsc = ws;
#pragma unroll
            for (int d = 1; d < 16; d <<= 1) {
                int t = __shfl_up(wsc, d, 64);
                if (lane >= d) wsc += t;
            }
            if (lane < 16) wsum[lane] = wsc - ws;
        }
        __syncthreads();
        int carry = carry_s;
        int ex = carry + wsum[w] + (sc - s);
#pragma unroll
        for (int t = 0; t < 4; ++t) {
            if (i0 + t < n) out[i0 + t] = ex;
            ex += v[t];
        }
        __syncthreads();
        if (tid == 1023) carry_s = ex;
    }
    __syncthreads();
    if (tid == 0) out[n] = carry_s;
}

__global__ __launch_bounds__(1024) void exscan2(const int* __restrict__ ce, int* __restrict__ oe,
                                                const int* __restrict__ cn, int* __restrict__ on_) {
    if (blockIdx.x == 0) exscan_body(ce, oe, M_EDGES);
    else exscan_body(cn, on_, N_NODES);
}

__global__ void fill_kernel(const int* __restrict__ ni, const int* __restrict__ ei,
                            const int* __restrict__ off_e, const int* __restrict__ off_n,
                            int* __restrict__ cur_e, int* __restrict__ cur_n,
                            int* __restrict__ idx_e, int* __restrict__ idx_n) {
    int i = blockIdx.x * 256 + threadIdx.x;
    if (i < NNZ_CNT) {
        int e = ei[i], n = ni[i];
        int pe = atomicAdd(&cur_e[e], 1);
        idx_e[off_e[e] + pe] = n;
        int pn = atomicAdd(&cur_n[n], 1);
        idx_n[off_n[n] + pn] = e;
    }
}

__global__ void dinv_kernel(const int* __restrict__ off_n, const int* __restrict__ idx_n,
                            const int* __restrict__ cnt_e, float* __restrict__ dinv) {
    int n = blockIdx.x * 256 + threadIdx.x;
    if (n < N_NODES) {
        int s = off_n[n], e = off_n[n + 1];
        float p = 0.f;
        for (int j = s; j < e; ++j) p += (float)cnt_e[idx_n[j]];
        dinv[n] = (p > 0.f) ? 1.0f / p : 1.0f;
    }
}

// -------- weight prep (all 4 mats): W[K x 256] fp32 -> blocked planes [c/64][k/8][c%64] ----
struct WPA {
    const float* W[4];
    unsigned short* h[4];
    unsigned short* l[4];
};
__global__ void wprep_all(WPA p) {
    int m = blockIdx.y;
    int K = (m == 0) ? FT_DIM : HID;
    int i = blockIdx.x * 256 + threadIdx.x;
    if (i >= K * 256) return;
    int k = i >> 8, c = i & 255;
    float x = p.W[m][i];
    unsigned short hh = f2bf(x);
    long o = ((long)((c >> 6) * (K >> 3) + (k >> 3)) * 64 + (c & 63)) * 8 + (k & 7);
    p.h[m][o] = hh;
    p.l[m][o] = f2bf(x - bf2f(hh));
}

// ---------------- fp32 -> bf16 (round only, row-major) ----------------
__global__ void fsplit(const float4* __restrict__ src, u4v* __restrict__ h, int n4) {
    int i = blockIdx.x * 256 + threadIdx.x;
    if (i < n4) {
        float4 v = src[i];
        h[i] = (u4v){f2bf(v.x), f2bf(v.y), f2bf(v.z), f2bf(v.w)};
    }
}

// -------- relu(bn(x)) -> blocked hi/lo planes, BN finalize fused (K=256) --------
__global__ __launch_bounds__(256) void bn_split_blk(const float* __restrict__ src,
        const float* __restrict__ stats, const float* __restrict__ g,
        const float* __restrict__ be,
        unsigned short* __restrict__ hOut, unsigned short* __restrict__ lOut) {
    __shared__ float sa[HID], sc_[HID];
    int tid = threadIdx.x;
    {
        float mean = stats[tid] * ROWSINV;
        float var = stats[HID + tid] * ROWSINV - mean * mean;
        float av = g[tid] * rsqrtf(var + EPSV);
        sa[tid] = av;
        sc_[tid] = be[tid] - mean * av;
    }
    __syncthreads();
    int r = tid >> 2, kqg = tid & 3;
    long row = (long)blockIdx.x * 64 + r;
    long cbase = ((long)blockIdx.x * 32) * 64 + r;
#pragma unroll
    for (int t = 0; t < 8; ++t) {
        int kq = kqg * 8 + t;
        const float* sp = src + row * HID + kq * 8;
        float4 v0 = *(const float4*)sp;
        float4 v1 = *(const float4*)(sp + 4);
        float4 a0 = *(const float4*)(sa + kq * 8);
        float4 a1 = *(const float4*)(sa + kq * 8 + 4);
        float4 c0 = *(const float4*)(sc_ + kq * 8);
        float4 c1 = *(const float4*)(sc_ + kq * 8 + 4);
        float x[8];
        x[0] = fmaxf(fmaf(a0.x, v0.x, c0.x), 0.f);
        x[1] = fmaxf(fmaf(a0.y, v0.y, c0.y), 0.f);
        x[2] = fmaxf(fmaf(a0.z, v0.z, c0.z), 0.f);
        x[3] = fmaxf(fmaf(a0.w, v0.w, c0.w), 0.f);
        x[4] = fmaxf(fmaf(a1.x, v1.x, c1.x), 0.f);
        x[5] = fmaxf(fmaf(a1.y, v1.y, c1.y), 0.f);
        x[6] = fmaxf(fmaf(a1.z, v1.z, c1.z), 0.f);
        x[7] = fmaxf(fmaf(a1.w, v1.w, c1.w), 0.f);
        s8v h, l;
#pragma unroll
        for (int q = 0; q < 8; ++q) {
            unsigned short hh = f2bf(x[q]);
            h[q] = (short)hh;
            l[q] = (short)f2bf(x[q] - bf2f(hh));
        }
        long o = (cbase + (long)kq * 64) * 8;
        *(s8v*)(hOut + o) = h;
        *(s8v*)(lOut + o) = l;
    }
}

// -------- relu(bn(x)) -> row-major bf16, BN finalize fused --------
__global__ __launch_bounds__(256) void bn_rowmajor(const float4* __restrict__ src,
        const float* __restrict__ stats, const float* __restrict__ g,
        const float* __restrict__ be, u4v* __restrict__ hOut, int n4) {
    __shared__ float sa[HID], sc_[HID];
    int tid = threadIdx.x;
    {
        float mean = stats[tid] * ROWSINV;
        float var = stats[HID + tid] * ROWSINV - mean * mean;
        float av = g[tid] * rsqrtf(var + EPSV);
        sa[tid] = av;
        sc_[tid] = be[tid] - mean * av;
    }
    __syncthreads();
    int i = blockIdx.x * 256 + tid;
    if (i >= n4) return;
    int col = (i << 2) & (HID - 1);
    float4 av = *(const float4*)(sa + col);
    float4 cv = *(const float4*)(sc_ + col);
    float4 v = src[i];
    float x0 = fmaxf(fmaf(av.x, v.x, cv.x), 0.f);
    float x1 = fmaxf(fmaf(av.y, v.y, cv.y), 0.f);
    float x2 = fmaxf(fmaf(av.z, v.z, cv.z), 0.f);
    float x3 = fmaxf(fmaf(av.w, v.w, cv.w), 0.f);
    hOut[i] = (u4v){f2bf(x0), f2bf(x1), f2bf(x2), f2bf(x3)};
}

// ---------------- multi-gather: 16B/lane, D/8 lanes per gather ----------------
// D=256: 2 gathers/instr; D=128: 4 gathers/instr. fp32 accumulate, cross-half reduce.
// PLANES: write blocked hi/lo planes (one 16B chunk per lane); else row-major bf16.
template<int D, bool PLANES>
__global__ __launch_bounds__(256) void gatherX(const int* __restrict__ off,
        const int* __restrict__ idx, const unsigned short* __restrict__ Y,
        unsigned short* __restrict__ outh, unsigned short* __restrict__ outl) {
    constexpr int LP = D / 8;        // lanes per gather
    constexpr int GPI = 64 / LP;     // gathers per instruction
    int lane = threadIdx.x & 63;
    int r = blockIdx.x * 4 + (threadIdx.x >> 6);
    int h = lane / LP;
    int f0 = (lane & (LP - 1)) * 8;
    int s = off[r], e = off[r + 1];
    float a0[8] = {}, a1[8] = {};
    int j = s;
    for (; j + 2 * GPI <= e; j += 2 * GPI) {
        int ia = idx[j + h];
        int ib = idx[j + GPI + h];
        u8v ga = *(const u8v*)(Y + (long)ia * D + f0);
        u8v gb = *(const u8v*)(Y + (long)ib * D + f0);
#pragma unroll
        for (int v = 0; v < 8; ++v) { a0[v] += bf2f(ga[v]); a1[v] += bf2f(gb[v]); }
    }
    for (; j < e; j += GPI) {
        int jj = j + h;
        int iv = idx[(jj < e) ? jj : s];
        u8v g = *(const u8v*)(Y + (long)iv * D + f0);
        if (jj < e) {
#pragma unroll
            for (int v = 0; v < 8; ++v) a0[v] += bf2f(g[v]);
        }
    }
    float sum[8];
#pragma unroll
    for (int v = 0; v < 8; ++v) {
        sum[v] = a0[v] + a1[v];
#pragma unroll
        for (int m = LP; m < 64; m <<= 1) sum[v] += __shfl_xor(sum[v], m, 64);
    }
    if (h == 0) {
        if (PLANES) {
            s8v hh, ll;
#pragma unroll
            for (int v = 0; v < 8; ++v) {
                unsigned short t = f2bf(sum[v]);
                hh[v] = (short)t;
                ll[v] = (short)f2bf(sum[v] - bf2f(t));
            }
            long o = ablk(r, f0, D);
            *(s8v*)(outh + o) = hh;
            *(s8v*)(outl + o) = ll;
        } else {
            u8v o;
#pragma unroll
            for (int v = 0; v < 8; ++v) o[v] = f2bf(sum[v]);
            *(u8v*)(outh + (long)r * D + f0) = o;
        }
    }
}

// node-side readout: pooled sum (optionally -> blocked P planes) + head matmul (d=256)
template<bool WRITE_P>
__global__ __launch_bounds__(256) void gather_head(const int* __restrict__ off,
        const int* __restrict__ idx, const unsigned short* __restrict__ Y,
        const float* __restrict__ dinv, const float* __restrict__ Wh,
        const float* __restrict__ hb, float* __restrict__ on,
        unsigned short* __restrict__ Ph, unsigned short* __restrict__ Pl) {
    int lane = threadIdx.x & 63;
    int r = blockIdx.x * 4 + (threadIdx.x >> 6);
    int h = lane >> 5;
    int f0 = (lane & 31) * 8;
    int s = off[r], e = off[r + 1];
    float a0[8] = {}, a1[8] = {};
    int j = s;
    for (; j + 4 <= e; j += 4) {
        int ia = idx[j + h];
        int ib = idx[j + 2 + h];
        u8v ga = *(const u8v*)(Y + (long)ia * 256 + f0);
        u8v gb = *(const u8v*)(Y + (long)ib * 256 + f0);
#pragma unroll
        for (int v = 0; v < 8; ++v) { a0[v] += bf2f(ga[v]); a1[v] += bf2f(gb[v]); }
    }
    for (; j < e; j += 2) {
        int jj = j + h;
        int iv = idx[(jj < e) ? jj : s];
        u8v g = *(const u8v*)(Y + (long)iv * 256 + f0);
        if (jj < e) {
#pragma unroll
            for (int v = 0; v < 8; ++v) a0[v] += bf2f(g[v]);
        }
    }
    float sum[8];
#pragma unroll
    for (int v = 0; v < 8; ++v) {
        sum[v] = a0[v] + a1[v];
        sum[v] += __shfl_xor(sum[v], 32, 64);
    }
    if (WRITE_P && h == 0) {
        s8v hh, ll;
#pragma unroll
        for (int v = 0; v < 8; ++v) {
            unsigned short t = f2bf(sum[v]);
            hh[v] = (short)t;
            ll[v] = (short)f2bf(sum[v] - bf2f(t));
        }
        long o = ablk(r, f0, HID);
        *(s8v*)(Ph + o) = hh;
        *(s8v*)(Pl + o) = ll;
    }
    float di = dinv[r];
    const float* wp = Wh + (long)f0 * NCLS;
    float p[NCLS];
#pragma unroll
    for (int c = 0; c < NCLS; ++c) {
        float acc = 0.f;
#pragma unroll
        for (int v = 0; v < 8; ++v) acc += sum[v] * wp[v * NCLS + c];
        p[c] = di * acc;
    }
#pragma unroll
    for (int c = 0; c < NCLS; ++c) {
#pragma unroll
        for (int m = 1; m < 32; m <<= 1) p[c] += __shfl_xor(p[c], m, 64);
    }
    if (lane == 0) {
        if (WRITE_P) {
#pragma unroll
            for (int c = 0; c < NCLS; ++c) on[(long)r * NCLS + c] = p[c] + hb[c];
        } else {
#pragma unroll
            for (int c = 0; c < NCLS; ++c) on[(long)r * NCLS + c] += p[c];
        }
    }
}

// ---------------- split-bf16 MFMA GEMM: blocked global -> global_load_lds, K-step 64 ------
// A planes blocked [rowblk][kq][r], B planes blocked [colblk][kq][c] (16B chunks).
// LDS regions are chunk-linear: staging writes and fragment ds_read_b128 both
// conflict-free. Tile 64x128, K-step 64 (48 MFMA per barrier pair), 4 waves.
template<int K>
__global__ __launch_bounds__(256) void gemm_lds(const unsigned short* __restrict__ Ahg,
        const unsigned short* __restrict__ Alg, const unsigned short* __restrict__ Bhg,
        const unsigned short* __restrict__ Blg, const float* __restrict__ bias,
        float* __restrict__ C, float* __restrict__ stats) {
    constexpr int KQ = K >> 3;
    __shared__ __align__(16) unsigned short Asl[16 * 512];   // 16KB: region a = p*8+kqo
    __shared__ __align__(16) unsigned short Bsl[32 * 512];   // 32KB: region b = p*16+ch*8+kqo
    __shared__ float lsum[128], lsq[128];
    int tid = threadIdx.x;
    int lane = tid & 63, w = tid >> 6;
    long row0 = (long)blockIdx.x * 64;
    int col0 = blockIdx.y * 128;
    int colblk0 = blockIdx.y * 2;
    int lm = lane & 15, lq = lane >> 4;
    int rw = (w & 1) * 32, chw = w >> 1;
    int cw = chw * 64;
    f4v acc[2][4];
#pragma unroll
    for (int i = 0; i < 2; ++i)
#pragma unroll
        for (int j = 0; j < 4; ++j) acc[i][j] = (f4v){0.f, 0.f, 0.f, 0.f};
    if (tid < 128) { lsum[tid] = 0.f; lsq[tid] = 0.f; }

    for (int ks = 0; ks < K / 64; ++ks) {
        int kq0 = ks * 8;
        // A: 4 instr/wave; region a = w*4+t -> plane a>>3, kqo a&7
#pragma unroll
        for (int t = 0; t < 4; ++t) {
            int a = w * 4 + t;
            const unsigned short* g = ((a >> 3) ? Alg : Ahg)
                + ((long)(blockIdx.x * KQ + kq0 + (a & 7)) * 64 + lane) * 8;
            __builtin_amdgcn_global_load_lds(
                (const __attribute__((address_space(1))) void*)g,
                (__attribute__((address_space(3))) void*)(Asl + a * 512), 16, 0, 0);
        }
        // B: 8 instr/wave; region b = w*8+u -> plane b>>4, ch (b>>3)&1, kqo b&7
#pragma unroll
        for (int u = 0; u < 8; ++u) {
            int b = w * 8 + u;
            const unsigned short* g = ((b >> 4) ? Blg : Bhg)
                + ((long)((colblk0 + ((b >> 3) & 1)) * KQ + kq0 + (b & 7)) * 64 + lane) * 8;
            __builtin_amdgcn_global_load_lds(
                (const __attribute__((address_space(1))) void*)g,
                (__attribute__((address_space(3))) void*)(Bsl + b * 512), 16, 0, 0);
        }
        __syncthreads();
#pragma unroll
        for (int kk = 0; kk < 2; ++kk) {
            s8v ah[2], al[2], bh[4], bl[4];
#pragma unroll
            for (int i = 0; i < 2; ++i) {
                int r_loc = rw + i * 16 + lm;
                ah[i] = *(const s8v*)&Asl[(kk * 4 + lq) * 512 + r_loc * 8];
                al[i] = *(const s8v*)&Asl[(8 + kk * 4 + lq) * 512 + r_loc * 8];
            }
#pragma unroll
            for (int j = 0; j < 4; ++j) {
                int c_loc = j * 16 + lm;
                bh[j] = *(const s8v*)&Bsl[(chw * 8 + kk * 4 + lq) * 512 + c_loc * 8];
                bl[j] = *(const s8v*)&Bsl[(16 + chw * 8 + kk * 4 + lq) * 512 + c_loc * 8];
            }
#pragma unroll
            for (int i = 0; i < 2; ++i)
#pragma unroll
                for (int j = 0; j < 4; ++j) {
                    acc[i][j] = __builtin_amdgcn_mfma_f32_16x16x32_bf16(al[i], bh[j], acc[i][j], 0, 0, 0);
                    acc[i][j] = __builtin_amdgcn_mfma_f32_16x16x32_bf16(ah[i], bl[j], acc[i][j], 0, 0, 0);
                    acc[i][j] = __builtin_amdgcn_mfma_f32_16x16x32_bf16(ah[i], bh[j], acc[i][j], 0, 0, 0);
                }
        }
        __syncthreads();
    }
    // ---- epilogue: bias, store, fused column stats ----
#pragma unroll
    for (int j = 0; j < 4; ++j) {
        int lc = cw + j * 16 + lm;
        int col = col0 + lc;
        float bsv = bias[col];
        float s = 0.f, sq = 0.f;
#pragma unroll
        for (int i = 0; i < 2; ++i) {
#pragma unroll
            for (int reg = 0; reg < 4; ++reg) {
                long row = row0 + rw + i * 16 + lq * 4 + reg;
                float v = acc[i][j][reg] + bsv;
                C[row * HID + col] = v;
                s += v;
                sq += v * v;
            }
        }
        atomicAdd(&lsum[lc], s);
        atomicAdd(&lsq[lc], sq);
    }
    __syncthreads();
    if (tid < 128) {
        atomicAdd(&stats[col0 + tid], lsum[tid]);
        atomicAdd(&stats[HID + col0 + tid], lsq[tid]);
    }
}

// ---------------- readout ----------------
__global__ __launch_bounds__(256) void readout_accum(const float* __restrict__ on,
                                                     const int* __restrict__ ab,
                                                     float* __restrict__ racc,
                                                     float* __restrict__ rcnt) {
    __shared__ float lacc[NG * NCLS];
    __shared__ float lcnt[NG];
    int tid = threadIdx.x;
    for (int i = tid; i < NG * NCLS; i += 256) lacc[i] = 0.f;
    if (tid < NG) lcnt[tid] = 0.f;
    __syncthreads();
    int n = blockIdx.x * 256 + tid;
    if (n < N_NODES) {
        int b = ab[n];
        atomicAdd(&lcnt[b], 1.0f);
        for (int c = 0; c < NCLS; ++c) atomicAdd(&lacc[b * NCLS + c], on[(long)n * NCLS + c]);
    }
    __syncthreads();
    if (tid < NG && lcnt[tid] > 0.f) {
        atomicAdd(&rcnt[tid], lcnt[tid]);
        for (int c = 0; c < NCLS; ++c) atomicAdd(&racc[tid * NCLS + c], lacc[tid * NCLS + c]);
    }
}

__global__ void readout_final(const float* __restrict__ racc, const float* __restrict__ rcnt,
                              float* __restrict__ out) {
    int i = blockIdx.x * 256 + threadIdx.x;
    if (i < NG * NCLS) out[i] = racc[i] / fmaxf(rcnt[i / NCLS], 1.0f);
}

// ---------------- launch ----------------
extern "C" void kernel_launch(void* const* d_in, const int* in_sizes, int n_in,
                              void* d_out, int out_size, void* d_ws, size_t ws_size,
                              hipStream_t stream) {
    const float* X         = (const float*)d_in[0];
    const int*   node_idx  = (const int*)d_in[1];
    const int*   edge_idx  = (const int*)d_in[2];
    const int*   all_batch = (const int*)d_in[3];
    const float* W1[2]  = {(const float*)d_in[4],  (const float*)d_in[12]};
    const float* b1[2]  = {(const float*)d_in[5],  (const float*)d_in[13]};
    const float* g1[2]  = {(const float*)d_in[6],  (const float*)d_in[14]};
    const float* be1[2] = {(const float*)d_in[7],  (const float*)d_in[15]};
    const float* W2[2]  = {(const float*)d_in[8],  (const float*)d_in[16]};
    const float* b2[2]  = {(const float*)d_in[9],  (const float*)d_in[17]};
    const float* bng[2] = {(const float*)d_in[10], (const float*)d_in[18]};
    const float* bnb[2] = {(const float*)d_in[11], (const float*)d_in[19]};
    const float* headW  = (const float*)d_in[20];
    const float* headb  = (const float*)d_in[21];
    float* out = (float*)d_out;

    char* base = (char*)d_ws;
    size_t off = 0;
    auto alloc = [&](size_t bytes) -> void* {
        size_t o = (off + 255) & ~(size_t)255;
        off = o + bytes;
        return (void*)(base + o);
    };

    const int ZINTS = 2 * M_EDGES + 2 * N_NODES;
    const int ZTOT  = ZINTS + 4 * 2 * HID + NG * NCLS + NG;
    int* ibase  = (int*)alloc((size_t)ZTOT * 4);
    int* cnt_e  = ibase;
    int* cnt_n  = cnt_e + M_EDGES;
    int* cur_e  = cnt_n + N_NODES;
    int* cur_n  = cur_e + M_EDGES;
    float* statsall = (float*)(ibase + ZINTS);
    float* racc     = statsall + 4 * 2 * HID;
    float* rcnt     = racc + NG * NCLS;

    int* off_e  = (int*)alloc((M_EDGES + 1) * 4);
    int* off_n  = (int*)alloc((N_NODES + 1) * 4);
    int* idx_e  = (int*)alloc((size_t)NNZ_CNT * 4);
    int* idx_n  = (int*)alloc((size_t)NNZ_CNT * 4);
    float* dinv = (float*)alloc((size_t)N_NODES * 4);

    unsigned short* Xb = (unsigned short*)alloc((size_t)N_NODES * FT_DIM * 2);
    unsigned short* Eb = (unsigned short*)alloc((size_t)M_EDGES * HID * 2);
    unsigned short* Ph = (unsigned short*)alloc((size_t)N_NODES * HID * 2);
    unsigned short* Pl = (unsigned short*)alloc((size_t)N_NODES * HID * 2);
    unsigned short* Ahp = (unsigned short*)alloc((size_t)N_NODES * HID * 2);
    unsigned short* Alp = (unsigned short*)alloc((size_t)N_NODES * HID * 2);
    unsigned short* Hb  = (unsigned short*)alloc((size_t)N_NODES * HID * 2);
    float* T      = (float*)alloc((size_t)N_NODES * HID * 4);
    float* onodes = (float*)alloc((size_t)N_NODES * NCLS * 4);
    unsigned short* Wp[4][2];
    int WK[4] = {FT_DIM, HID, HID, HID};
    for (int m = 0; m < 4; ++m) {
        Wp[m][0] = (unsigned short*)alloc((size_t)WK[m] * HID * 2);
        Wp[m][1] = (unsigned short*)alloc((size_t)WK[m] * HID * 2);
    }

    const int nnz_blocks = (NNZ_CNT + 255) / 256;
    const int n4 = N_NODES * HID / 4;
    const dim3 ggrid(N_NODES / 64, 2);

    // --- CSR build + degree norm + weight prep ---
    fzero<<<(ZTOT + 255) / 256, 256, 0, stream>>>((float*)ibase, ZTOT);
    count_kernel<<<nnz_blocks, 256, 0, stream>>>(node_idx, edge_idx, cnt_e, cnt_n);
    exscan2<<<2, 1024, 0, stream>>>(cnt_e, off_e, cnt_n, off_n);
    fill_kernel<<<nnz_blocks, 256, 0, stream>>>(node_idx, edge_idx, off_e, off_n,
                                                cur_e, cur_n, idx_e, idx_n);
    dinv_kernel<<<(N_NODES + 255) / 256, 256, 0, stream>>>(off_n, idx_n, cnt_e, dinv);
    WPA wpa;
    wpa.W[0] = W1[0]; wpa.W[1] = W2[0]; wpa.W[2] = W1[1]; wpa.W[3] = W2[1];
    for (int m = 0; m < 4; ++m) { wpa.h[m] = Wp[m][0]; wpa.l[m] = Wp[m][1]; }
    wprep_all<<<dim3(256, 4), 256, 0, stream>>>(wpa);
    fsplit<<<(N_NODES * FT_DIM / 4 + 255) / 256, 256, 0, stream>>>((const float4*)X,
                                                                   (u4v*)Xb, N_NODES * FT_DIM / 4);

    // ---------------- layer 0 ----------------
    gatherX<FT_DIM, false><<<M_EDGES / 4, 256, 0, stream>>>(off_e, idx_e, Xb, Eb, nullptr);
    gatherX<FT_DIM, true><<<N_NODES / 4, 256, 0, stream>>>(off_n, idx_n, Eb, Ph, Pl);
    gemm_lds<FT_DIM><<<ggrid, 256, 0, stream>>>(Ph, Pl, Wp[0][0], Wp[0][1], b1[0], T,
                                                statsall + 0 * 512);
    bn_split_blk<<<N_NODES / 64, 256, 0, stream>>>(T, statsall + 0 * 512, g1[0], be1[0],
                                                   Ahp, Alp);
    gemm_lds<HID><<<ggrid, 256, 0, stream>>>(Ahp, Alp, Wp[1][0], Wp[1][1], b2[0], T,
                                             statsall + 1 * 512);
    bn_rowmajor<<<(n4 + 255) / 256, 256, 0, stream>>>((const float4*)T, statsall + 1 * 512,
                                                      bng[0], bnb[0], (u4v*)Hb, n4);
    // shared edge pass (layer-0 readout AND layer-1 pooling)
    gatherX<HID, false><<<M_EDGES / 4, 256, 0, stream>>>(off_e, idx_e, Hb, Eb, nullptr);
    gather_head<true><<<N_NODES / 4, 256, 0, stream>>>(off_n, idx_n, Eb, dinv, headW, headb,
                                                       onodes, Ph, Pl);

    // ---------------- layer 1 ----------------
    gemm_lds<HID><<<ggrid, 256, 0, stream>>>(Ph, Pl, Wp[2][0], Wp[2][1], b1[1], T,
                                             statsall + 2 * 512);
    bn_split_blk<<<N_NODES / 64, 256, 0, stream>>>(T, statsall + 2 * 512, g1[1], be1[1],
                                                   Ahp, Alp);
    gemm_lds<HID><<<ggrid, 256, 0, stream>>>(Ahp, Alp, Wp[3][0], Wp[3][1], b2[1], T,
                                             statsall + 3 * 512);
    bn_rowmajor<<<(n4 + 255) / 256, 256, 0, stream>>>((const float4*)T, statsall + 3 * 512,
                                                      bng[1], bnb[1], (u4v*)Hb, n4);
    gatherX<HID, false><<<M_EDGES / 4, 256, 0, stream>>>(off_e, idx_e, Hb, Eb, nullptr);
    gather_head<false><<<N_NODES / 4, 256, 0, stream>>>(off_n, idx_n, Eb, dinv,
                                                        headW + (size_t)HID * NCLS, headb,
                                                        onodes, nullptr, nullptr);

    // ---------------- readout ----------------
    readout_accum<<<(N_NODES + 255) / 256, 256, 0, stream>>>(onodes, all_batch, racc, rcnt);
    readout_final<<<(NG * NCLS + 255) / 256, 256, 0, stream>>>(racc, rcnt, out);
}

// Round 7
// 627.811 us; speedup vs baseline: 1.2671x; 1.1325x over previous
//
#include <hip/hip_runtime.h>

#define N_NODES 40000
#define M_EDGES 10000
#define NNZ_CNT 400000
#define FT_DIM  128
#define HID     256
#define NCLS    10
#define NG      128
#define EPSV    1e-5f
#define ROWSINV (1.0f / 40000.0f)

typedef short s8v __attribute__((ext_vector_type(8)));
typedef unsigned short u8v __attribute__((ext_vector_type(8)));
typedef float f4v __attribute__((ext_vector_type(4)));
typedef unsigned short u4v __attribute__((ext_vector_type(4)));
typedef unsigned short u2v __attribute__((ext_vector_type(2)));

__device__ __forceinline__ unsigned short f2bf(float x) {
    unsigned int u = __float_as_uint(x);
    u += 0x7fffu + ((u >> 16) & 1u);
    return (unsigned short)(u >> 16);
}
__device__ __forceinline__ float bf2f(unsigned short h) {
    return __uint_as_float(((unsigned int)h) << 16);
}

// blocked-chunk element address (in shorts) for (r, k): layout [r/64][k/8][r%64] 16B chunks
__device__ __forceinline__ long ablk(int r, int k, int K) {
    return ((long)((r >> 6) * (K >> 3) + (k >> 3)) * 64 + (r & 63)) * 8 + (k & 7);
}

// ---------------- utility ----------------
__global__ void fzero(float* __restrict__ p, int n) {
    int i = blockIdx.x * 256 + threadIdx.x;
    if (i < n) p[i] = 0.f;
}

// ---------------- CSR build ----------------
__global__ void count_kernel(const int* __restrict__ ni, const int* __restrict__ ei,
                             int* __restrict__ cnt_e, int* __restrict__ cnt_n) {
    int i = blockIdx.x * 256 + threadIdx.x;
    if (i < NNZ_CNT) {
        atomicAdd(&cnt_e[ei[i]], 1);
        atomicAdd(&cnt_n[ni[i]], 1);
    }
}

__device__ void exscan_body(const int* __restrict__ in, int* __restrict__ out, int n) {
    __shared__ int wsum[16];
    __shared__ int carry_s;
    int tid = threadIdx.x, lane = tid & 63, w = tid >> 6;
    if (tid == 0) carry_s = 0;
    __syncthreads();
    for (int base = 0; base < n; base += 4096) {
        int i0 = base + tid * 4;
        int v[4];
#pragma unroll
        for (int t = 0; t < 4; ++t) v[t] = (i0 + t < n) ? in[i0 + t] : 0;
        int s = v[0] + v[1] + v[2] + v[3];
        int sc = s;
#pragma unroll
        for (int d = 1; d < 64; d <<= 1) {
            int t = __shfl_up(sc, d, 64);
            if (lane >= d) sc += t;
        }
        if (lane == 63) wsum[w] = sc;
        __syncthreads();
        if (tid < 64) {
            int ws = (lane < 16) ? wsum[lane] : 0;
            int wsc = ws;
#pragma unroll
            for (int d = 1; d < 16; d <<= 1) {
                int t = __shfl_up(wsc, d, 64);
                if (lane >= d) wsc += t;
            }
            if (lane < 16) wsum[lane] = wsc - ws;
        }
        __syncthreads();
        int carry = carry_s;
        int ex = carry + wsum[w] + (sc - s);
#pragma unroll
        for (int t = 0; t < 4; ++t) {
            if (i0 + t < n) out[i0 + t] = ex;
            ex += v[t];
        }
        __syncthreads();
        if (tid == 1023) carry_s = ex;
    }
    __syncthreads();
    if (tid == 0) out[n] = carry_s;
}

__global__ __launch_bounds__(1024) void exscan2(const int* __restrict__ ce, int* __restrict__ oe,
                                                const int* __restrict__ cn, int* __restrict__ on_) {
    if (blockIdx.x == 0) exscan_body(ce, oe, M_EDGES);
    else exscan_body(cn, on_, N_NODES);
}

__global__ void fill_kernel(const int* __restrict__ ni, const int* __restrict__ ei,
                            const int* __restrict__ off_e, const int* __restrict__ off_n,
                            int* __restrict__ cur_e, int* __restrict__ cur_n,
                            int* __restrict__ idx_e, int* __restrict__ idx_n) {
    int i = blockIdx.x * 256 + threadIdx.x;
    if (i < NNZ_CNT) {
        int e = ei[i], n = ni[i];
        int pe = atomicAdd(&cur_e[e], 1);
        idx_e[off_e[e] + pe] = n;
        int pn = atomicAdd(&cur_n[n], 1);
        idx_n[off_n[n] + pn] = e;
    }
}

__global__ void dinv_kernel(const int* __restrict__ off_n, const int* __restrict__ idx_n,
                            const int* __restrict__ cnt_e, float* __restrict__ dinv) {
    int n = blockIdx.x * 256 + threadIdx.x;
    if (n < N_NODES) {
        int s = off_n[n], e = off_n[n + 1];
        float p = 0.f;
        for (int j = s; j < e; ++j) p += (float)cnt_e[idx_n[j]];
        dinv[n] = (p > 0.f) ? 1.0f / p : 1.0f;
    }
}

// -------- weight prep (all 4 mats): W[K x 256] fp32 -> blocked planes [c/64][k/8][c%64] ----
struct WPA {
    const float* W[4];
    unsigned short* h[4];
    unsigned short* l[4];
};
__global__ void wprep_all(WPA p) {
    int m = blockIdx.y;
    int K = (m == 0) ? FT_DIM : HID;
    int i = blockIdx.x * 256 + threadIdx.x;
    if (i >= K * 256) return;
    int k = i >> 8, c = i & 255;
    float x = p.W[m][i];
    unsigned short hh = f2bf(x);
    long o = ((long)((c >> 6) * (K >> 3) + (k >> 3)) * 64 + (c & 63)) * 8 + (k & 7);
    p.h[m][o] = hh;
    p.l[m][o] = f2bf(x - bf2f(hh));
}

// ---------------- fp32 -> bf16 (round only, row-major) ----------------
__global__ void fsplit(const float4* __restrict__ src, u4v* __restrict__ h, int n4) {
    int i = blockIdx.x * 256 + threadIdx.x;
    if (i < n4) {
        float4 v = src[i];
        h[i] = (u4v){f2bf(v.x), f2bf(v.y), f2bf(v.z), f2bf(v.w)};
    }
}

// -------- relu(bn(x)) -> blocked hi/lo planes, BN finalize fused (K=256) --------
__global__ __launch_bounds__(256) void bn_split_blk(const float* __restrict__ src,
        const float* __restrict__ stats, const float* __restrict__ g,
        const float* __restrict__ be,
        unsigned short* __restrict__ hOut, unsigned short* __restrict__ lOut) {
    __shared__ float sa[HID], sc_[HID];
    int tid = threadIdx.x;
    {
        float mean = stats[tid] * ROWSINV;
        float var = stats[HID + tid] * ROWSINV - mean * mean;
        float av = g[tid] * rsqrtf(var + EPSV);
        sa[tid] = av;
        sc_[tid] = be[tid] - mean * av;
    }
    __syncthreads();
    int r = tid >> 2, kqg = tid & 3;
    long row = (long)blockIdx.x * 64 + r;
    long cbase = ((long)blockIdx.x * 32) * 64 + r;
#pragma unroll
    for (int t = 0; t < 8; ++t) {
        int kq = kqg * 8 + t;
        const float* sp = src + row * HID + kq * 8;
        float4 v0 = *(const float4*)sp;
        float4 v1 = *(const float4*)(sp + 4);
        float4 a0 = *(const float4*)(sa + kq * 8);
        float4 a1 = *(const float4*)(sa + kq * 8 + 4);
        float4 c0 = *(const float4*)(sc_ + kq * 8);
        float4 c1 = *(const float4*)(sc_ + kq * 8 + 4);
        float x[8];
        x[0] = fmaxf(fmaf(a0.x, v0.x, c0.x), 0.f);
        x[1] = fmaxf(fmaf(a0.y, v0.y, c0.y), 0.f);
        x[2] = fmaxf(fmaf(a0.z, v0.z, c0.z), 0.f);
        x[3] = fmaxf(fmaf(a0.w, v0.w, c0.w), 0.f);
        x[4] = fmaxf(fmaf(a1.x, v1.x, c1.x), 0.f);
        x[5] = fmaxf(fmaf(a1.y, v1.y, c1.y), 0.f);
        x[6] = fmaxf(fmaf(a1.z, v1.z, c1.z), 0.f);
        x[7] = fmaxf(fmaf(a1.w, v1.w, c1.w), 0.f);
        s8v h, l;
#pragma unroll
        for (int q = 0; q < 8; ++q) {
            unsigned short hh = f2bf(x[q]);
            h[q] = (short)hh;
            l[q] = (short)f2bf(x[q] - bf2f(hh));
        }
        long o = (cbase + (long)kq * 64) * 8;
        *(s8v*)(hOut + o) = h;
        *(s8v*)(lOut + o) = l;
    }
}

// -------- relu(bn(x)) -> row-major bf16, BN finalize fused --------
__global__ __launch_bounds__(256) void bn_rowmajor(const float4* __restrict__ src,
        const float* __restrict__ stats, const float* __restrict__ g,
        const float* __restrict__ be, u4v* __restrict__ hOut, int n4) {
    __shared__ float sa[HID], sc_[HID];
    int tid = threadIdx.x;
    {
        float mean = stats[tid] * ROWSINV;
        float var = stats[HID + tid] * ROWSINV - mean * mean;
        float av = g[tid] * rsqrtf(var + EPSV);
        sa[tid] = av;
        sc_[tid] = be[tid] - mean * av;
    }
    __syncthreads();
    int i = blockIdx.x * 256 + tid;
    if (i >= n4) return;
    int col = (i << 2) & (HID - 1);
    float4 av = *(const float4*)(sa + col);
    float4 cv = *(const float4*)(sc_ + col);
    float4 v = src[i];
    float x0 = fmaxf(fmaf(av.x, v.x, cv.x), 0.f);
    float x1 = fmaxf(fmaf(av.y, v.y, cv.y), 0.f);
    float x2 = fmaxf(fmaf(av.z, v.z, cv.z), 0.f);
    float x3 = fmaxf(fmaf(av.w, v.w, cv.w), 0.f);
    hOut[i] = (u4v){f2bf(x0), f2bf(x1), f2bf(x2), f2bf(x3)};
}

// ---------------- gathers: one wave per row, uniform (scalar) indices ----------------
// edge gather d=128 (avg degree 40): 8 independent chains, 4B/lane
__global__ __launch_bounds__(256) void gather_e128(const int* __restrict__ off,
        const int* __restrict__ idx, const unsigned short* __restrict__ Y,
        unsigned short* __restrict__ outh) {
    int lane = threadIdx.x & 63;
    int r = blockIdx.x * 4 + (threadIdx.x >> 6);
    int f0 = lane * 2;
    int s = off[r], e = off[r + 1];
    float a[8][2] = {};
    int j = s;
    for (; j + 8 <= e; j += 8) {
#pragma unroll
        for (int u = 0; u < 8; ++u) {
            int iv = __builtin_amdgcn_readfirstlane(idx[j + u]);
            u2v g = *(const u2v*)(Y + (long)iv * FT_DIM + f0);
            a[u][0] += bf2f(g[0]);
            a[u][1] += bf2f(g[1]);
        }
    }
    for (; j < e; ++j) {
        int iv = __builtin_amdgcn_readfirstlane(idx[j]);
        u2v g = *(const u2v*)(Y + (long)iv * FT_DIM + f0);
        a[0][0] += bf2f(g[0]);
        a[0][1] += bf2f(g[1]);
    }
    float s0 = 0.f, s1 = 0.f;
#pragma unroll
    for (int u = 0; u < 8; ++u) { s0 += a[u][0]; s1 += a[u][1]; }
    *(u2v*)(outh + (long)r * FT_DIM + f0) = (u2v){f2bf(s0), f2bf(s1)};
}

// node gather d=128 (avg degree 10): 4 chains, writes blocked hi/lo planes
__global__ __launch_bounds__(256) void gather_n128_planes(const int* __restrict__ off,
        const int* __restrict__ idx, const unsigned short* __restrict__ Y,
        unsigned short* __restrict__ Ph, unsigned short* __restrict__ Pl) {
    int lane = threadIdx.x & 63;
    int r = blockIdx.x * 4 + (threadIdx.x >> 6);
    int f0 = lane * 2;
    int s = off[r], e = off[r + 1];
    float a[4][2] = {};
    int j = s;
    for (; j + 4 <= e; j += 4) {
#pragma unroll
        for (int u = 0; u < 4; ++u) {
            int iv = __builtin_amdgcn_readfirstlane(idx[j + u]);
            u2v g = *(const u2v*)(Y + (long)iv * FT_DIM + f0);
            a[u][0] += bf2f(g[0]);
            a[u][1] += bf2f(g[1]);
        }
    }
    for (; j < e; ++j) {
        int iv = __builtin_amdgcn_readfirstlane(idx[j]);
        u2v g = *(const u2v*)(Y + (long)iv * FT_DIM + f0);
        a[0][0] += bf2f(g[0]);
        a[0][1] += bf2f(g[1]);
    }
    float s0 = a[0][0] + a[1][0] + a[2][0] + a[3][0];
    float s1 = a[0][1] + a[1][1] + a[2][1] + a[3][1];
    unsigned short h0 = f2bf(s0), h1 = f2bf(s1);
    long o = ablk(r, f0, FT_DIM);
    *(u2v*)(Ph + o) = (u2v){h0, h1};
    *(u2v*)(Pl + o) = (u2v){f2bf(s0 - bf2f(h0)), f2bf(s1 - bf2f(h1))};
}

// edge gather d=256 (avg degree 40): 8 chains, 8B/lane; epilogue computes
// z[e][0..9] = rowsum . Wh (head matmul hoisted to edge level); optionally writes Eb.
template<bool WRITE_EB>
__global__ __launch_bounds__(256) void gather_e256_z(const int* __restrict__ off,
        const int* __restrict__ idx, const unsigned short* __restrict__ Y,
        unsigned short* __restrict__ Eb, const float* __restrict__ Wh,
        float* __restrict__ z) {
    int lane = threadIdx.x & 63;
    int r = blockIdx.x * 4 + (threadIdx.x >> 6);
    int f0 = lane * 4;
    int s = off[r], e = off[r + 1];
    float a[8][4] = {};
    int j = s;
    for (; j + 8 <= e; j += 8) {
#pragma unroll
        for (int u = 0; u < 8; ++u) {
            int iv = __builtin_amdgcn_readfirstlane(idx[j + u]);
            u4v g = *(const u4v*)(Y + (long)iv * HID + f0);
#pragma unroll
            for (int v = 0; v < 4; ++v) a[u][v] += bf2f(g[v]);
        }
    }
    for (; j < e; ++j) {
        int iv = __builtin_amdgcn_readfirstlane(idx[j]);
        u4v g = *(const u4v*)(Y + (long)iv * HID + f0);
#pragma unroll
        for (int v = 0; v < 4; ++v) a[0][v] += bf2f(g[v]);
    }
    float sum[4];
#pragma unroll
    for (int v = 0; v < 4; ++v) {
        sum[v] = 0.f;
#pragma unroll
        for (int u = 0; u < 8; ++u) sum[v] += a[u][v];
    }
    if (WRITE_EB) {
        *(u4v*)(Eb + (long)r * HID + f0) =
            (u4v){f2bf(sum[0]), f2bf(sum[1]), f2bf(sum[2]), f2bf(sum[3])};
    }
    // head: p[c] = sum_f row[f] * Wh[f][c]
    const float* wp = Wh + (long)f0 * NCLS;
    float p[NCLS];
#pragma unroll
    for (int c = 0; c < NCLS; ++c)
        p[c] = sum[0] * wp[c] + sum[1] * wp[NCLS + c] + sum[2] * wp[2 * NCLS + c]
             + sum[3] * wp[3 * NCLS + c];
#pragma unroll
    for (int c = 0; c < NCLS; ++c) {
#pragma unroll
        for (int m = 1; m < 64; m <<= 1) p[c] += __shfl_xor(p[c], m, 64);
    }
    if (lane == 0) {
        float* zp = z + (long)r * 16;
        *(float4*)(zp)      = (float4){p[0], p[1], p[2], p[3]};
        *(float4*)(zp + 4)  = (float4){p[4], p[5], p[6], p[7]};
        *(float4*)(zp + 8)  = (float4){p[8], p[9], 0.f, 0.f};
        *(float4*)(zp + 12) = (float4){0.f, 0.f, 0.f, 0.f};
    }
}

// node gather d=256 (avg degree 10): 4 chains, writes blocked hi/lo planes
__global__ __launch_bounds__(256) void gather_n256_planes(const int* __restrict__ off,
        const int* __restrict__ idx, const unsigned short* __restrict__ Y,
        unsigned short* __restrict__ Ph, unsigned short* __restrict__ Pl) {
    int lane = threadIdx.x & 63;
    int r = blockIdx.x * 4 + (threadIdx.x >> 6);
    int f0 = lane * 4;
    int s = off[r], e = off[r + 1];
    float a[4][4] = {};
    int j = s;
    for (; j + 4 <= e; j += 4) {
#pragma unroll
        for (int u = 0; u < 4; ++u) {
            int iv = __builtin_amdgcn_readfirstlane(idx[j + u]);
            u4v g = *(const u4v*)(Y + (long)iv * HID + f0);
#pragma unroll
            for (int v = 0; v < 4; ++v) a[u][v] += bf2f(g[v]);
        }
    }
    for (; j < e; ++j) {
        int iv = __builtin_amdgcn_readfirstlane(idx[j]);
        u4v g = *(const u4v*)(Y + (long)iv * HID + f0);
#pragma unroll
        for (int v = 0; v < 4; ++v) a[0][v] += bf2f(g[v]);
    }
    u4v h, l;
#pragma unroll
    for (int v = 0; v < 4; ++v) {
        float sum = a[0][v] + a[1][v] + a[2][v] + a[3][v];
        unsigned short hh = f2bf(sum);
        h[v] = hh;
        l[v] = f2bf(sum - bf2f(hh));
    }
    long o = ablk(r, f0, HID);
    *(u4v*)(Ph + o) = h;
    *(u4v*)(Pl + o) = l;
}

// node readout over z rows (64B each): 4 threads per node, float4 per thread.
// onodes padded to 16 floats/node. FIRST: write dinv*sum + bias; else accumulate.
template<bool FIRST>
__global__ __launch_bounds__(256) void gather_z(const int* __restrict__ off,
        const int* __restrict__ idx, const float* __restrict__ z,
        const float* __restrict__ dinv, const float* __restrict__ hb,
        float* __restrict__ on) {
    int tid = threadIdx.x;
    int t = tid & 3;
    int n = blockIdx.x * 64 + (tid >> 2);
    int s = off[n], e = off[n + 1];
    float4 a0 = {0,0,0,0}, a1 = {0,0,0,0}, a2 = {0,0,0,0}, a3 = {0,0,0,0};
    int j = s;
    for (; j + 4 <= e; j += 4) {
        float4 g0 = *(const float4*)(z + (long)idx[j] * 16 + t * 4);
        float4 g1 = *(const float4*)(z + (long)idx[j + 1] * 16 + t * 4);
        float4 g2 = *(const float4*)(z + (long)idx[j + 2] * 16 + t * 4);
        float4 g3 = *(const float4*)(z + (long)idx[j + 3] * 16 + t * 4);
        a0.x += g0.x; a0.y += g0.y; a0.z += g0.z; a0.w += g0.w;
        a1.x += g1.x; a1.y += g1.y; a1.z += g1.z; a1.w += g1.w;
        a2.x += g2.x; a2.y += g2.y; a2.z += g2.z; a2.w += g2.w;
        a3.x += g3.x; a3.y += g3.y; a3.z += g3.z; a3.w += g3.w;
    }
    for (; j < e; ++j) {
        float4 g0 = *(const float4*)(z + (long)idx[j] * 16 + t * 4);
        a0.x += g0.x; a0.y += g0.y; a0.z += g0.z; a0.w += g0.w;
    }
    float di = dinv[n];
    float4 acc;
    acc.x = (a0.x + a1.x + a2.x + a3.x) * di;
    acc.y = (a0.y + a1.y + a2.y + a3.y) * di;
    acc.z = (a0.z + a1.z + a2.z + a3.z) * di;
    acc.w = (a0.w + a1.w + a2.w + a3.w) * di;
    float* op = on + (long)n * 16 + t * 4;
    if (FIRST) {
        float4 b;
#pragma unroll
        for (int k = 0; k < 4; ++k) {
            int c = t * 4 + k;
            ((float*)&b)[k] = (c < NCLS) ? hb[c] : 0.f;
        }
        *(float4*)op = (float4){acc.x + b.x, acc.y + b.y, acc.z + b.z, acc.w + b.w};
    } else {
        float4 old = *(float4*)op;
        *(float4*)op = (float4){old.x + acc.x, old.y + acc.y, old.z + acc.z, old.w + acc.w};
    }
}

// ---------------- split-bf16 MFMA GEMM: blocked global -> global_load_lds, K-step 64 ------
template<int K>
__global__ __launch_bounds__(256) void gemm_lds(const unsigned short* __restrict__ Ahg,
        const unsigned short* __restrict__ Alg, const unsigned short* __restrict__ Bhg,
        const unsigned short* __restrict__ Blg, const float* __restrict__ bias,
        float* __restrict__ C, float* __restrict__ stats) {
    constexpr int KQ = K >> 3;
    __shared__ __align__(16) unsigned short Asl[16 * 512];
    __shared__ __align__(16) unsigned short Bsl[32 * 512];
    __shared__ float lsum[128], lsq[128];
    int tid = threadIdx.x;
    int lane = tid & 63, w = tid >> 6;
    long row0 = (long)blockIdx.x * 64;
    int col0 = blockIdx.y * 128;
    int colblk0 = blockIdx.y * 2;
    int lm = lane & 15, lq = lane >> 4;
    int rw = (w & 1) * 32, chw = w >> 1;
    int cw = chw * 64;
    f4v acc[2][4];
#pragma unroll
    for (int i = 0; i < 2; ++i)
#pragma unroll
        for (int j = 0; j < 4; ++j) acc[i][j] = (f4v){0.f, 0.f, 0.f, 0.f};
    if (tid < 128) { lsum[tid] = 0.f; lsq[tid] = 0.f; }

    for (int ks = 0; ks < K / 64; ++ks) {
        int kq0 = ks * 8;
#pragma unroll
        for (int t = 0; t < 4; ++t) {
            int a = w * 4 + t;
            const unsigned short* g = ((a >> 3) ? Alg : Ahg)
                + ((long)(blockIdx.x * KQ + kq0 + (a & 7)) * 64 + lane) * 8;
            __builtin_amdgcn_global_load_lds(
                (const __attribute__((address_space(1))) void*)g,
                (__attribute__((address_space(3))) void*)(Asl + a * 512), 16, 0, 0);
        }
#pragma unroll
        for (int u = 0; u < 8; ++u) {
            int b = w * 8 + u;
            const unsigned short* g = ((b >> 4) ? Blg : Bhg)
                + ((long)((colblk0 + ((b >> 3) & 1)) * KQ + kq0 + (b & 7)) * 64 + lane) * 8;
            __builtin_amdgcn_global_load_lds(
                (const __attribute__((address_space(1))) void*)g,
                (__attribute__((address_space(3))) void*)(Bsl + b * 512), 16, 0, 0);
        }
        __syncthreads();
#pragma unroll
        for (int kk = 0; kk < 2; ++kk) {
            s8v ah[2], al[2], bh[4], bl[4];
#pragma unroll
            for (int i = 0; i < 2; ++i) {
                int r_loc = rw + i * 16 + lm;
                ah[i] = *(const s8v*)&Asl[(kk * 4 + lq) * 512 + r_loc * 8];
                al[i] = *(const s8v*)&Asl[(8 + kk * 4 + lq) * 512 + r_loc * 8];
            }
#pragma unroll
            for (int j = 0; j < 4; ++j) {
                int c_loc = j * 16 + lm;
                bh[j] = *(const s8v*)&Bsl[(chw * 8 + kk * 4 + lq) * 512 + c_loc * 8];
                bl[j] = *(const s8v*)&Bsl[(16 + chw * 8 + kk * 4 + lq) * 512 + c_loc * 8];
            }
#pragma unroll
            for (int i = 0; i < 2; ++i)
#pragma unroll
                for (int j = 0; j < 4; ++j) {
                    acc[i][j] = __builtin_amdgcn_mfma_f32_16x16x32_bf16(al[i], bh[j], acc[i][j], 0, 0, 0);
                    acc[i][j] = __builtin_amdgcn_mfma_f32_16x16x32_bf16(ah[i], bl[j], acc[i][j], 0, 0, 0);
                    acc[i][j] = __builtin_amdgcn_mfma_f32_16x16x32_bf16(ah[i], bh[j], acc[i][j], 0, 0, 0);
                }
        }
        __syncthreads();
    }
#pragma unroll
    for (int j = 0; j < 4; ++j) {
        int lc = cw + j * 16 + lm;
        int col = col0 + lc;
        float bsv = bias[col];
        float s = 0.f, sq = 0.f;
#pragma unroll
        for (int i = 0; i < 2; ++i) {
#pragma unroll
            for (int reg = 0; reg < 4; ++reg) {
                long row = row0 + rw + i * 16 + lq * 4 + reg;
                float v = acc[i][j][reg] + bsv;
                C[row * HID + col] = v;
                s += v;
                sq += v * v;
            }
        }
        atomicAdd(&lsum[lc], s);
        atomicAdd(&lsq[lc], sq);
    }
    __syncthreads();
    if (tid < 128) {
        atomicAdd(&stats[col0 + tid], lsum[tid]);
        atomicAdd(&stats[HID + col0 + tid], lsq[tid]);
    }
}

// ---------------- readout (onodes stride 16) ----------------
__global__ __launch_bounds__(256) void readout_accum(const float* __restrict__ on,
                                                     const int* __restrict__ ab,
                                                     float* __restrict__ racc,
                                                     float* __restrict__ rcnt) {
    __shared__ float lacc[NG * NCLS];
    __shared__ float lcnt[NG];
    int tid = threadIdx.x;
    for (int i = tid; i < NG * NCLS; i += 256) lacc[i] = 0.f;
    if (tid < NG) lcnt[tid] = 0.f;
    __syncthreads();
    int n = blockIdx.x * 256 + tid;
    if (n < N_NODES) {
        int b = ab[n];
        atomicAdd(&lcnt[b], 1.0f);
        for (int c = 0; c < NCLS; ++c) atomicAdd(&lacc[b * NCLS + c], on[(long)n * 16 + c]);
    }
    __syncthreads();
    if (tid < NG && lcnt[tid] > 0.f) {
        atomicAdd(&rcnt[tid], lcnt[tid]);
        for (int c = 0; c < NCLS; ++c) atomicAdd(&racc[tid * NCLS + c], lacc[tid * NCLS + c]);
    }
}

__global__ void readout_final(const float* __restrict__ racc, const float* __restrict__ rcnt,
                              float* __restrict__ out) {
    int i = blockIdx.x * 256 + threadIdx.x;
    if (i < NG * NCLS) out[i] = racc[i] / fmaxf(rcnt[i / NCLS], 1.0f);
}

// ---------------- launch ----------------
extern "C" void kernel_launch(void* const* d_in, const int* in_sizes, int n_in,
                              void* d_out, int out_size, void* d_ws, size_t ws_size,
                              hipStream_t stream) {
    const float* X         = (const float*)d_in[0];
    const int*   node_idx  = (const int*)d_in[1];
    const int*   edge_idx  = (const int*)d_in[2];
    const int*   all_batch = (const int*)d_in[3];
    const float* W1[2]  = {(const float*)d_in[4],  (const float*)d_in[12]};
    const float* b1[2]  = {(const float*)d_in[5],  (const float*)d_in[13]};
    const float* g1[2]  = {(const float*)d_in[6],  (const float*)d_in[14]};
    const float* be1[2] = {(const float*)d_in[7],  (const float*)d_in[15]};
    const float* W2[2]  = {(const float*)d_in[8],  (const float*)d_in[16]};
    const float* b2[2]  = {(const float*)d_in[9],  (const float*)d_in[17]};
    const float* bng[2] = {(const float*)d_in[10], (const float*)d_in[18]};
    const float* bnb[2] = {(const float*)d_in[11], (const float*)d_in[19]};
    const float* headW  = (const float*)d_in[20];
    const float* headb  = (const float*)d_in[21];
    float* out = (float*)d_out;

    char* base = (char*)d_ws;
    size_t off = 0;
    auto alloc = [&](size_t bytes) -> void* {
        size_t o = (off + 255) & ~(size_t)255;
        off = o + bytes;
        return (void*)(base + o);
    };

    const int ZINTS = 2 * M_EDGES + 2 * N_NODES;
    const int ZTOT  = ZINTS + 4 * 2 * HID + NG * NCLS + NG;
    int* ibase  = (int*)alloc((size_t)ZTOT * 4);
    int* cnt_e  = ibase;
    int* cnt_n  = cnt_e + M_EDGES;
    int* cur_e  = cnt_n + N_NODES;
    int* cur_n  = cur_e + M_EDGES;
    float* statsall = (float*)(ibase + ZINTS);
    float* racc     = statsall + 4 * 2 * HID;
    float* rcnt     = racc + NG * NCLS;

    int* off_e  = (int*)alloc((M_EDGES + 1) * 4);
    int* off_n  = (int*)alloc((N_NODES + 1) * 4);
    int* idx_e  = (int*)alloc((size_t)NNZ_CNT * 4);
    int* idx_n  = (int*)alloc((size_t)NNZ_CNT * 4);
    float* dinv = (float*)alloc((size_t)N_NODES * 4);

    unsigned short* Xb = (unsigned short*)alloc((size_t)N_NODES * FT_DIM * 2);
    unsigned short* Eb = (unsigned short*)alloc((size_t)M_EDGES * HID * 2);
    unsigned short* Ph = (unsigned short*)alloc((size_t)N_NODES * HID * 2);
    unsigned short* Pl = (unsigned short*)alloc((size_t)N_NODES * HID * 2);
    unsigned short* Ahp = (unsigned short*)alloc((size_t)N_NODES * HID * 2);
    unsigned short* Alp = (unsigned short*)alloc((size_t)N_NODES * HID * 2);
    unsigned short* Hb  = (unsigned short*)alloc((size_t)N_NODES * HID * 2);
    float* T      = (float*)alloc((size_t)N_NODES * HID * 4);
    float* onodes = (float*)alloc((size_t)N_NODES * 16 * 4);
    float* zbuf   = (float*)alloc((size_t)M_EDGES * 16 * 4);
    unsigned short* Wp[4][2];
    int WK[4] = {FT_DIM, HID, HID, HID};
    for (int m = 0; m < 4; ++m) {
        Wp[m][0] = (unsigned short*)alloc((size_t)WK[m] * HID * 2);
        Wp[m][1] = (unsigned short*)alloc((size_t)WK[m] * HID * 2);
    }

    const int nnz_blocks = (NNZ_CNT + 255) / 256;
    const int n4 = N_NODES * HID / 4;
    const dim3 ggrid(N_NODES / 64, 2);

    // --- CSR build + degree norm + weight prep ---
    fzero<<<(ZTOT + 255) / 256, 256, 0, stream>>>((float*)ibase, ZTOT);
    count_kernel<<<nnz_blocks, 256, 0, stream>>>(node_idx, edge_idx, cnt_e, cnt_n);
    exscan2<<<2, 1024, 0, stream>>>(cnt_e, off_e, cnt_n, off_n);
    fill_kernel<<<nnz_blocks, 256, 0, stream>>>(node_idx, edge_idx, off_e, off_n,
                                                cur_e, cur_n, idx_e, idx_n);
    dinv_kernel<<<(N_NODES + 255) / 256, 256, 0, stream>>>(off_n, idx_n, cnt_e, dinv);
    WPA wpa;
    wpa.W[0] = W1[0]; wpa.W[1] = W2[0]; wpa.W[2] = W1[1]; wpa.W[3] = W2[1];
    for (int m = 0; m < 4; ++m) { wpa.h[m] = Wp[m][0]; wpa.l[m] = Wp[m][1]; }
    wprep_all<<<dim3(256, 4), 256, 0, stream>>>(wpa);
    fsplit<<<(N_NODES * FT_DIM / 4 + 255) / 256, 256, 0, stream>>>((const float4*)X,
                                                                   (u4v*)Xb, N_NODES * FT_DIM / 4);

    // ---------------- layer 0 ----------------
    gather_e128<<<M_EDGES / 4, 256, 0, stream>>>(off_e, idx_e, Xb, Eb);
    gather_n128_planes<<<N_NODES / 4, 256, 0, stream>>>(off_n, idx_n, Eb, Ph, Pl);
    gemm_lds<FT_DIM><<<ggrid, 256, 0, stream>>>(Ph, Pl, Wp[0][0], Wp[0][1], b1[0], T,
                                                statsall + 0 * 512);
    bn_split_blk<<<N_NODES / 64, 256, 0, stream>>>(T, statsall + 0 * 512, g1[0], be1[0],
                                                   Ahp, Alp);
    gemm_lds<HID><<<ggrid, 256, 0, stream>>>(Ahp, Alp, Wp[1][0], Wp[1][1], b2[0], T,
                                             statsall + 1 * 512);
    bn_rowmajor<<<(n4 + 255) / 256, 256, 0, stream>>>((const float4*)T, statsall + 1 * 512,
                                                      bng[0], bnb[0], (u4v*)Hb, n4);
    // shared edge pass: Eb (layer-1 pooling) + z (layer-0 readout head)
    gather_e256_z<true><<<M_EDGES / 4, 256, 0, stream>>>(off_e, idx_e, Hb, Eb, headW, zbuf);
    gather_z<true><<<N_NODES / 64, 256, 0, stream>>>(off_n, idx_n, zbuf, dinv, headb, onodes);
    gather_n256_planes<<<N_NODES / 4, 256, 0, stream>>>(off_n, idx_n, Eb, Ph, Pl);

    // ---------------- layer 1 ----------------
    gemm_lds<HID><<<ggrid, 256, 0, stream>>>(Ph, Pl, Wp[2][0], Wp[2][1], b1[1], T,
                                             statsall + 2 * 512);
    bn_split_blk<<<N_NODES / 64, 256, 0, stream>>>(T, statsall + 2 * 512, g1[1], be1[1],
                                                   Ahp, Alp);
    gemm_lds<HID><<<ggrid, 256, 0, stream>>>(Ahp, Alp, Wp[3][0], Wp[3][1], b2[1], T,
                                             statsall + 3 * 512);
    bn_rowmajor<<<(n4 + 255) / 256, 256, 0, stream>>>((const float4*)T, statsall + 3 * 512,
                                                      bng[1], bnb[1], (u4v*)Hb, n4);
    gather_e256_z<false><<<M_EDGES / 4, 256, 0, stream>>>(off_e, idx_e, Hb, nullptr,
                                                          headW + (size_t)HID * NCLS, zbuf);
    gather_z<false><<<N_NODES / 64, 256, 0, stream>>>(off_n, idx_n, zbuf, dinv, nullptr, onodes);

    // ---------------- readout ----------------
    readout_accum<<<(N_NODES + 255) / 256, 256, 0, stream>>>(onodes, all_batch, racc, rcnt);
    readout_final<<<(NG * NCLS + 255) / 256, 256, 0, stream>>>(racc, rcnt, out);
}

// Round 8
// 603.305 us; speedup vs baseline: 1.3186x; 1.0406x over previous
//
#include <hip/hip_runtime.h>

#define N_NODES 40000
#define M_EDGES 10000
#define NNZ_CNT 400000
#define FT_DIM  128
#define HID     256
#define NCLS    10
#define NG      128
#define EPSV    1e-5f
#define ROWSINV (1.0f / 40000.0f)

typedef short s8v __attribute__((ext_vector_type(8)));
typedef float f4v __attribute__((ext_vector_type(4)));
typedef unsigned short u4v __attribute__((ext_vector_type(4)));
typedef unsigned short u2v __attribute__((ext_vector_type(2)));

__device__ __forceinline__ unsigned short f2bf(float x) {
    unsigned int u = __float_as_uint(x);
    u += 0x7fffu + ((u >> 16) & 1u);
    return (unsigned short)(u >> 16);
}
__device__ __forceinline__ float bf2f(unsigned short h) {
    return __uint_as_float(((unsigned int)h) << 16);
}

// blocked-chunk element address (in shorts) for (r, k): layout [r/64][k/8][r%64] 16B chunks
__device__ __forceinline__ long ablk(int r, int k, int K) {
    return ((long)((r >> 6) * (K >> 3) + (k >> 3)) * 64 + (r & 63)) * 8 + (k & 7);
}

// ---------------- utility ----------------
__global__ void fzero(float* __restrict__ p, int n) {
    int i = blockIdx.x * 256 + threadIdx.x;
    if (i < n) p[i] = 0.f;
}

// ---------------- CSR build ----------------
__global__ void count_kernel(const int* __restrict__ ni, const int* __restrict__ ei,
                             int* __restrict__ cnt_e, int* __restrict__ cnt_n) {
    int i = blockIdx.x * 256 + threadIdx.x;
    if (i < NNZ_CNT) {
        atomicAdd(&cnt_e[ei[i]], 1);
        atomicAdd(&cnt_n[ni[i]], 1);
    }
}

__device__ void exscan_body(const int* __restrict__ in, int* __restrict__ out, int n) {
    __shared__ int wsum[16];
    __shared__ int carry_s;
    int tid = threadIdx.x, lane = tid & 63, w = tid >> 6;
    if (tid == 0) carry_s = 0;
    __syncthreads();
    for (int base = 0; base < n; base += 4096) {
        int i0 = base + tid * 4;
        int v[4];
#pragma unroll
        for (int t = 0; t < 4; ++t) v[t] = (i0 + t < n) ? in[i0 + t] : 0;
        int s = v[0] + v[1] + v[2] + v[3];
        int sc = s;
#pragma unroll
        for (int d = 1; d < 64; d <<= 1) {
            int t = __shfl_up(sc, d, 64);
            if (lane >= d) sc += t;
        }
        if (lane == 63) wsum[w] = sc;
        __syncthreads();
        if (tid < 64) {
            int ws = (lane < 16) ? wsum[lane] : 0;
            int wsc = ws;
#pragma unroll
            for (int d = 1; d < 16; d <<= 1) {
                int t = __shfl_up(wsc, d, 64);
                if (lane >= d) wsc += t;
            }
            if (lane < 16) wsum[lane] = wsc - ws;
        }
        __syncthreads();
        int carry = carry_s;
        int ex = carry + wsum[w] + (sc - s);
#pragma unroll
        for (int t = 0; t < 4; ++t) {
            if (i0 + t < n) out[i0 + t] = ex;
            ex += v[t];
        }
        __syncthreads();
        if (tid == 1023) carry_s = ex;
    }
    __syncthreads();
    if (tid == 0) out[n] = carry_s;
}

__global__ __launch_bounds__(1024) void exscan2(const int* __restrict__ ce, int* __restrict__ oe,
                                                const int* __restrict__ cn, int* __restrict__ on_) {
    if (blockIdx.x == 0) exscan_body(ce, oe, M_EDGES);
    else exscan_body(cn, on_, N_NODES);
}

__global__ void fill_kernel(const int* __restrict__ ni, const int* __restrict__ ei,
                            const int* __restrict__ off_e, const int* __restrict__ off_n,
                            int* __restrict__ cur_e, int* __restrict__ cur_n,
                            int* __restrict__ idx_e, int* __restrict__ idx_n) {
    int i = blockIdx.x * 256 + threadIdx.x;
    if (i < NNZ_CNT) {
        int e = ei[i], n = ni[i];
        int pe = atomicAdd(&cur_e[e], 1);
        idx_e[off_e[e] + pe] = n;
        int pn = atomicAdd(&cur_n[n], 1);
        idx_n[off_n[n] + pn] = e;
    }
}

__global__ void dinv_kernel(const int* __restrict__ off_n, const int* __restrict__ idx_n,
                            const int* __restrict__ cnt_e, float* __restrict__ dinv) {
    int n = blockIdx.x * 256 + threadIdx.x;
    if (n < N_NODES) {
        int s = off_n[n], e = off_n[n + 1];
        float p = 0.f;
        for (int j = s; j < e; ++j) p += (float)cnt_e[idx_n[j]];
        dinv[n] = (p > 0.f) ? 1.0f / p : 1.0f;
    }
}

// -------- weight prep (all 4 mats): W[K x 256] fp32 -> blocked hi/lo planes --------
struct WPA {
    const float* W[4];
    unsigned short* h[4];
    unsigned short* l[4];
};
__global__ void wprep_all(WPA p) {
    int m = blockIdx.y;
    int K = (m == 0) ? FT_DIM : HID;
    int i = blockIdx.x * 256 + threadIdx.x;
    if (i >= K * 256) return;
    int k = i >> 8, c = i & 255;
    float x = p.W[m][i];
    unsigned short hh = f2bf(x);
    long o = ((long)((c >> 6) * (K >> 3) + (k >> 3)) * 64 + (c & 63)) * 8 + (k & 7);
    p.h[m][o] = hh;
    p.l[m][o] = f2bf(x - bf2f(hh));
}

// ---------------- fp32 -> bf16 (round only, row-major) ----------------
__global__ void fsplit(const float4* __restrict__ src, u4v* __restrict__ h, int n4) {
    int i = blockIdx.x * 256 + threadIdx.x;
    if (i < n4) {
        float4 v = src[i];
        h[i] = (u4v){f2bf(v.x), f2bf(v.y), f2bf(v.z), f2bf(v.w)};
    }
}

// -------- relu(bn(x)) -> blocked single bf16 plane, BN finalize fused (K=256) --------
__global__ __launch_bounds__(256) void bn_split_blk(const float* __restrict__ src,
        const float* __restrict__ stats, const float* __restrict__ g,
        const float* __restrict__ be, unsigned short* __restrict__ hOut) {
    __shared__ float sa[HID], sc_[HID];
    int tid = threadIdx.x;
    {
        float mean = stats[tid] * ROWSINV;
        float var = stats[HID + tid] * ROWSINV - mean * mean;
        float av = g[tid] * rsqrtf(var + EPSV);
        sa[tid] = av;
        sc_[tid] = be[tid] - mean * av;
    }
    __syncthreads();
    int r = tid >> 2, kqg = tid & 3;
    long row = (long)blockIdx.x * 64 + r;
    long cbase = ((long)blockIdx.x * 32) * 64 + r;
#pragma unroll
    for (int t = 0; t < 8; ++t) {
        int kq = kqg * 8 + t;
        const float* sp = src + row * HID + kq * 8;
        float4 v0 = *(const float4*)sp;
        float4 v1 = *(const float4*)(sp + 4);
        float4 a0 = *(const float4*)(sa + kq * 8);
        float4 a1 = *(const float4*)(sa + kq * 8 + 4);
        float4 c0 = *(const float4*)(sc_ + kq * 8);
        float4 c1 = *(const float4*)(sc_ + kq * 8 + 4);
        s8v h;
        h[0] = (short)f2bf(fmaxf(fmaf(a0.x, v0.x, c0.x), 0.f));
        h[1] = (short)f2bf(fmaxf(fmaf(a0.y, v0.y, c0.y), 0.f));
        h[2] = (short)f2bf(fmaxf(fmaf(a0.z, v0.z, c0.z), 0.f));
        h[3] = (short)f2bf(fmaxf(fmaf(a0.w, v0.w, c0.w), 0.f));
        h[4] = (short)f2bf(fmaxf(fmaf(a1.x, v1.x, c1.x), 0.f));
        h[5] = (short)f2bf(fmaxf(fmaf(a1.y, v1.y, c1.y), 0.f));
        h[6] = (short)f2bf(fmaxf(fmaf(a1.z, v1.z, c1.z), 0.f));
        h[7] = (short)f2bf(fmaxf(fmaf(a1.w, v1.w, c1.w), 0.f));
        *(s8v*)(hOut + (cbase + (long)kq * 64) * 8) = h;
    }
}

// -------- relu(bn(x)) -> row-major bf16, BN finalize fused --------
__global__ __launch_bounds__(256) void bn_rowmajor(const float4* __restrict__ src,
        const float* __restrict__ stats, const float* __restrict__ g,
        const float* __restrict__ be, u4v* __restrict__ hOut, int n4) {
    __shared__ float sa[HID], sc_[HID];
    int tid = threadIdx.x;
    {
        float mean = stats[tid] * ROWSINV;
        float var = stats[HID + tid] * ROWSINV - mean * mean;
        float av = g[tid] * rsqrtf(var + EPSV);
        sa[tid] = av;
        sc_[tid] = be[tid] - mean * av;
    }
    __syncthreads();
    int i = blockIdx.x * 256 + tid;
    if (i >= n4) return;
    int col = (i << 2) & (HID - 1);
    float4 av = *(const float4*)(sa + col);
    float4 cv = *(const float4*)(sc_ + col);
    float4 v = src[i];
    float x0 = fmaxf(fmaf(av.x, v.x, cv.x), 0.f);
    float x1 = fmaxf(fmaf(av.y, v.y, cv.y), 0.f);
    float x2 = fmaxf(fmaf(av.z, v.z, cv.z), 0.f);
    float x3 = fmaxf(fmaf(av.w, v.w, cv.w), 0.f);
    hOut[i] = (u4v){f2bf(x0), f2bf(x1), f2bf(x2), f2bf(x3)};
}

// ---------------- gathers: one wave per row, uniform (scalar) indices ----------------
// edge gather d=128 (avg degree 40): 8 independent chains, 4B/lane
__global__ __launch_bounds__(256) void gather_e128(const int* __restrict__ off,
        const int* __restrict__ idx, const unsigned short* __restrict__ Y,
        unsigned short* __restrict__ outh) {
    int lane = threadIdx.x & 63;
    int r = blockIdx.x * 4 + (threadIdx.x >> 6);
    int f0 = lane * 2;
    int s = off[r], e = off[r + 1];
    float a[8][2] = {};
    int j = s;
    for (; j + 8 <= e; j += 8) {
#pragma unroll
        for (int u = 0; u < 8; ++u) {
            int iv = __builtin_amdgcn_readfirstlane(idx[j + u]);
            u2v g = *(const u2v*)(Y + (long)iv * FT_DIM + f0);
            a[u][0] += bf2f(g[0]);
            a[u][1] += bf2f(g[1]);
        }
    }
    for (; j < e; ++j) {
        int iv = __builtin_amdgcn_readfirstlane(idx[j]);
        u2v g = *(const u2v*)(Y + (long)iv * FT_DIM + f0);
        a[0][0] += bf2f(g[0]);
        a[0][1] += bf2f(g[1]);
    }
    float s0 = 0.f, s1 = 0.f;
#pragma unroll
    for (int u = 0; u < 8; ++u) { s0 += a[u][0]; s1 += a[u][1]; }
    *(u2v*)(outh + (long)r * FT_DIM + f0) = (u2v){f2bf(s0), f2bf(s1)};
}

// node gather d=128 (avg degree 10): 4 chains, writes blocked single plane
__global__ __launch_bounds__(256) void gather_n128_planes(const int* __restrict__ off,
        const int* __restrict__ idx, const unsigned short* __restrict__ Y,
        unsigned short* __restrict__ Ph) {
    int lane = threadIdx.x & 63;
    int r = blockIdx.x * 4 + (threadIdx.x >> 6);
    int f0 = lane * 2;
    int s = off[r], e = off[r + 1];
    float a[4][2] = {};
    int j = s;
    for (; j + 4 <= e; j += 4) {
#pragma unroll
        for (int u = 0; u < 4; ++u) {
            int iv = __builtin_amdgcn_readfirstlane(idx[j + u]);
            u2v g = *(const u2v*)(Y + (long)iv * FT_DIM + f0);
            a[u][0] += bf2f(g[0]);
            a[u][1] += bf2f(g[1]);
        }
    }
    for (; j < e; ++j) {
        int iv = __builtin_amdgcn_readfirstlane(idx[j]);
        u2v g = *(const u2v*)(Y + (long)iv * FT_DIM + f0);
        a[0][0] += bf2f(g[0]);
        a[0][1] += bf2f(g[1]);
    }
    float s0 = a[0][0] + a[1][0] + a[2][0] + a[3][0];
    float s1 = a[0][1] + a[1][1] + a[2][1] + a[3][1];
    *(u2v*)(Ph + ablk(r, f0, FT_DIM)) = (u2v){f2bf(s0), f2bf(s1)};
}

// edge gather d=256 (avg degree 40): 8 chains, 8B/lane; epilogue computes
// z[e][0..9] = rowsum . Wh (head matmul hoisted to edge level); optionally writes Eb.
template<bool WRITE_EB>
__global__ __launch_bounds__(256) void gather_e256_z(const int* __restrict__ off,
        const int* __restrict__ idx, const unsigned short* __restrict__ Y,
        unsigned short* __restrict__ Eb, const float* __restrict__ Wh,
        float* __restrict__ z) {
    int lane = threadIdx.x & 63;
    int r = blockIdx.x * 4 + (threadIdx.x >> 6);
    int f0 = lane * 4;
    int s = off[r], e = off[r + 1];
    float a[8][4] = {};
    int j = s;
    for (; j + 8 <= e; j += 8) {
#pragma unroll
        for (int u = 0; u < 8; ++u) {
            int iv = __builtin_amdgcn_readfirstlane(idx[j + u]);
            u4v g = *(const u4v*)(Y + (long)iv * HID + f0);
#pragma unroll
            for (int v = 0; v < 4; ++v) a[u][v] += bf2f(g[v]);
        }
    }
    for (; j < e; ++j) {
        int iv = __builtin_amdgcn_readfirstlane(idx[j]);
        u4v g = *(const u4v*)(Y + (long)iv * HID + f0);
#pragma unroll
        for (int v = 0; v < 4; ++v) a[0][v] += bf2f(g[v]);
    }
    float sum[4];
#pragma unroll
    for (int v = 0; v < 4; ++v) {
        sum[v] = 0.f;
#pragma unroll
        for (int u = 0; u < 8; ++u) sum[v] += a[u][v];
    }
    if (WRITE_EB) {
        *(u4v*)(Eb + (long)r * HID + f0) =
            (u4v){f2bf(sum[0]), f2bf(sum[1]), f2bf(sum[2]), f2bf(sum[3])};
    }
    const float* wp = Wh + (long)f0 * NCLS;
    float p[NCLS];
#pragma unroll
    for (int c = 0; c < NCLS; ++c)
        p[c] = sum[0] * wp[c] + sum[1] * wp[NCLS + c] + sum[2] * wp[2 * NCLS + c]
             + sum[3] * wp[3 * NCLS + c];
#pragma unroll
    for (int c = 0; c < NCLS; ++c) {
#pragma unroll
        for (int m = 1; m < 64; m <<= 1) p[c] += __shfl_xor(p[c], m, 64);
    }
    if (lane == 0) {
        float* zp = z + (long)r * 16;
        *(float4*)(zp)      = (float4){p[0], p[1], p[2], p[3]};
        *(float4*)(zp + 4)  = (float4){p[4], p[5], p[6], p[7]};
        *(float4*)(zp + 8)  = (float4){p[8], p[9], 0.f, 0.f};
        *(float4*)(zp + 12) = (float4){0.f, 0.f, 0.f, 0.f};
    }
}

// node gather d=256 (avg degree 10): 4 chains, writes blocked single plane
__global__ __launch_bounds__(256) void gather_n256_planes(const int* __restrict__ off,
        const int* __restrict__ idx, const unsigned short* __restrict__ Y,
        unsigned short* __restrict__ Ph) {
    int lane = threadIdx.x & 63;
    int r = blockIdx.x * 4 + (threadIdx.x >> 6);
    int f0 = lane * 4;
    int s = off[r], e = off[r + 1];
    float a[4][4] = {};
    int j = s;
    for (; j + 4 <= e; j += 4) {
#pragma unroll
        for (int u = 0; u < 4; ++u) {
            int iv = __builtin_amdgcn_readfirstlane(idx[j + u]);
            u4v g = *(const u4v*)(Y + (long)iv * HID + f0);
#pragma unroll
            for (int v = 0; v < 4; ++v) a[u][v] += bf2f(g[v]);
        }
    }
    for (; j < e; ++j) {
        int iv = __builtin_amdgcn_readfirstlane(idx[j]);
        u4v g = *(const u4v*)(Y + (long)iv * HID + f0);
#pragma unroll
        for (int v = 0; v < 4; ++v) a[0][v] += bf2f(g[v]);
    }
    u4v h;
#pragma unroll
    for (int v = 0; v < 4; ++v) h[v] = f2bf(a[0][v] + a[1][v] + a[2][v] + a[3][v]);
    *(u4v*)(Ph + ablk(r, f0, HID)) = h;
}

// node readout over z rows (64B each): 4 threads per node, float4 per thread.
template<bool FIRST>
__global__ __launch_bounds__(256) void gather_z(const int* __restrict__ off,
        const int* __restrict__ idx, const float* __restrict__ z,
        const float* __restrict__ dinv, const float* __restrict__ hb,
        float* __restrict__ on) {
    int tid = threadIdx.x;
    int t = tid & 3;
    int n = blockIdx.x * 64 + (tid >> 2);
    int s = off[n], e = off[n + 1];
    float4 a0 = {0,0,0,0}, a1 = {0,0,0,0}, a2 = {0,0,0,0}, a3 = {0,0,0,0};
    int j = s;
    for (; j + 4 <= e; j += 4) {
        float4 g0 = *(const float4*)(z + (long)idx[j] * 16 + t * 4);
        float4 g1 = *(const float4*)(z + (long)idx[j + 1] * 16 + t * 4);
        float4 g2 = *(const float4*)(z + (long)idx[j + 2] * 16 + t * 4);
        float4 g3 = *(const float4*)(z + (long)idx[j + 3] * 16 + t * 4);
        a0.x += g0.x; a0.y += g0.y; a0.z += g0.z; a0.w += g0.w;
        a1.x += g1.x; a1.y += g1.y; a1.z += g1.z; a1.w += g1.w;
        a2.x += g2.x; a2.y += g2.y; a2.z += g2.z; a2.w += g2.w;
        a3.x += g3.x; a3.y += g3.y; a3.z += g3.z; a3.w += g3.w;
    }
    for (; j < e; ++j) {
        float4 g0 = *(const float4*)(z + (long)idx[j] * 16 + t * 4);
        a0.x += g0.x; a0.y += g0.y; a0.z += g0.z; a0.w += g0.w;
    }
    float di = dinv[n];
    float4 acc;
    acc.x = (a0.x + a1.x + a2.x + a3.x) * di;
    acc.y = (a0.y + a1.y + a2.y + a3.y) * di;
    acc.z = (a0.z + a1.z + a2.z + a3.z) * di;
    acc.w = (a0.w + a1.w + a2.w + a3.w) * di;
    float* op = on + (long)n * 16 + t * 4;
    if (FIRST) {
        float4 b;
#pragma unroll
        for (int k = 0; k < 4; ++k) {
            int c = t * 4 + k;
            ((float*)&b)[k] = (c < NCLS) ? hb[c] : 0.f;
        }
        *(float4*)op = (float4){acc.x + b.x, acc.y + b.y, acc.z + b.z, acc.w + b.w};
    } else {
        float4 old = *(float4*)op;
        *(float4*)op = (float4){old.x + acc.x, old.y + acc.y, old.z + acc.z, old.w + acc.w};
    }
}

// ---------------- single-A-plane MFMA GEMM: C = A_bf16 @ (Bh+Bl) + bias ----------------
// A plane blocked [rowblk][kq][r], B planes blocked [colblk][kq][c] (16B chunks).
// LDS exactly 40KB (A 8K + B 32K; stats aliased onto Asl after the k-loop) -> 4 blocks/CU.
// Tile 64x128, K-step 64, 2 MFMA per (i,j,kk). Fused column stats.
template<int K>
__global__ __launch_bounds__(256) void gemm_lds(const unsigned short* __restrict__ Ahg,
        const unsigned short* __restrict__ Bhg, const unsigned short* __restrict__ Blg,
        const float* __restrict__ bias, float* __restrict__ C, float* __restrict__ stats) {
    constexpr int KQ = K >> 3;
    __shared__ __align__(16) unsigned short Asl[8 * 512];    // 8 KB
    __shared__ __align__(16) unsigned short Bsl[32 * 512];   // 32 KB
    float* lsum = (float*)Asl;          // aliased: Asl dead after k-loop
    float* lsq  = lsum + 128;
    int tid = threadIdx.x;
    int lane = tid & 63, w = tid >> 6;
    long row0 = (long)blockIdx.x * 64;
    int col0 = blockIdx.y * 128;
    int colblk0 = blockIdx.y * 2;
    int lm = lane & 15, lq = lane >> 4;
    int rw = (w & 1) * 32, chw = w >> 1;
    int cw = chw * 64;
    f4v acc[2][4];
#pragma unroll
    for (int i = 0; i < 2; ++i)
#pragma unroll
        for (int j = 0; j < 4; ++j) acc[i][j] = (f4v){0.f, 0.f, 0.f, 0.f};

    for (int ks = 0; ks < K / 64; ++ks) {
        int kq0 = ks * 8;
        // A: 2 instr/wave; region a = 2w+t (0..7) -> kq offset a
#pragma unroll
        for (int t = 0; t < 2; ++t) {
            int a = 2 * w + t;
            const unsigned short* g = Ahg
                + ((long)(blockIdx.x * KQ + kq0 + a) * 64 + lane) * 8;
            __builtin_amdgcn_global_load_lds(
                (const __attribute__((address_space(1))) void*)g,
                (__attribute__((address_space(3))) void*)(Asl + a * 512), 16, 0, 0);
        }
        // B: 8 instr/wave; region b = w*8+u -> plane b>>4, ch (b>>3)&1, kq b&7
#pragma unroll
        for (int u = 0; u < 8; ++u) {
            int b = w * 8 + u;
            const unsigned short* g = ((b >> 4) ? Blg : Bhg)
                + ((long)((colblk0 + ((b >> 3) & 1)) * KQ + kq0 + (b & 7)) * 64 + lane) * 8;
            __builtin_amdgcn_global_load_lds(
                (const __attribute__((address_space(1))) void*)g,
                (__attribute__((address_space(3))) void*)(Bsl + b * 512), 16, 0, 0);
        }
        __syncthreads();
#pragma unroll
        for (int kk = 0; kk < 2; ++kk) {
            s8v ah[2], bh[4], bl[4];
#pragma unroll
            for (int i = 0; i < 2; ++i) {
                int r_loc = rw + i * 16 + lm;
                ah[i] = *(const s8v*)&Asl[(kk * 4 + lq) * 512 + r_loc * 8];
            }
#pragma unroll
            for (int j = 0; j < 4; ++j) {
                int c_loc = j * 16 + lm;
                bh[j] = *(const s8v*)&Bsl[(chw * 8 + kk * 4 + lq) * 512 + c_loc * 8];
                bl[j] = *(const s8v*)&Bsl[(16 + chw * 8 + kk * 4 + lq) * 512 + c_loc * 8];
            }
#pragma unroll
            for (int i = 0; i < 2; ++i)
#pragma unroll
                for (int j = 0; j < 4; ++j) {
                    acc[i][j] = __builtin_amdgcn_mfma_f32_16x16x32_bf16(ah[i], bl[j], acc[i][j], 0, 0, 0);
                    acc[i][j] = __builtin_amdgcn_mfma_f32_16x16x32_bf16(ah[i], bh[j], acc[i][j], 0, 0, 0);
                }
        }
        __syncthreads();
    }
    // ---- epilogue: init aliased stats LDS, store C, fused column stats ----
    if (tid < 128) { lsum[tid] = 0.f; lsq[tid] = 0.f; }
    __syncthreads();
#pragma unroll
    for (int j = 0; j < 4; ++j) {
        int lc = cw + j * 16 + lm;
        int col = col0 + lc;
        float bsv = bias[col];
        float s = 0.f, sq = 0.f;
#pragma unroll
        for (int i = 0; i < 2; ++i) {
#pragma unroll
            for (int reg = 0; reg < 4; ++reg) {
                long row = row0 + rw + i * 16 + lq * 4 + reg;
                float v = acc[i][j][reg] + bsv;
                C[row * HID + col] = v;
                s += v;
                sq += v * v;
            }
        }
        atomicAdd(&lsum[lc], s);
        atomicAdd(&lsq[lc], sq);
    }
    __syncthreads();
    if (tid < 128) {
        atomicAdd(&stats[col0 + tid], lsum[tid]);
        atomicAdd(&stats[HID + col0 + tid], lsq[tid]);
    }
}

// ---------------- readout (onodes stride 16) ----------------
__global__ __launch_bounds__(256) void readout_accum(const float* __restrict__ on,
                                                     const int* __restrict__ ab,
                                                     float* __restrict__ racc,
                                                     float* __restrict__ rcnt) {
    __shared__ float lacc[NG * NCLS];
    __shared__ float lcnt[NG];
    int tid = threadIdx.x;
    for (int i = tid; i < NG * NCLS; i += 256) lacc[i] = 0.f;
    if (tid < NG) lcnt[tid] = 0.f;
    __syncthreads();
    int n = blockIdx.x * 256 + tid;
    if (n < N_NODES) {
        int b = ab[n];
        atomicAdd(&lcnt[b], 1.0f);
        for (int c = 0; c < NCLS; ++c) atomicAdd(&lacc[b * NCLS + c], on[(long)n * 16 + c]);
    }
    __syncthreads();
    if (tid < NG && lcnt[tid] > 0.f) {
        atomicAdd(&rcnt[tid], lcnt[tid]);
        for (int c = 0; c < NCLS; ++c) atomicAdd(&racc[tid * NCLS + c], lacc[tid * NCLS + c]);
    }
}

__global__ void readout_final(const float* __restrict__ racc, const float* __restrict__ rcnt,
                              float* __restrict__ out) {
    int i = blockIdx.x * 256 + threadIdx.x;
    if (i < NG * NCLS) out[i] = racc[i] / fmaxf(rcnt[i / NCLS], 1.0f);
}

// ---------------- launch ----------------
extern "C" void kernel_launch(void* const* d_in, const int* in_sizes, int n_in,
                              void* d_out, int out_size, void* d_ws, size_t ws_size,
                              hipStream_t stream) {
    const float* X         = (const float*)d_in[0];
    const int*   node_idx  = (const int*)d_in[1];
    const int*   edge_idx  = (const int*)d_in[2];
    const int*   all_batch = (const int*)d_in[3];
    const float* W1[2]  = {(const float*)d_in[4],  (const float*)d_in[12]};
    const float* b1[2]  = {(const float*)d_in[5],  (const float*)d_in[13]};
    const float* g1[2]  = {(const float*)d_in[6],  (const float*)d_in[14]};
    const float* be1[2] = {(const float*)d_in[7],  (const float*)d_in[15]};
    const float* W2[2]  = {(const float*)d_in[8],  (const float*)d_in[16]};
    const float* b2[2]  = {(const float*)d_in[9],  (const float*)d_in[17]};
    const float* bng[2] = {(const float*)d_in[10], (const float*)d_in[18]};
    const float* bnb[2] = {(const float*)d_in[11], (const float*)d_in[19]};
    const float* headW  = (const float*)d_in[20];
    const float* headb  = (const float*)d_in[21];
    float* out = (float*)d_out;

    char* base = (char*)d_ws;
    size_t off = 0;
    auto alloc = [&](size_t bytes) -> void* {
        size_t o = (off + 255) & ~(size_t)255;
        off = o + bytes;
        return (void*)(base + o);
    };

    const int ZINTS = 2 * M_EDGES + 2 * N_NODES;
    const int ZTOT  = ZINTS + 4 * 2 * HID + NG * NCLS + NG;
    int* ibase  = (int*)alloc((size_t)ZTOT * 4);
    int* cnt_e  = ibase;
    int* cnt_n  = cnt_e + M_EDGES;
    int* cur_e  = cnt_n + N_NODES;
    int* cur_n  = cur_e + M_EDGES;
    float* statsall = (float*)(ibase + ZINTS);
    float* racc     = statsall + 4 * 2 * HID;
    float* rcnt     = racc + NG * NCLS;

    int* off_e  = (int*)alloc((M_EDGES + 1) * 4);
    int* off_n  = (int*)alloc((N_NODES + 1) * 4);
    int* idx_e  = (int*)alloc((size_t)NNZ_CNT * 4);
    int* idx_n  = (int*)alloc((size_t)NNZ_CNT * 4);
    float* dinv = (float*)alloc((size_t)N_NODES * 4);

    unsigned short* Xb = (unsigned short*)alloc((size_t)N_NODES * FT_DIM * 2);
    unsigned short* Eb = (unsigned short*)alloc((size_t)M_EDGES * HID * 2);
    unsigned short* Ph = (unsigned short*)alloc((size_t)N_NODES * HID * 2);
    unsigned short* Ahp = (unsigned short*)alloc((size_t)N_NODES * HID * 2);
    unsigned short* Hb  = (unsigned short*)alloc((size_t)N_NODES * HID * 2);
    float* T      = (float*)alloc((size_t)N_NODES * HID * 4);
    float* onodes = (float*)alloc((size_t)N_NODES * 16 * 4);
    float* zbuf   = (float*)alloc((size_t)M_EDGES * 16 * 4);
    unsigned short* Wp[4][2];
    int WK[4] = {FT_DIM, HID, HID, HID};
    for (int m = 0; m < 4; ++m) {
        Wp[m][0] = (unsigned short*)alloc((size_t)WK[m] * HID * 2);
        Wp[m][1] = (unsigned short*)alloc((size_t)WK[m] * HID * 2);
    }

    const int nnz_blocks = (NNZ_CNT + 255) / 256;
    const int n4 = N_NODES * HID / 4;
    const dim3 ggrid(N_NODES / 64, 2);

    // --- CSR build + degree norm + weight prep ---
    fzero<<<(ZTOT + 255) / 256, 256, 0, stream>>>((float*)ibase, ZTOT);
    count_kernel<<<nnz_blocks, 256, 0, stream>>>(node_idx, edge_idx, cnt_e, cnt_n);
    exscan2<<<2, 1024, 0, stream>>>(cnt_e, off_e, cnt_n, off_n);
    fill_kernel<<<nnz_blocks, 256, 0, stream>>>(node_idx, edge_idx, off_e, off_n,
                                                cur_e, cur_n, idx_e, idx_n);
    dinv_kernel<<<(N_NODES + 255) / 256, 256, 0, stream>>>(off_n, idx_n, cnt_e, dinv);
    WPA wpa;
    wpa.W[0] = W1[0]; wpa.W[1] = W2[0]; wpa.W[2] = W1[1]; wpa.W[3] = W2[1];
    for (int m = 0; m < 4; ++m) { wpa.h[m] = Wp[m][0]; wpa.l[m] = Wp[m][1]; }
    wprep_all<<<dim3(256, 4), 256, 0, stream>>>(wpa);
    fsplit<<<(N_NODES * FT_DIM / 4 + 255) / 256, 256, 0, stream>>>((const float4*)X,
                                                                   (u4v*)Xb, N_NODES * FT_DIM / 4);

    // ---------------- layer 0 ----------------
    gather_e128<<<M_EDGES / 4, 256, 0, stream>>>(off_e, idx_e, Xb, Eb);
    gather_n128_planes<<<N_NODES / 4, 256, 0, stream>>>(off_n, idx_n, Eb, Ph);
    gemm_lds<FT_DIM><<<ggrid, 256, 0, stream>>>(Ph, Wp[0][0], Wp[0][1], b1[0], T,
                                                statsall + 0 * 512);
    bn_split_blk<<<N_NODES / 64, 256, 0, stream>>>(T, statsall + 0 * 512, g1[0], be1[0], Ahp);
    gemm_lds<HID><<<ggrid, 256, 0, stream>>>(Ahp, Wp[1][0], Wp[1][1], b2[0], T,
                                             statsall + 1 * 512);
    bn_rowmajor<<<(n4 + 255) / 256, 256, 0, stream>>>((const float4*)T, statsall + 1 * 512,
                                                      bng[0], bnb[0], (u4v*)Hb, n4);
    // shared edge pass: Eb (layer-1 pooling) + z (layer-0 readout head)
    gather_e256_z<true><<<M_EDGES / 4, 256, 0, stream>>>(off_e, idx_e, Hb, Eb, headW, zbuf);
    gather_z<true><<<N_NODES / 64, 256, 0, stream>>>(off_n, idx_n, zbuf, dinv, headb, onodes);
    gather_n256_planes<<<N_NODES / 4, 256, 0, stream>>>(off_n, idx_n, Eb, Ph);

    // ---------------- layer 1 ----------------
    gemm_lds<HID><<<ggrid, 256, 0, stream>>>(Ph, Wp[2][0], Wp[2][1], b1[1], T,
                                             statsall + 2 * 512);
    bn_split_blk<<<N_NODES / 64, 256, 0, stream>>>(T, statsall + 2 * 512, g1[1], be1[1], Ahp);
    gemm_lds<HID><<<ggrid, 256, 0, stream>>>(Ahp, Wp[3][0], Wp[3][1], b2[1], T,
                                             statsall + 3 * 512);
    bn_rowmajor<<<(n4 + 255) / 256, 256, 0, stream>>>((const float4*)T, statsall + 3 * 512,
                                                      bng[1], bnb[1], (u4v*)Hb, n4);
    gather_e256_z<false><<<M_EDGES / 4, 256, 0, stream>>>(off_e, idx_e, Hb, nullptr,
                                                          headW + (size_t)HID * NCLS, zbuf);
    gather_z<false><<<N_NODES / 64, 256, 0, stream>>>(off_n, idx_n, zbuf, dinv, nullptr, onodes);

    // ---------------- readout ----------------
    readout_accum<<<(N_NODES + 255) / 256, 256, 0, stream>>>(onodes, all_batch, racc, rcnt);
    readout_final<<<(NG * NCLS + 255) / 256, 256, 0, stream>>>(racc, rcnt, out);
}

// Round 9
// 577.804 us; speedup vs baseline: 1.3767x; 1.0441x over previous
//
#include <hip/hip_runtime.h>

#define N_NODES 40000
#define M_PAD   40064          // 313 * 128
#define M_EDGES 10000
#define NNZ_CNT 400000
#define FT_DIM  128
#define HID     256
#define NCLS    10
#define NG      128
#define EPSV    1e-5f
#define ROWSINV (1.0f / 40000.0f)

typedef short s8v __attribute__((ext_vector_type(8)));
typedef unsigned short u8v __attribute__((ext_vector_type(8)));
typedef float f4v __attribute__((ext_vector_type(4)));
typedef unsigned short u4v __attribute__((ext_vector_type(4)));
typedef unsigned short u2v __attribute__((ext_vector_type(2)));

__device__ __forceinline__ unsigned short f2bf(float x) {
    unsigned int u = __float_as_uint(x);
    u += 0x7fffu + ((u >> 16) & 1u);
    return (unsigned short)(u >> 16);
}
__device__ __forceinline__ float bf2f(unsigned short h) {
    return __uint_as_float(((unsigned int)h) << 16);
}

// blocked-chunk element address (in shorts) for (r, k): layout [r/64][k/8][r%64] 16B chunks
__device__ __forceinline__ long ablk(int r, int k, int K) {
    return ((long)((r >> 6) * (K >> 3) + (k >> 3)) * 64 + (r & 63)) * 8 + (k & 7);
}

// ---------------- utility ----------------
__global__ void fzero(float* __restrict__ p, int n) {
    int i = blockIdx.x * 256 + threadIdx.x;
    if (i < n) p[i] = 0.f;
}

// ---------------- CSR build ----------------
__global__ void count_kernel(const int* __restrict__ ni, const int* __restrict__ ei,
                             int* __restrict__ cnt_e, int* __restrict__ cnt_n) {
    int i = blockIdx.x * 256 + threadIdx.x;
    if (i < NNZ_CNT) {
        atomicAdd(&cnt_e[ei[i]], 1);
        atomicAdd(&cnt_n[ni[i]], 1);
    }
}

__device__ void exscan_body(const int* __restrict__ in, int* __restrict__ out, int n) {
    __shared__ int wsum[16];
    __shared__ int carry_s;
    int tid = threadIdx.x, lane = tid & 63, w = tid >> 6;
    if (tid == 0) carry_s = 0;
    __syncthreads();
    for (int base = 0; base < n; base += 4096) {
        int i0 = base + tid * 4;
        int v[4];
#pragma unroll
        for (int t = 0; t < 4; ++t) v[t] = (i0 + t < n) ? in[i0 + t] : 0;
        int s = v[0] + v[1] + v[2] + v[3];
        int sc = s;
#pragma unroll
        for (int d = 1; d < 64; d <<= 1) {
            int t = __shfl_up(sc, d, 64);
            if (lane >= d) sc += t;
        }
        if (lane == 63) wsum[w] = sc;
        __syncthreads();
        if (tid < 64) {
            int ws = (lane < 16) ? wsum[lane] : 0;
            int wsc = ws;
#pragma unroll
            for (int d = 1; d < 16; d <<= 1) {
                int t = __shfl_up(wsc, d, 64);
                if (lane >= d) wsc += t;
            }
            if (lane < 16) wsum[lane] = wsc - ws;
        }
        __syncthreads();
        int carry = carry_s;
        int ex = carry + wsum[w] + (sc - s);
#pragma unroll
        for (int t = 0; t < 4; ++t) {
            if (i0 + t < n) out[i0 + t] = ex;
            ex += v[t];
        }
        __syncthreads();
        if (tid == 1023) carry_s = ex;
    }
    __syncthreads();
    if (tid == 0) out[n] = carry_s;
}

__global__ __launch_bounds__(1024) void exscan2(const int* __restrict__ ce, int* __restrict__ oe,
                                                const int* __restrict__ cn, int* __restrict__ on_) {
    if (blockIdx.x == 0) exscan_body(ce, oe, M_EDGES);
    else exscan_body(cn, on_, N_NODES);
}

__global__ void fill_kernel(const int* __restrict__ ni, const int* __restrict__ ei,
                            const int* __restrict__ off_e, const int* __restrict__ off_n,
                            int* __restrict__ cur_e, int* __restrict__ cur_n,
                            int* __restrict__ idx_e, int* __restrict__ idx_n) {
    int i = blockIdx.x * 256 + threadIdx.x;
    if (i < NNZ_CNT) {
        int e = ei[i], n = ni[i];
        int pe = atomicAdd(&cur_e[e], 1);
        idx_e[off_e[e] + pe] = n;
        int pn = atomicAdd(&cur_n[n], 1);
        idx_n[off_n[n] + pn] = e;
    }
}

__global__ void dinv_kernel(const int* __restrict__ off_n, const int* __restrict__ idx_n,
                            const int* __restrict__ cnt_e, float* __restrict__ dinv) {
    int n = blockIdx.x * 256 + threadIdx.x;
    if (n < N_NODES) {
        int s = off_n[n], e = off_n[n + 1];
        float p = 0.f;
        for (int j = s; j < e; ++j) p += (float)cnt_e[idx_n[j]];
        dinv[n] = (p > 0.f) ? 1.0f / p : 1.0f;
    }
}

// -------- weight prep (all 4 mats): W[K x 256] fp32 -> blocked hi/lo planes --------
struct WPA {
    const float* W[4];
    unsigned short* h[4];
    unsigned short* l[4];
};
__global__ void wprep_all(WPA p) {
    int m = blockIdx.y;
    int K = (m == 0) ? FT_DIM : HID;
    int i = blockIdx.x * 256 + threadIdx.x;
    if (i >= K * 256) return;
    int k = i >> 8, c = i & 255;
    float x = p.W[m][i];
    unsigned short hh = f2bf(x);
    long o = ((long)((c >> 6) * (K >> 3) + (k >> 3)) * 64 + (c & 63)) * 8 + (k & 7);
    p.h[m][o] = hh;
    p.l[m][o] = f2bf(x - bf2f(hh));
}

// ---------------- fp32 -> bf16 (round only, row-major) ----------------
__global__ void fsplit(const float4* __restrict__ src, u4v* __restrict__ h, int n4) {
    int i = blockIdx.x * 256 + threadIdx.x;
    if (i < n4) {
        float4 v = src[i];
        h[i] = (u4v){f2bf(v.x), f2bf(v.y), f2bf(v.z), f2bf(v.w)};
    }
}

// -------- relu(bn(x)) -> blocked single bf16 plane, BN finalize fused (K=256) --------
__global__ __launch_bounds__(256) void bn_split_blk(const float* __restrict__ src,
        const float* __restrict__ stats, const float* __restrict__ g,
        const float* __restrict__ be, unsigned short* __restrict__ hOut) {
    __shared__ float sa[HID], sc_[HID];
    int tid = threadIdx.x;
    {
        float mean = stats[tid] * ROWSINV;
        float var = stats[HID + tid] * ROWSINV - mean * mean;
        float av = g[tid] * rsqrtf(var + EPSV);
        sa[tid] = av;
        sc_[tid] = be[tid] - mean * av;
    }
    __syncthreads();
    int r = tid >> 2, kqg = tid & 3;
    long row = (long)blockIdx.x * 64 + r;
    long cbase = ((long)blockIdx.x * 32) * 64 + r;
#pragma unroll
    for (int t = 0; t < 8; ++t) {
        int kq = kqg * 8 + t;
        const float* sp = src + row * HID + kq * 8;
        float4 v0 = *(const float4*)sp;
        float4 v1 = *(const float4*)(sp + 4);
        float4 a0 = *(const float4*)(sa + kq * 8);
        float4 a1 = *(const float4*)(sa + kq * 8 + 4);
        float4 c0 = *(const float4*)(sc_ + kq * 8);
        float4 c1 = *(const float4*)(sc_ + kq * 8 + 4);
        s8v h;
        h[0] = (short)f2bf(fmaxf(fmaf(a0.x, v0.x, c0.x), 0.f));
        h[1] = (short)f2bf(fmaxf(fmaf(a0.y, v0.y, c0.y), 0.f));
        h[2] = (short)f2bf(fmaxf(fmaf(a0.z, v0.z, c0.z), 0.f));
        h[3] = (short)f2bf(fmaxf(fmaf(a0.w, v0.w, c0.w), 0.f));
        h[4] = (short)f2bf(fmaxf(fmaf(a1.x, v1.x, c1.x), 0.f));
        h[5] = (short)f2bf(fmaxf(fmaf(a1.y, v1.y, c1.y), 0.f));
        h[6] = (short)f2bf(fmaxf(fmaf(a1.z, v1.z, c1.z), 0.f));
        h[7] = (short)f2bf(fmaxf(fmaf(a1.w, v1.w, c1.w), 0.f));
        *(s8v*)(hOut + (cbase + (long)kq * 64) * 8) = h;
    }
}

// -------- relu(bn(x)) -> row-major bf16, BN finalize fused --------
__global__ __launch_bounds__(256) void bn_rowmajor(const float4* __restrict__ src,
        const float* __restrict__ stats, const float* __restrict__ g,
        const float* __restrict__ be, u4v* __restrict__ hOut, int n4) {
    __shared__ float sa[HID], sc_[HID];
    int tid = threadIdx.x;
    {
        float mean = stats[tid] * ROWSINV;
        float var = stats[HID + tid] * ROWSINV - mean * mean;
        float av = g[tid] * rsqrtf(var + EPSV);
        sa[tid] = av;
        sc_[tid] = be[tid] - mean * av;
    }
    __syncthreads();
    int i = blockIdx.x * 256 + tid;
    if (i >= n4) return;
    int col = (i << 2) & (HID - 1);
    float4 av = *(const float4*)(sa + col);
    float4 cv = *(const float4*)(sc_ + col);
    float4 v = src[i];
    float x0 = fmaxf(fmaf(av.x, v.x, cv.x), 0.f);
    float x1 = fmaxf(fmaf(av.y, v.y, cv.y), 0.f);
    float x2 = fmaxf(fmaf(av.z, v.z, cv.z), 0.f);
    float x3 = fmaxf(fmaf(av.w, v.w, cv.w), 0.f);
    hOut[i] = (u4v){f2bf(x0), f2bf(x1), f2bf(x2), f2bf(x3)};
}

// ---------------- gathers ----------------
// edge gather d=128 (avg degree 40): 8 independent chains, 4B/lane, scalar idx
__global__ __launch_bounds__(256) void gather_e128(const int* __restrict__ off,
        const int* __restrict__ idx, const unsigned short* __restrict__ Y,
        unsigned short* __restrict__ outh) {
    int lane = threadIdx.x & 63;
    int r = blockIdx.x * 4 + (threadIdx.x >> 6);
    int f0 = lane * 2;
    int s = off[r], e = off[r + 1];
    float a[8][2] = {};
    int j = s;
    for (; j + 8 <= e; j += 8) {
#pragma unroll
        for (int u = 0; u < 8; ++u) {
            int iv = __builtin_amdgcn_readfirstlane(idx[j + u]);
            u2v g = *(const u2v*)(Y + (long)iv * FT_DIM + f0);
            a[u][0] += bf2f(g[0]);
            a[u][1] += bf2f(g[1]);
        }
    }
    for (; j < e; ++j) {
        int iv = __builtin_amdgcn_readfirstlane(idx[j]);
        u2v g = *(const u2v*)(Y + (long)iv * FT_DIM + f0);
        a[0][0] += bf2f(g[0]);
        a[0][1] += bf2f(g[1]);
    }
    float s0 = 0.f, s1 = 0.f;
#pragma unroll
    for (int u = 0; u < 8; ++u) { s0 += a[u][0]; s1 += a[u][1]; }
    *(u2v*)(outh + (long)r * FT_DIM + f0) = (u2v){f2bf(s0), f2bf(s1)};
}

// node gather d=128 (avg degree 10): 4 chains, writes blocked single plane
__global__ __launch_bounds__(256) void gather_n128_planes(const int* __restrict__ off,
        const int* __restrict__ idx, const unsigned short* __restrict__ Y,
        unsigned short* __restrict__ Ph) {
    int lane = threadIdx.x & 63;
    int r = blockIdx.x * 4 + (threadIdx.x >> 6);
    int f0 = lane * 2;
    int s = off[r], e = off[r + 1];
    float a[4][2] = {};
    int j = s;
    for (; j + 4 <= e; j += 4) {
#pragma unroll
        for (int u = 0; u < 4; ++u) {
            int iv = __builtin_amdgcn_readfirstlane(idx[j + u]);
            u2v g = *(const u2v*)(Y + (long)iv * FT_DIM + f0);
            a[u][0] += bf2f(g[0]);
            a[u][1] += bf2f(g[1]);
        }
    }
    for (; j < e; ++j) {
        int iv = __builtin_amdgcn_readfirstlane(idx[j]);
        u2v g = *(const u2v*)(Y + (long)iv * FT_DIM + f0);
        a[0][0] += bf2f(g[0]);
        a[0][1] += bf2f(g[1]);
    }
    float s0 = a[0][0] + a[1][0] + a[2][0] + a[3][0];
    float s1 = a[0][1] + a[1][1] + a[2][1] + a[3][1];
    *(u2v*)(Ph + ablk(r, f0, FT_DIM)) = (u2v){f2bf(s0), f2bf(s1)};
}

// edge gather d=256: 16B/lane, half-wave = one row; halves take even/odd edges of the
// SAME list (idx stays scalar: 2x readfirstlane + cndmask). 8 loads = 16 edges per iter.
// Epilogue: z[e] = rowsum . Wh; optionally writes Eb.
template<bool WRITE_EB>
__global__ __launch_bounds__(256) void gather_e256_z(const int* __restrict__ off,
        const int* __restrict__ idx, const unsigned short* __restrict__ Y,
        unsigned short* __restrict__ Eb, const float* __restrict__ Wh,
        float* __restrict__ z) {
    int lane = threadIdx.x & 63;
    int r = blockIdx.x * 4 + (threadIdx.x >> 6);
    int hh = lane >> 5;
    int f0 = (lane & 31) * 8;
    int s = off[r], e = off[r + 1];
    float A[4][8] = {};
    int j = s;
    for (; j + 16 <= e; j += 16) {
        u8v g[8];
#pragma unroll
        for (int u = 0; u < 8; ++u) {
            int i0 = __builtin_amdgcn_readfirstlane(idx[j + 2 * u]);
            int i1 = __builtin_amdgcn_readfirstlane(idx[j + 2 * u + 1]);
            int iv = hh ? i1 : i0;
            g[u] = *(const u8v*)(Y + (long)iv * HID + f0);
        }
#pragma unroll
        for (int u = 0; u < 8; ++u)
#pragma unroll
            for (int v = 0; v < 8; ++v) A[u & 3][v] += bf2f(g[u][v]);
    }
    for (; j < e; j += 2) {
        int has1 = (j + 1 < e);
        int i0 = __builtin_amdgcn_readfirstlane(idx[j]);
        int i1 = __builtin_amdgcn_readfirstlane(idx[has1 ? j + 1 : j]);
        int iv = hh ? i1 : i0;
        u8v g = *(const u8v*)(Y + (long)iv * HID + f0);
        if (!hh || has1) {
#pragma unroll
            for (int v = 0; v < 8; ++v) A[0][v] += bf2f(g[v]);
        }
    }
    float sum[8];
#pragma unroll
    for (int v = 0; v < 8; ++v) {
        sum[v] = A[0][v] + A[1][v] + A[2][v] + A[3][v];
        sum[v] += __shfl_xor(sum[v], 32, 64);
    }
    if (WRITE_EB && hh == 0) {
        u8v o;
#pragma unroll
        for (int v = 0; v < 8; ++v) o[v] = f2bf(sum[v]);
        *(u8v*)(Eb + (long)r * HID + f0) = o;
    }
    const float* wp = Wh + (long)f0 * NCLS;
    float p[NCLS];
#pragma unroll
    for (int c = 0; c < NCLS; ++c) {
        float acc = 0.f;
#pragma unroll
        for (int v = 0; v < 8; ++v) acc += sum[v] * wp[v * NCLS + c];
        p[c] = acc;
    }
#pragma unroll
    for (int c = 0; c < NCLS; ++c) {
#pragma unroll
        for (int m = 1; m < 32; m <<= 1) p[c] += __shfl_xor(p[c], m, 64);
    }
    if (lane == 0) {
        float* zp = z + (long)r * 16;
        *(float4*)(zp)      = (float4){p[0], p[1], p[2], p[3]};
        *(float4*)(zp + 4)  = (float4){p[4], p[5], p[6], p[7]};
        *(float4*)(zp + 8)  = (float4){p[8], p[9], 0.f, 0.f};
        *(float4*)(zp + 12) = (float4){0.f, 0.f, 0.f, 0.f};
    }
}

// node gather d=256 (avg degree 10): 16B/lane half-pair, writes blocked single plane
__global__ __launch_bounds__(256) void gather_n256_planes(const int* __restrict__ off,
        const int* __restrict__ idx, const unsigned short* __restrict__ Y,
        unsigned short* __restrict__ Ph) {
    int lane = threadIdx.x & 63;
    int r = blockIdx.x * 4 + (threadIdx.x >> 6);
    int hh = lane >> 5;
    int f0 = (lane & 31) * 8;
    int s = off[r], e = off[r + 1];
    float A[2][8] = {};
    int j = s;
    for (; j + 8 <= e; j += 8) {
        u8v g[4];
#pragma unroll
        for (int u = 0; u < 4; ++u) {
            int i0 = __builtin_amdgcn_readfirstlane(idx[j + 2 * u]);
            int i1 = __builtin_amdgcn_readfirstlane(idx[j + 2 * u + 1]);
            int iv = hh ? i1 : i0;
            g[u] = *(const u8v*)(Y + (long)iv * HID + f0);
        }
#pragma unroll
        for (int u = 0; u < 4; ++u)
#pragma unroll
            for (int v = 0; v < 8; ++v) A[u & 1][v] += bf2f(g[u][v]);
    }
    for (; j < e; j += 2) {
        int has1 = (j + 1 < e);
        int i0 = __builtin_amdgcn_readfirstlane(idx[j]);
        int i1 = __builtin_amdgcn_readfirstlane(idx[has1 ? j + 1 : j]);
        int iv = hh ? i1 : i0;
        u8v g = *(const u8v*)(Y + (long)iv * HID + f0);
        if (!hh || has1) {
#pragma unroll
            for (int v = 0; v < 8; ++v) A[0][v] += bf2f(g[v]);
        }
    }
    s8v o;
#pragma unroll
    for (int v = 0; v < 8; ++v) {
        float sum = A[0][v] + A[1][v];
        sum += __shfl_xor(sum, 32, 64);
        o[v] = (short)f2bf(sum);
    }
    if (hh == 0) *(s8v*)(Ph + ablk(r, f0, HID)) = o;
}

// node readout over z rows (64B each): 4 threads per node, float4 per thread.
template<bool FIRST>
__global__ __launch_bounds__(256) void gather_z(const int* __restrict__ off,
        const int* __restrict__ idx, const float* __restrict__ z,
        const float* __restrict__ dinv, const float* __restrict__ hb,
        float* __restrict__ on) {
    int tid = threadIdx.x;
    int t = tid & 3;
    int n = blockIdx.x * 64 + (tid >> 2);
    int s = off[n], e = off[n + 1];
    float4 a0 = {0,0,0,0}, a1 = {0,0,0,0}, a2 = {0,0,0,0}, a3 = {0,0,0,0};
    int j = s;
    for (; j + 4 <= e; j += 4) {
        float4 g0 = *(const float4*)(z + (long)idx[j] * 16 + t * 4);
        float4 g1 = *(const float4*)(z + (long)idx[j + 1] * 16 + t * 4);
        float4 g2 = *(const float4*)(z + (long)idx[j + 2] * 16 + t * 4);
        float4 g3 = *(const float4*)(z + (long)idx[j + 3] * 16 + t * 4);
        a0.x += g0.x; a0.y += g0.y; a0.z += g0.z; a0.w += g0.w;
        a1.x += g1.x; a1.y += g1.y; a1.z += g1.z; a1.w += g1.w;
        a2.x += g2.x; a2.y += g2.y; a2.z += g2.z; a2.w += g2.w;
        a3.x += g3.x; a3.y += g3.y; a3.z += g3.z; a3.w += g3.w;
    }
    for (; j < e; ++j) {
        float4 g0 = *(const float4*)(z + (long)idx[j] * 16 + t * 4);
        a0.x += g0.x; a0.y += g0.y; a0.z += g0.z; a0.w += g0.w;
    }
    float di = dinv[n];
    float4 acc;
    acc.x = (a0.x + a1.x + a2.x + a3.x) * di;
    acc.y = (a0.y + a1.y + a2.y + a3.y) * di;
    acc.z = (a0.z + a1.z + a2.z + a3.z) * di;
    acc.w = (a0.w + a1.w + a2.w + a3.w) * di;
    float* op = on + (long)n * 16 + t * 4;
    if (FIRST) {
        float4 b;
#pragma unroll
        for (int k = 0; k < 4; ++k) {
            int c = t * 4 + k;
            ((float*)&b)[k] = (c < NCLS) ? hb[c] : 0.f;
        }
        *(float4*)op = (float4){acc.x + b.x, acc.y + b.y, acc.z + b.z, acc.w + b.w};
    } else {
        float4 old = *(float4*)op;
        *(float4*)op = (float4){old.x + acc.x, old.y + acc.y, old.z + acc.z, old.w + acc.w};
    }
}

// ---------------- single-A-plane MFMA GEMM, 128x128 tile ----------------
// A plane blocked [rowblk][kq][r], B planes blocked [colblk][kq][c] (16B chunks).
// Grid (313, 2); M padded to 40064: rows >= 40000 masked from stores & stats.
// LDS 48 KB (A 16K + B 32K; stats aliased onto Asl) -> 3 blocks/CU.
// Wave w: rows w*32..w*32+31 x all 128 cols; 64 MFMA per wave per barrier.
template<int K>
__global__ __launch_bounds__(256) void gemm128(const unsigned short* __restrict__ Ahg,
        const unsigned short* __restrict__ Bhg, const unsigned short* __restrict__ Blg,
        const float* __restrict__ bias, float* __restrict__ C, float* __restrict__ stats) {
    constexpr int KQ = K >> 3;
    __shared__ __align__(16) unsigned short Asl[16 * 512];   // 16 KB
    __shared__ __align__(16) unsigned short Bsl[32 * 512];   // 32 KB
    float* lsum = (float*)Asl;
    float* lsq  = lsum + 128;
    int tid = threadIdx.x;
    int lane = tid & 63, w = tid >> 6;
    int bx = blockIdx.x;
    int col0 = blockIdx.y * 128;
    int colblk0 = blockIdx.y * 2;
    int lm = lane & 15, lq = lane >> 4;
    int rbw = w >> 1;                 // 64-row sub-block
    int rw = (w & 1) * 32;            // offset within sub-block
    f4v acc[2][8];
#pragma unroll
    for (int i = 0; i < 2; ++i)
#pragma unroll
        for (int j = 0; j < 8; ++j) acc[i][j] = (f4v){0.f, 0.f, 0.f, 0.f};

    for (int ks = 0; ks < K / 64; ++ks) {
        int kq0 = ks * 8;
        // A: 16 regions (rb*8+kqo), 4 instr/wave
#pragma unroll
        for (int t = 0; t < 4; ++t) {
            int a = w * 4 + t;
            int rb = a >> 3, kqo = a & 7;
            const unsigned short* g = Ahg
                + ((long)((bx * 2 + rb) * KQ + kq0 + kqo) * 64 + lane) * 8;
            __builtin_amdgcn_global_load_lds(
                (const __attribute__((address_space(1))) void*)g,
                (__attribute__((address_space(3))) void*)(Asl + a * 512), 16, 0, 0);
        }
        // B: 32 regions (plane*16 + cb*8 + kqo), 8 instr/wave
#pragma unroll
        for (int u = 0; u < 8; ++u) {
            int b = w * 8 + u;
            const unsigned short* g = ((b >> 4) ? Blg : Bhg)
                + ((long)((colblk0 + ((b >> 3) & 1)) * KQ + kq0 + (b & 7)) * 64 + lane) * 8;
            __builtin_amdgcn_global_load_lds(
                (const __attribute__((address_space(1))) void*)g,
                (__attribute__((address_space(3))) void*)(Bsl + b * 512), 16, 0, 0);
        }
        __syncthreads();
#pragma unroll
        for (int kk = 0; kk < 2; ++kk) {
            s8v ah[2];
#pragma unroll
            for (int i = 0; i < 2; ++i)
                ah[i] = *(const s8v*)&Asl[(rbw * 8 + kk * 4 + lq) * 512
                                          + (rw + i * 16 + lm) * 8];
#pragma unroll
            for (int j = 0; j < 8; ++j) {
                int cb = j >> 2;
                int c64 = (j & 3) * 16 + lm;
                s8v bh = *(const s8v*)&Bsl[(cb * 8 + kk * 4 + lq) * 512 + c64 * 8];
                s8v bl = *(const s8v*)&Bsl[(16 + cb * 8 + kk * 4 + lq) * 512 + c64 * 8];
#pragma unroll
                for (int i = 0; i < 2; ++i) {
                    acc[i][j] = __builtin_amdgcn_mfma_f32_16x16x32_bf16(ah[i], bl, acc[i][j], 0, 0, 0);
                    acc[i][j] = __builtin_amdgcn_mfma_f32_16x16x32_bf16(ah[i], bh, acc[i][j], 0, 0, 0);
                }
            }
        }
        __syncthreads();
    }
    // ---- epilogue: aliased stats LDS, masked store + column stats ----
    if (tid < 128) { lsum[tid] = 0.f; lsq[tid] = 0.f; }
    __syncthreads();
#pragma unroll
    for (int j = 0; j < 8; ++j) {
        int lc = j * 16 + lm;
        int col = col0 + lc;
        float bsv = bias[col];
        float s = 0.f, sq = 0.f;
#pragma unroll
        for (int i = 0; i < 2; ++i) {
#pragma unroll
            for (int reg = 0; reg < 4; ++reg) {
                long row = (long)bx * 128 + rbw * 64 + rw + i * 16 + lq * 4 + reg;
                if (row < N_NODES) {
                    float v = acc[i][j][reg] + bsv;
                    C[row * HID + col] = v;
                    s += v;
                    sq += v * v;
                }
            }
        }
        atomicAdd(&lsum[lc], s);
        atomicAdd(&lsq[lc], sq);
    }
    __syncthreads();
    if (tid < 128) {
        atomicAdd(&stats[col0 + tid], lsum[tid]);
        atomicAdd(&stats[HID + col0 + tid], lsq[tid]);
    }
}

// ---------------- readout (onodes stride 16) ----------------
__global__ __launch_bounds__(256) void readout_accum(const float* __restrict__ on,
                                                     const int* __restrict__ ab,
                                                     float* __restrict__ racc,
                                                     float* __restrict__ rcnt) {
    __shared__ float lacc[NG * NCLS];
    __shared__ float lcnt[NG];
    int tid = threadIdx.x;
    for (int i = tid; i < NG * NCLS; i += 256) lacc[i] = 0.f;
    if (tid < NG) lcnt[tid] = 0.f;
    __syncthreads();
    int n = blockIdx.x * 256 + tid;
    if (n < N_NODES) {
        int b = ab[n];
        atomicAdd(&lcnt[b], 1.0f);
        for (int c = 0; c < NCLS; ++c) atomicAdd(&lacc[b * NCLS + c], on[(long)n * 16 + c]);
    }
    __syncthreads();
    if (tid < NG && lcnt[tid] > 0.f) {
        atomicAdd(&rcnt[tid], lcnt[tid]);
        for (int c = 0; c < NCLS; ++c) atomicAdd(&racc[tid * NCLS + c], lacc[tid * NCLS + c]);
    }
}

__global__ void readout_final(const float* __restrict__ racc, const float* __restrict__ rcnt,
                              float* __restrict__ out) {
    int i = blockIdx.x * 256 + threadIdx.x;
    if (i < NG * NCLS) out[i] = racc[i] / fmaxf(rcnt[i / NCLS], 1.0f);
}

// ---------------- launch ----------------
extern "C" void kernel_launch(void* const* d_in, const int* in_sizes, int n_in,
                              void* d_out, int out_size, void* d_ws, size_t ws_size,
                              hipStream_t stream) {
    const float* X         = (const float*)d_in[0];
    const int*   node_idx  = (const int*)d_in[1];
    const int*   edge_idx  = (const int*)d_in[2];
    const int*   all_batch = (const int*)d_in[3];
    const float* W1[2]  = {(const float*)d_in[4],  (const float*)d_in[12]};
    const float* b1[2]  = {(const float*)d_in[5],  (const float*)d_in[13]};
    const float* g1[2]  = {(const float*)d_in[6],  (const float*)d_in[14]};
    const float* be1[2] = {(const float*)d_in[7],  (const float*)d_in[15]};
    const float* W2[2]  = {(const float*)d_in[8],  (const float*)d_in[16]};
    const float* b2[2]  = {(const float*)d_in[9],  (const float*)d_in[17]};
    const float* bng[2] = {(const float*)d_in[10], (const float*)d_in[18]};
    const float* bnb[2] = {(const float*)d_in[11], (const float*)d_in[19]};
    const float* headW  = (const float*)d_in[20];
    const float* headb  = (const float*)d_in[21];
    float* out = (float*)d_out;

    char* base = (char*)d_ws;
    size_t off = 0;
    auto alloc = [&](size_t bytes) -> void* {
        size_t o = (off + 255) & ~(size_t)255;
        off = o + bytes;
        return (void*)(base + o);
    };

    const int ZINTS = 2 * M_EDGES + 2 * N_NODES;
    const int ZTOT  = ZINTS + 4 * 2 * HID + NG * NCLS + NG;
    int* ibase  = (int*)alloc((size_t)ZTOT * 4);
    int* cnt_e  = ibase;
    int* cnt_n  = cnt_e + M_EDGES;
    int* cur_e  = cnt_n + N_NODES;
    int* cur_n  = cur_e + M_EDGES;
    float* statsall = (float*)(ibase + ZINTS);
    float* racc     = statsall + 4 * 2 * HID;
    float* rcnt     = racc + NG * NCLS;

    int* off_e  = (int*)alloc((M_EDGES + 1) * 4);
    int* off_n  = (int*)alloc((N_NODES + 1) * 4);
    int* idx_e  = (int*)alloc((size_t)NNZ_CNT * 4);
    int* idx_n  = (int*)alloc((size_t)NNZ_CNT * 4);
    float* dinv = (float*)alloc((size_t)N_NODES * 4);

    unsigned short* Xb = (unsigned short*)alloc((size_t)N_NODES * FT_DIM * 2);
    unsigned short* Eb = (unsigned short*)alloc((size_t)M_EDGES * HID * 2);
    unsigned short* Ph = (unsigned short*)alloc((size_t)M_PAD * HID * 2);   // padded
    unsigned short* Ahp = (unsigned short*)alloc((size_t)M_PAD * HID * 2);  // padded
    unsigned short* Hb  = (unsigned short*)alloc((size_t)N_NODES * HID * 2);
    float* T      = (float*)alloc((size_t)N_NODES * HID * 4);
    float* onodes = (float*)alloc((size_t)N_NODES * 16 * 4);
    float* zbuf   = (float*)alloc((size_t)M_EDGES * 16 * 4);
    unsigned short* Wp[4][2];
    int WK[4] = {FT_DIM, HID, HID, HID};
    for (int m = 0; m < 4; ++m) {
        Wp[m][0] = (unsigned short*)alloc((size_t)WK[m] * HID * 2);
        Wp[m][1] = (unsigned short*)alloc((size_t)WK[m] * HID * 2);
    }

    const int nnz_blocks = (NNZ_CNT + 255) / 256;
    const int n4 = N_NODES * HID / 4;
    const dim3 ggrid(M_PAD / 128, 2);

    // --- CSR build + degree norm + weight prep ---
    fzero<<<(ZTOT + 255) / 256, 256, 0, stream>>>((float*)ibase, ZTOT);
    count_kernel<<<nnz_blocks, 256, 0, stream>>>(node_idx, edge_idx, cnt_e, cnt_n);
    exscan2<<<2, 1024, 0, stream>>>(cnt_e, off_e, cnt_n, off_n);
    fill_kernel<<<nnz_blocks, 256, 0, stream>>>(node_idx, edge_idx, off_e, off_n,
                                                cur_e, cur_n, idx_e, idx_n);
    dinv_kernel<<<(N_NODES + 255) / 256, 256, 0, stream>>>(off_n, idx_n, cnt_e, dinv);
    WPA wpa;
    wpa.W[0] = W1[0]; wpa.W[1] = W2[0]; wpa.W[2] = W1[1]; wpa.W[3] = W2[1];
    for (int m = 0; m < 4; ++m) { wpa.h[m] = Wp[m][0]; wpa.l[m] = Wp[m][1]; }
    wprep_all<<<dim3(256, 4), 256, 0, stream>>>(wpa);
    fsplit<<<(N_NODES * FT_DIM / 4 + 255) / 256, 256, 0, stream>>>((const float4*)X,
                                                                   (u4v*)Xb, N_NODES * FT_DIM / 4);

    // ---------------- layer 0 ----------------
    gather_e128<<<M_EDGES / 4, 256, 0, stream>>>(off_e, idx_e, Xb, Eb);
    gather_n128_planes<<<N_NODES / 4, 256, 0, stream>>>(off_n, idx_n, Eb, Ph);
    gemm128<FT_DIM><<<ggrid, 256, 0, stream>>>(Ph, Wp[0][0], Wp[0][1], b1[0], T,
                                               statsall + 0 * 512);
    bn_split_blk<<<N_NODES / 64, 256, 0, stream>>>(T, statsall + 0 * 512, g1[0], be1[0], Ahp);
    gemm128<HID><<<ggrid, 256, 0, stream>>>(Ahp, Wp[1][0], Wp[1][1], b2[0], T,
                                            statsall + 1 * 512);
    bn_rowmajor<<<(n4 + 255) / 256, 256, 0, stream>>>((const float4*)T, statsall + 1 * 512,
                                                      bng[0], bnb[0], (u4v*)Hb, n4);
    // shared edge pass: Eb (layer-1 pooling) + z (layer-0 readout head)
    gather_e256_z<true><<<M_EDGES / 4, 256, 0, stream>>>(off_e, idx_e, Hb, Eb, headW, zbuf);
    gather_z<true><<<N_NODES / 64, 256, 0, stream>>>(off_n, idx_n, zbuf, dinv, headb, onodes);
    gather_n256_planes<<<N_NODES / 4, 256, 0, stream>>>(off_n, idx_n, Eb, Ph);

    // ---------------- layer 1 ----------------
    gemm128<HID><<<ggrid, 256, 0, stream>>>(Ph, Wp[2][0], Wp[2][1], b1[1], T,
                                            statsall + 2 * 512);
    bn_split_blk<<<N_NODES / 64, 256, 0, stream>>>(T, statsall + 2 * 512, g1[1], be1[1], Ahp);
    gemm128<HID><<<ggrid, 256, 0, stream>>>(Ahp, Wp[3][0], Wp[3][1], b2[1], T,
                                            statsall + 3 * 512);
    bn_rowmajor<<<(n4 + 255) / 256, 256, 0, stream>>>((const float4*)T, statsall + 3 * 512,
                                                      bng[1], bnb[1], (u4v*)Hb, n4);
    gather_e256_z<false><<<M_EDGES / 4, 256, 0, stream>>>(off_e, idx_e, Hb, nullptr,
                                                          headW + (size_t)HID * NCLS, zbuf);
    gather_z<false><<<N_NODES / 64, 256, 0, stream>>>(off_n, idx_n, zbuf, dinv, nullptr, onodes);

    // ---------------- readout ----------------
    readout_accum<<<(N_NODES + 255) / 256, 256, 0, stream>>>(onodes, all_batch, racc, rcnt);
    readout_final<<<(NG * NCLS + 255) / 256, 256, 0, stream>>>(racc, rcnt, out);
}

// Round 10
// 567.272 us; speedup vs baseline: 1.4023x; 1.0186x over previous
//
#include <hip/hip_runtime.h>

#define N_NODES 40000
#define M_PAD   40064          // 313 * 128
#define M_EDGES 10000
#define NNZ_CNT 400000
#define FT_DIM  128
#define HID     256
#define NCLS    10
#define NG      128
#define EPSV    1e-5f
#define ROWSINV (1.0f / 40000.0f)

#define NBE 79    // edge buckets: key >> 7 (128 keys each)
#define NBN 157   // node buckets: key >> 8 (256 keys each)

typedef short s8v __attribute__((ext_vector_type(8)));
typedef unsigned short u8v __attribute__((ext_vector_type(8)));
typedef float f4v __attribute__((ext_vector_type(4)));
typedef unsigned short u4v __attribute__((ext_vector_type(4)));
typedef unsigned short u2v __attribute__((ext_vector_type(2)));

__device__ __forceinline__ unsigned short f2bf(float x) {
    unsigned int u = __float_as_uint(x);
    u += 0x7fffu + ((u >> 16) & 1u);
    return (unsigned short)(u >> 16);
}
__device__ __forceinline__ float bf2f(unsigned short h) {
    return __uint_as_float(((unsigned int)h) << 16);
}

// blocked-chunk element address (in shorts) for (r, k): layout [r/64][k/8][r%64] 16B chunks
__device__ __forceinline__ long ablk(int r, int k, int K) {
    return ((long)((r >> 6) * (K >> 3) + (k >> 3)) * 64 + (r & 63)) * 8 + (k & 7);
}

// ---------------- utility ----------------
__global__ void fzero(float* __restrict__ p, int n) {
    int i = blockIdx.x * 256 + threadIdx.x;
    if (i < n) p[i] = 0.f;
}

// ---------------- CSR build ----------------
__global__ void count_kernel(const int* __restrict__ ni, const int* __restrict__ ei,
                             int* __restrict__ cnt_e, int* __restrict__ cnt_n) {
    int i = blockIdx.x * 256 + threadIdx.x;
    if (i < NNZ_CNT) {
        atomicAdd(&cnt_e[ei[i]], 1);
        atomicAdd(&cnt_n[ni[i]], 1);
    }
}

__device__ void exscan_body(const int* __restrict__ in, int* __restrict__ out, int n) {
    __shared__ int wsum[16];
    __shared__ int carry_s;
    int tid = threadIdx.x, lane = tid & 63, w = tid >> 6;
    if (tid == 0) carry_s = 0;
    __syncthreads();
    for (int base = 0; base < n; base += 4096) {
        int i0 = base + tid * 4;
        int v[4];
#pragma unroll
        for (int t = 0; t < 4; ++t) v[t] = (i0 + t < n) ? in[i0 + t] : 0;
        int s = v[0] + v[1] + v[2] + v[3];
        int sc = s;
#pragma unroll
        for (int d = 1; d < 64; d <<= 1) {
            int t = __shfl_up(sc, d, 64);
            if (lane >= d) sc += t;
        }
        if (lane == 63) wsum[w] = sc;
        __syncthreads();
        if (tid < 64) {
            int ws = (lane < 16) ? wsum[lane] : 0;
            int wsc = ws;
#pragma unroll
            for (int d = 1; d < 16; d <<= 1) {
                int t = __shfl_up(wsc, d, 64);
                if (lane >= d) wsc += t;
            }
            if (lane < 16) wsum[lane] = wsc - ws;
        }
        __syncthreads();
        int carry = carry_s;
        int ex = carry + wsum[w] + (sc - s);
#pragma unroll
        for (int t = 0; t < 4; ++t) {
            if (i0 + t < n) out[i0 + t] = ex;
            ex += v[t];
        }
        __syncthreads();
        if (tid == 1023) carry_s = ex;
    }
    __syncthreads();
    if (tid == 0) out[n] = carry_s;
}

// scans both counts AND initializes the per-bucket global cursors (gcur = off[bucket_k0])
__global__ __launch_bounds__(1024) void exscan2(const int* __restrict__ ce, int* __restrict__ oe,
                                                const int* __restrict__ cn, int* __restrict__ on_,
                                                int* __restrict__ gcur_e, int* __restrict__ gcur_n) {
    int tid = threadIdx.x;
    if (blockIdx.x == 0) {
        exscan_body(ce, oe, M_EDGES);
        __syncthreads();
        for (int b = tid; b < NBE; b += 1024) gcur_e[b] = oe[b << 7];
    } else {
        exscan_body(cn, on_, N_NODES);
        __syncthreads();
        for (int b = tid; b < NBN; b += 1024) gcur_n[b] = on_[b << 8];
    }
}

// ---- partition: LDS multisplit by bucket, run-burst append into staging ----
// staging layout == final idx layout (bucket region = [off[k0], off[k1])), entries packed u32.
template<int NB, int SH, bool EDGE>
__device__ void part_side(const int* __restrict__ key, const int* __restrict__ val,
                          int* __restrict__ gcur, unsigned* __restrict__ stg,
                          unsigned* buf, int* hist, int* loff, int* lcur, int* gbase,
                          int i0, int items) {
    int tid = threadIdx.x;
    for (int b = tid; b < NB; b += 256) hist[b] = 0;
    __syncthreads();
    for (int p = tid; p < items; p += 256) atomicAdd(&hist[key[i0 + p] >> SH], 1);
    __syncthreads();
    if (tid == 0) {
        int s = 0;
        for (int b = 0; b < NB; ++b) { loff[b] = s; s += hist[b]; }
    }
    __syncthreads();
    for (int b = tid; b < NB; b += 256) lcur[b] = loff[b];
    __syncthreads();
    for (int p = tid; p < items; p += 256) {
        int k = key[i0 + p], v = val[i0 + p];
        int pos = atomicAdd(&lcur[k >> SH], 1);
        buf[pos] = EDGE ? (((unsigned)k << 16) | (unsigned)v)
                        : (((unsigned)k << 14) | (unsigned)v);
    }
    __syncthreads();
    for (int b = tid; b < NB; b += 256) gbase[b] = atomicAdd(&gcur[b], hist[b]);
    __syncthreads();
    for (int p = tid; p < items; p += 256) {
        unsigned en = buf[p];
        int k = EDGE ? (int)(en >> 16) : (int)(en >> 14);
        int b = k >> SH;
        stg[gbase[b] + (p - loff[b])] = en;
    }
    __syncthreads();
}

__global__ __launch_bounds__(256) void partition_kernel(const int* __restrict__ ni,
        const int* __restrict__ ei, int* __restrict__ gcur_e, int* __restrict__ gcur_n,
        unsigned* __restrict__ stg_e, unsigned* __restrict__ stg_n) {
    __shared__ unsigned buf[8192];                 // 32 KB
    __shared__ int hist[160], loff[160], lcur[160], gbase[160];
    int i0 = blockIdx.x * 8192;
    int items = NNZ_CNT - i0;
    if (items > 8192) items = 8192;
    part_side<NBE, 7, true>(ei, ni, gcur_e, stg_e, buf, hist, loff, lcur, gbase, i0, items);
    part_side<NBN, 8, false>(ni, ei, gcur_n, stg_n, buf, hist, loff, lcur, gbase, i0, items);
}

// ---- bucket-local fill: one workgroup per bucket; scatter stays in one XCD's L2 ----
__global__ __launch_bounds__(256) void bucket_fill(const int* __restrict__ off_e,
        const int* __restrict__ off_n, const unsigned* __restrict__ stg_e,
        const unsigned* __restrict__ stg_n, int* __restrict__ idx_e,
        int* __restrict__ idx_n) {
    __shared__ int cur[257];
    int tid = threadIdx.x;
    int b = blockIdx.x;
    if (b < NBE) {
        int k0 = b << 7, k1 = min(k0 + 128, M_EDGES), nk = k1 - k0;
        int base = off_e[k0];
        for (int i = tid; i <= nk; i += 256) cur[i] = off_e[k0 + i] - base;
        __syncthreads();
        int cnt = cur[nk];
        for (int p = tid; p < cnt; p += 256) {
            unsigned en = stg_e[base + p];
            int loc = atomicAdd(&cur[(int)(en >> 16) - k0], 1);
            idx_e[base + loc] = (int)(en & 0xFFFFu);
        }
    } else {
        b -= NBE;
        int k0 = b << 8, k1 = min(k0 + 256, N_NODES), nk = k1 - k0;
        int base = off_n[k0];
        for (int i = tid; i <= nk; i += 256) cur[i] = off_n[k0 + i] - base;
        __syncthreads();
        int cnt = cur[nk];
        for (int p = tid; p < cnt; p += 256) {
            unsigned en = stg_n[base + p];
            int loc = atomicAdd(&cur[(int)(en >> 14) - k0], 1);
            idx_n[base + loc] = (int)(en & 0x3FFFu);
        }
    }
}

__global__ void dinv_kernel(const int* __restrict__ off_n, const int* __restrict__ idx_n,
                            const int* __restrict__ cnt_e, float* __restrict__ dinv) {
    int n = blockIdx.x * 256 + threadIdx.x;
    if (n < N_NODES) {
        int s = off_n[n], e = off_n[n + 1];
        float p = 0.f;
        for (int j = s; j < e; ++j) p += (float)cnt_e[idx_n[j]];
        dinv[n] = (p > 0.f) ? 1.0f / p : 1.0f;
    }
}

// -------- weight prep (all 4 mats): W[K x 256] fp32 -> blocked hi/lo planes --------
struct WPA {
    const float* W[4];
    unsigned short* h[4];
    unsigned short* l[4];
};
__global__ void wprep_all(WPA p) {
    int m = blockIdx.y;
    int K = (m == 0) ? FT_DIM : HID;
    int i = blockIdx.x * 256 + threadIdx.x;
    if (i >= K * 256) return;
    int k = i >> 8, c = i & 255;
    float x = p.W[m][i];
    unsigned short hh = f2bf(x);
    long o = ((long)((c >> 6) * (K >> 3) + (k >> 3)) * 64 + (c & 63)) * 8 + (k & 7);
    p.h[m][o] = hh;
    p.l[m][o] = f2bf(x - bf2f(hh));
}

// ---------------- fp32 -> bf16 (round only, row-major) ----------------
__global__ void fsplit(const float4* __restrict__ src, u4v* __restrict__ h, int n4) {
    int i = blockIdx.x * 256 + threadIdx.x;
    if (i < n4) {
        float4 v = src[i];
        h[i] = (u4v){f2bf(v.x), f2bf(v.y), f2bf(v.z), f2bf(v.w)};
    }
}

// -------- relu(bn(x)) -> blocked single bf16 plane, BN finalize fused (K=256) --------
__global__ __launch_bounds__(256) void bn_split_blk(const float* __restrict__ src,
        const float* __restrict__ stats, const float* __restrict__ g,
        const float* __restrict__ be, unsigned short* __restrict__ hOut) {
    __shared__ float sa[HID], sc_[HID];
    int tid = threadIdx.x;
    {
        float mean = stats[tid] * ROWSINV;
        float var = stats[HID + tid] * ROWSINV - mean * mean;
        float av = g[tid] * rsqrtf(var + EPSV);
        sa[tid] = av;
        sc_[tid] = be[tid] - mean * av;
    }
    __syncthreads();
    int r = tid >> 2, kqg = tid & 3;
    long row = (long)blockIdx.x * 64 + r;
    long cbase = ((long)blockIdx.x * 32) * 64 + r;
#pragma unroll
    for (int t = 0; t < 8; ++t) {
        int kq = kqg * 8 + t;
        const float* sp = src + row * HID + kq * 8;
        float4 v0 = *(const float4*)sp;
        float4 v1 = *(const float4*)(sp + 4);
        float4 a0 = *(const float4*)(sa + kq * 8);
        float4 a1 = *(const float4*)(sa + kq * 8 + 4);
        float4 c0 = *(const float4*)(sc_ + kq * 8);
        float4 c1 = *(const float4*)(sc_ + kq * 8 + 4);
        s8v h;
        h[0] = (short)f2bf(fmaxf(fmaf(a0.x, v0.x, c0.x), 0.f));
        h[1] = (short)f2bf(fmaxf(fmaf(a0.y, v0.y, c0.y), 0.f));
        h[2] = (short)f2bf(fmaxf(fmaf(a0.z, v0.z, c0.z), 0.f));
        h[3] = (short)f2bf(fmaxf(fmaf(a0.w, v0.w, c0.w), 0.f));
        h[4] = (short)f2bf(fmaxf(fmaf(a1.x, v1.x, c1.x), 0.f));
        h[5] = (short)f2bf(fmaxf(fmaf(a1.y, v1.y, c1.y), 0.f));
        h[6] = (short)f2bf(fmaxf(fmaf(a1.z, v1.z, c1.z), 0.f));
        h[7] = (short)f2bf(fmaxf(fmaf(a1.w, v1.w, c1.w), 0.f));
        *(s8v*)(hOut + (cbase + (long)kq * 64) * 8) = h;
    }
}

// -------- relu(bn(x)) -> row-major bf16, BN finalize fused --------
__global__ __launch_bounds__(256) void bn_rowmajor(const float4* __restrict__ src,
        const float* __restrict__ stats, const float* __restrict__ g,
        const float* __restrict__ be, u4v* __restrict__ hOut, int n4) {
    __shared__ float sa[HID], sc_[HID];
    int tid = threadIdx.x;
    {
        float mean = stats[tid] * ROWSINV;
        float var = stats[HID + tid] * ROWSINV - mean * mean;
        float av = g[tid] * rsqrtf(var + EPSV);
        sa[tid] = av;
        sc_[tid] = be[tid] - mean * av;
    }
    __syncthreads();
    int i = blockIdx.x * 256 + tid;
    if (i >= n4) return;
    int col = (i << 2) & (HID - 1);
    float4 av = *(const float4*)(sa + col);
    float4 cv = *(const float4*)(sc_ + col);
    float4 v = src[i];
    float x0 = fmaxf(fmaf(av.x, v.x, cv.x), 0.f);
    float x1 = fmaxf(fmaf(av.y, v.y, cv.y), 0.f);
    float x2 = fmaxf(fmaf(av.z, v.z, cv.z), 0.f);
    float x3 = fmaxf(fmaf(av.w, v.w, cv.w), 0.f);
    hOut[i] = (u4v){f2bf(x0), f2bf(x1), f2bf(x2), f2bf(x3)};
}

// ---------------- gathers ----------------
// edge gather d=128 (avg degree 40): 8 independent chains, 4B/lane, scalar idx
__global__ __launch_bounds__(256) void gather_e128(const int* __restrict__ off,
        const int* __restrict__ idx, const unsigned short* __restrict__ Y,
        unsigned short* __restrict__ outh) {
    int lane = threadIdx.x & 63;
    int r = blockIdx.x * 4 + (threadIdx.x >> 6);
    int f0 = lane * 2;
    int s = off[r], e = off[r + 1];
    float a[8][2] = {};
    int j = s;
    for (; j + 8 <= e; j += 8) {
#pragma unroll
        for (int u = 0; u < 8; ++u) {
            int iv = __builtin_amdgcn_readfirstlane(idx[j + u]);
            u2v g = *(const u2v*)(Y + (long)iv * FT_DIM + f0);
            a[u][0] += bf2f(g[0]);
            a[u][1] += bf2f(g[1]);
        }
    }
    for (; j < e; ++j) {
        int iv = __builtin_amdgcn_readfirstlane(idx[j]);
        u2v g = *(const u2v*)(Y + (long)iv * FT_DIM + f0);
        a[0][0] += bf2f(g[0]);
        a[0][1] += bf2f(g[1]);
    }
    float s0 = 0.f, s1 = 0.f;
#pragma unroll
    for (int u = 0; u < 8; ++u) { s0 += a[u][0]; s1 += a[u][1]; }
    *(u2v*)(outh + (long)r * FT_DIM + f0) = (u2v){f2bf(s0), f2bf(s1)};
}

// node gather d=128 (avg degree 10): 4 chains, writes blocked single plane
__global__ __launch_bounds__(256) void gather_n128_planes(const int* __restrict__ off,
        const int* __restrict__ idx, const unsigned short* __restrict__ Y,
        unsigned short* __restrict__ Ph) {
    int lane = threadIdx.x & 63;
    int r = blockIdx.x * 4 + (threadIdx.x >> 6);
    int f0 = lane * 2;
    int s = off[r], e = off[r + 1];
    float a[4][2] = {};
    int j = s;
    for (; j + 4 <= e; j += 4) {
#pragma unroll
        for (int u = 0; u < 4; ++u) {
            int iv = __builtin_amdgcn_readfirstlane(idx[j + u]);
            u2v g = *(const u2v*)(Y + (long)iv * FT_DIM + f0);
            a[u][0] += bf2f(g[0]);
            a[u][1] += bf2f(g[1]);
        }
    }
    for (; j < e; ++j) {
        int iv = __builtin_amdgcn_readfirstlane(idx[j]);
        u2v g = *(const u2v*)(Y + (long)iv * FT_DIM + f0);
        a[0][0] += bf2f(g[0]);
        a[0][1] += bf2f(g[1]);
    }
    float s0 = a[0][0] + a[1][0] + a[2][0] + a[3][0];
    float s1 = a[0][1] + a[1][1] + a[2][1] + a[3][1];
    *(u2v*)(Ph + ablk(r, f0, FT_DIM)) = (u2v){f2bf(s0), f2bf(s1)};
}

// edge gather d=256: 16B/lane, half-wave = one row; halves take even/odd edges of the
// SAME list (scalar idx). Epilogue: z[e] = rowsum . Wh; optionally writes Eb.
template<bool WRITE_EB>
__global__ __launch_bounds__(256) void gather_e256_z(const int* __restrict__ off,
        const int* __restrict__ idx, const unsigned short* __restrict__ Y,
        unsigned short* __restrict__ Eb, const float* __restrict__ Wh,
        float* __restrict__ z) {
    int lane = threadIdx.x & 63;
    int r = blockIdx.x * 4 + (threadIdx.x >> 6);
    int hh = lane >> 5;
    int f0 = (lane & 31) * 8;
    int s = off[r], e = off[r + 1];
    float A[4][8] = {};
    int j = s;
    for (; j + 16 <= e; j += 16) {
        u8v g[8];
#pragma unroll
        for (int u = 0; u < 8; ++u) {
            int i0 = __builtin_amdgcn_readfirstlane(idx[j + 2 * u]);
            int i1 = __builtin_amdgcn_readfirstlane(idx[j + 2 * u + 1]);
            int iv = hh ? i1 : i0;
            g[u] = *(const u8v*)(Y + (long)iv * HID + f0);
        }
#pragma unroll
        for (int u = 0; u < 8; ++u)
#pragma unroll
            for (int v = 0; v < 8; ++v) A[u & 3][v] += bf2f(g[u][v]);
    }
    for (; j < e; j += 2) {
        int has1 = (j + 1 < e);
        int i0 = __builtin_amdgcn_readfirstlane(idx[j]);
        int i1 = __builtin_amdgcn_readfirstlane(idx[has1 ? j + 1 : j]);
        int iv = hh ? i1 : i0;
        u8v g = *(const u8v*)(Y + (long)iv * HID + f0);
        if (!hh || has1) {
#pragma unroll
            for (int v = 0; v < 8; ++v) A[0][v] += bf2f(g[v]);
        }
    }
    float sum[8];
#pragma unroll
    for (int v = 0; v < 8; ++v) {
        sum[v] = A[0][v] + A[1][v] + A[2][v] + A[3][v];
        sum[v] += __shfl_xor(sum[v], 32, 64);
    }
    if (WRITE_EB && hh == 0) {
        u8v o;
#pragma unroll
        for (int v = 0; v < 8; ++v) o[v] = f2bf(sum[v]);
        *(u8v*)(Eb + (long)r * HID + f0) = o;
    }
    const float* wp = Wh + (long)f0 * NCLS;
    float p[NCLS];
#pragma unroll
    for (int c = 0; c < NCLS; ++c) {
        float acc = 0.f;
#pragma unroll
        for (int v = 0; v < 8; ++v) acc += sum[v] * wp[v * NCLS + c];
        p[c] = acc;
    }
#pragma unroll
    for (int c = 0; c < NCLS; ++c) {
#pragma unroll
        for (int m = 1; m < 32; m <<= 1) p[c] += __shfl_xor(p[c], m, 64);
    }
    if (lane == 0) {
        float* zp = z + (long)r * 16;
        *(float4*)(zp)      = (float4){p[0], p[1], p[2], p[3]};
        *(float4*)(zp + 4)  = (float4){p[4], p[5], p[6], p[7]};
        *(float4*)(zp + 8)  = (float4){p[8], p[9], 0.f, 0.f};
        *(float4*)(zp + 12) = (float4){0.f, 0.f, 0.f, 0.f};
    }
}

// node gather d=256 (avg degree 10): 16B/lane half-pair, writes blocked single plane
__global__ __launch_bounds__(256) void gather_n256_planes(const int* __restrict__ off,
        const int* __restrict__ idx, const unsigned short* __restrict__ Y,
        unsigned short* __restrict__ Ph) {
    int lane = threadIdx.x & 63;
    int r = blockIdx.x * 4 + (threadIdx.x >> 6);
    int hh = lane >> 5;
    int f0 = (lane & 31) * 8;
    int s = off[r], e = off[r + 1];
    float A[2][8] = {};
    int j = s;
    for (; j + 8 <= e; j += 8) {
        u8v g[4];
#pragma unroll
        for (int u = 0; u < 4; ++u) {
            int i0 = __builtin_amdgcn_readfirstlane(idx[j + 2 * u]);
            int i1 = __builtin_amdgcn_readfirstlane(idx[j + 2 * u + 1]);
            int iv = hh ? i1 : i0;
            g[u] = *(const u8v*)(Y + (long)iv * HID + f0);
        }
#pragma unroll
        for (int u = 0; u < 4; ++u)
#pragma unroll
            for (int v = 0; v < 8; ++v) A[u & 1][v] += bf2f(g[u][v]);
    }
    for (; j < e; j += 2) {
        int has1 = (j + 1 < e);
        int i0 = __builtin_amdgcn_readfirstlane(idx[j]);
        int i1 = __builtin_amdgcn_readfirstlane(idx[has1 ? j + 1 : j]);
        int iv = hh ? i1 : i0;
        u8v g = *(const u8v*)(Y + (long)iv * HID + f0);
        if (!hh || has1) {
#pragma unroll
            for (int v = 0; v < 8; ++v) A[0][v] += bf2f(g[v]);
        }
    }
    s8v o;
#pragma unroll
    for (int v = 0; v < 8; ++v) {
        float sum = A[0][v] + A[1][v];
        sum += __shfl_xor(sum, 32, 64);
        o[v] = (short)f2bf(sum);
    }
    if (hh == 0) *(s8v*)(Ph + ablk(r, f0, HID)) = o;
}

// node readout over z rows (64B each): 4 threads per node, float4 per thread.
template<bool FIRST>
__global__ __launch_bounds__(256) void gather_z(const int* __restrict__ off,
        const int* __restrict__ idx, const float* __restrict__ z,
        const float* __restrict__ dinv, const float* __restrict__ hb,
        float* __restrict__ on) {
    int tid = threadIdx.x;
    int t = tid & 3;
    int n = blockIdx.x * 64 + (tid >> 2);
    int s = off[n], e = off[n + 1];
    float4 a0 = {0,0,0,0}, a1 = {0,0,0,0}, a2 = {0,0,0,0}, a3 = {0,0,0,0};
    int j = s;
    for (; j + 4 <= e; j += 4) {
        float4 g0 = *(const float4*)(z + (long)idx[j] * 16 + t * 4);
        float4 g1 = *(const float4*)(z + (long)idx[j + 1] * 16 + t * 4);
        float4 g2 = *(const float4*)(z + (long)idx[j + 2] * 16 + t * 4);
        float4 g3 = *(const float4*)(z + (long)idx[j + 3] * 16 + t * 4);
        a0.x += g0.x; a0.y += g0.y; a0.z += g0.z; a0.w += g0.w;
        a1.x += g1.x; a1.y += g1.y; a1.z += g1.z; a1.w += g1.w;
        a2.x += g2.x; a2.y += g2.y; a2.z += g2.z; a2.w += g2.w;
        a3.x += g3.x; a3.y += g3.y; a3.z += g3.z; a3.w += g3.w;
    }
    for (; j < e; ++j) {
        float4 g0 = *(const float4*)(z + (long)idx[j] * 16 + t * 4);
        a0.x += g0.x; a0.y += g0.y; a0.z += g0.z; a0.w += g0.w;
    }
    float di = dinv[n];
    float4 acc;
    acc.x = (a0.x + a1.x + a2.x + a3.x) * di;
    acc.y = (a0.y + a1.y + a2.y + a3.y) * di;
    acc.z = (a0.z + a1.z + a2.z + a3.z) * di;
    acc.w = (a0.w + a1.w + a2.w + a3.w) * di;
    float* op = on + (long)n * 16 + t * 4;
    if (FIRST) {
        float4 b;
#pragma unroll
        for (int k = 0; k < 4; ++k) {
            int c = t * 4 + k;
            ((float*)&b)[k] = (c < NCLS) ? hb[c] : 0.f;
        }
        *(float4*)op = (float4){acc.x + b.x, acc.y + b.y, acc.z + b.z, acc.w + b.w};
    } else {
        float4 old = *(float4*)op;
        *(float4*)op = (float4){old.x + acc.x, old.y + acc.y, old.z + acc.z, old.w + acc.w};
    }
}

// ---------------- single-A-plane MFMA GEMM, 128x128 tile ----------------
template<int K>
__global__ __launch_bounds__(256) void gemm128(const unsigned short* __restrict__ Ahg,
        const unsigned short* __restrict__ Bhg, const unsigned short* __restrict__ Blg,
        const float* __restrict__ bias, float* __restrict__ C, float* __restrict__ stats) {
    constexpr int KQ = K >> 3;
    __shared__ __align__(16) unsigned short Asl[16 * 512];   // 16 KB
    __shared__ __align__(16) unsigned short Bsl[32 * 512];   // 32 KB
    float* lsum = (float*)Asl;
    float* lsq  = lsum + 128;
    int tid = threadIdx.x;
    int lane = tid & 63, w = tid >> 6;
    int bx = blockIdx.x;
    int col0 = blockIdx.y * 128;
    int colblk0 = blockIdx.y * 2;
    int lm = lane & 15, lq = lane >> 4;
    int rbw = w >> 1;
    int rw = (w & 1) * 32;
    f4v acc[2][8];
#pragma unroll
    for (int i = 0; i < 2; ++i)
#pragma unroll
        for (int j = 0; j < 8; ++j) acc[i][j] = (f4v){0.f, 0.f, 0.f, 0.f};

    for (int ks = 0; ks < K / 64; ++ks) {
        int kq0 = ks * 8;
#pragma unroll
        for (int t = 0; t < 4; ++t) {
            int a = w * 4 + t;
            int rb = a >> 3, kqo = a & 7;
            const unsigned short* g = Ahg
                + ((long)((bx * 2 + rb) * KQ + kq0 + kqo) * 64 + lane) * 8;
            __builtin_amdgcn_global_load_lds(
                (const __attribute__((address_space(1))) void*)g,
                (__attribute__((address_space(3))) void*)(Asl + a * 512), 16, 0, 0);
        }
#pragma unroll
        for (int u = 0; u < 8; ++u) {
            int b = w * 8 + u;
            const unsigned short* g = ((b >> 4) ? Blg : Bhg)
                + ((long)((colblk0 + ((b >> 3) & 1)) * KQ + kq0 + (b & 7)) * 64 + lane) * 8;
            __builtin_amdgcn_global_load_lds(
                (const __attribute__((address_space(1))) void*)g,
                (__attribute__((address_space(3))) void*)(Bsl + b * 512), 16, 0, 0);
        }
        __syncthreads();
#pragma unroll
        for (int kk = 0; kk < 2; ++kk) {
            s8v ah[2];
#pragma unroll
            for (int i = 0; i < 2; ++i)
                ah[i] = *(const s8v*)&Asl[(rbw * 8 + kk * 4 + lq) * 512
                                          + (rw + i * 16 + lm) * 8];
#pragma unroll
            for (int j = 0; j < 8; ++j) {
                int cb = j >> 2;
                int c64 = (j & 3) * 16 + lm;
                s8v bh = *(const s8v*)&Bsl[(cb * 8 + kk * 4 + lq) * 512 + c64 * 8];
                s8v bl = *(const s8v*)&Bsl[(16 + cb * 8 + kk * 4 + lq) * 512 + c64 * 8];
#pragma unroll
                for (int i = 0; i < 2; ++i) {
                    acc[i][j] = __builtin_amdgcn_mfma_f32_16x16x32_bf16(ah[i], bl, acc[i][j], 0, 0, 0);
                    acc[i][j] = __builtin_amdgcn_mfma_f32_16x16x32_bf16(ah[i], bh, acc[i][j], 0, 0, 0);
                }
            }
        }
        __syncthreads();
    }
    if (tid < 128) { lsum[tid] = 0.f; lsq[tid] = 0.f; }
    __syncthreads();
#pragma unroll
    for (int j = 0; j < 8; ++j) {
        int lc = j * 16 + lm;
        int col = col0 + lc;
        float bsv = bias[col];
        float s = 0.f, sq = 0.f;
#pragma unroll
        for (int i = 0; i < 2; ++i) {
#pragma unroll
            for (int reg = 0; reg < 4; ++reg) {
                long row = (long)bx * 128 + rbw * 64 + rw + i * 16 + lq * 4 + reg;
                if (row < N_NODES) {
                    float v = acc[i][j][reg] + bsv;
                    C[row * HID + col] = v;
                    s += v;
                    sq += v * v;
                }
            }
        }
        atomicAdd(&lsum[lc], s);
        atomicAdd(&lsq[lc], sq);
    }
    __syncthreads();
    if (tid < 128) {
        atomicAdd(&stats[col0 + tid], lsum[tid]);
        atomicAdd(&stats[HID + col0 + tid], lsq[tid]);
    }
}

// ---------------- readout (onodes stride 16) ----------------
__global__ __launch_bounds__(256) void readout_accum(const float* __restrict__ on,
                                                     const int* __restrict__ ab,
                                                     float* __restrict__ racc,
                                                     float* __restrict__ rcnt) {
    __shared__ float lacc[NG * NCLS];
    __shared__ float lcnt[NG];
    int tid = threadIdx.x;
    for (int i = tid; i < NG * NCLS; i += 256) lacc[i] = 0.f;
    if (tid < NG) lcnt[tid] = 0.f;
    __syncthreads();
    int n = blockIdx.x * 256 + tid;
    if (n < N_NODES) {
        int b = ab[n];
        atomicAdd(&lcnt[b], 1.0f);
        for (int c = 0; c < NCLS; ++c) atomicAdd(&lacc[b * NCLS + c], on[(long)n * 16 + c]);
    }
    __syncthreads();
    if (tid < NG && lcnt[tid] > 0.f) {
        atomicAdd(&rcnt[tid], lcnt[tid]);
        for (int c = 0; c < NCLS; ++c) atomicAdd(&racc[tid * NCLS + c], lacc[tid * NCLS + c]);
    }
}

__global__ void readout_final(const float* __restrict__ racc, const float* __restrict__ rcnt,
                              float* __restrict__ out) {
    int i = blockIdx.x * 256 + threadIdx.x;
    if (i < NG * NCLS) out[i] = racc[i] / fmaxf(rcnt[i / NCLS], 1.0f);
}

// ---------------- launch ----------------
extern "C" void kernel_launch(void* const* d_in, const int* in_sizes, int n_in,
                              void* d_out, int out_size, void* d_ws, size_t ws_size,
                              hipStream_t stream) {
    const float* X         = (const float*)d_in[0];
    const int*   node_idx  = (const int*)d_in[1];
    const int*   edge_idx  = (const int*)d_in[2];
    const int*   all_batch = (const int*)d_in[3];
    const float* W1[2]  = {(const float*)d_in[4],  (const float*)d_in[12]};
    const float* b1[2]  = {(const float*)d_in[5],  (const float*)d_in[13]};
    const float* g1[2]  = {(const float*)d_in[6],  (const float*)d_in[14]};
    const float* be1[2] = {(const float*)d_in[7],  (const float*)d_in[15]};
    const float* W2[2]  = {(const float*)d_in[8],  (const float*)d_in[16]};
    const float* b2[2]  = {(const float*)d_in[9],  (const float*)d_in[17]};
    const float* bng[2] = {(const float*)d_in[10], (const float*)d_in[18]};
    const float* bnb[2] = {(const float*)d_in[11], (const float*)d_in[19]};
    const float* headW  = (const float*)d_in[20];
    const float* headb  = (const float*)d_in[21];
    float* out = (float*)d_out;

    char* base = (char*)d_ws;
    size_t off = 0;
    auto alloc = [&](size_t bytes) -> void* {
        size_t o = (off + 255) & ~(size_t)255;
        off = o + bytes;
        return (void*)(base + o);
    };

    const int ZINTS = M_EDGES + N_NODES;           // counts only
    const int ZTOT  = ZINTS + 4 * 2 * HID + NG * NCLS + NG;
    int* ibase  = (int*)alloc((size_t)ZTOT * 4);
    int* cnt_e  = ibase;
    int* cnt_n  = cnt_e + M_EDGES;
    float* statsall = (float*)(ibase + ZINTS);
    float* racc     = statsall + 4 * 2 * HID;
    float* rcnt     = racc + NG * NCLS;

    int* off_e  = (int*)alloc((M_EDGES + 1) * 4);
    int* off_n  = (int*)alloc((N_NODES + 1) * 4);
    int* gcur_e = (int*)alloc(NBE * 4);
    int* gcur_n = (int*)alloc(NBN * 4);
    int* idx_e  = (int*)alloc((size_t)NNZ_CNT * 4);
    int* idx_n  = (int*)alloc((size_t)NNZ_CNT * 4);
    unsigned* stg_e = (unsigned*)alloc((size_t)NNZ_CNT * 4);
    unsigned* stg_n = (unsigned*)alloc((size_t)NNZ_CNT * 4);
    float* dinv = (float*)alloc((size_t)N_NODES * 4);

    unsigned short* Xb = (unsigned short*)alloc((size_t)N_NODES * FT_DIM * 2);
    unsigned short* Eb = (unsigned short*)alloc((size_t)M_EDGES * HID * 2);
    unsigned short* Ph = (unsigned short*)alloc((size_t)M_PAD * HID * 2);
    unsigned short* Ahp = (unsigned short*)alloc((size_t)M_PAD * HID * 2);
    unsigned short* Hb  = (unsigned short*)alloc((size_t)N_NODES * HID * 2);
    float* T      = (float*)alloc((size_t)N_NODES * HID * 4);
    float* onodes = (float*)alloc((size_t)N_NODES * 16 * 4);
    float* zbuf   = (float*)alloc((size_t)M_EDGES * 16 * 4);
    unsigned short* Wp[4][2];
    int WK[4] = {FT_DIM, HID, HID, HID};
    for (int m = 0; m < 4; ++m) {
        Wp[m][0] = (unsigned short*)alloc((size_t)WK[m] * HID * 2);
        Wp[m][1] = (unsigned short*)alloc((size_t)WK[m] * HID * 2);
    }

    const int nnz_blocks = (NNZ_CNT + 255) / 256;
    const int n4 = N_NODES * HID / 4;
    const dim3 ggrid(M_PAD / 128, 2);

    // --- CSR build (bucketed counting sort) + degree norm + weight prep ---
    fzero<<<(ZTOT + 255) / 256, 256, 0, stream>>>((float*)ibase, ZTOT);
    count_kernel<<<nnz_blocks, 256, 0, stream>>>(node_idx, edge_idx, cnt_e, cnt_n);
    exscan2<<<2, 1024, 0, stream>>>(cnt_e, off_e, cnt_n, off_n, gcur_e, gcur_n);
    partition_kernel<<<(NNZ_CNT + 8191) / 8192, 256, 0, stream>>>(node_idx, edge_idx,
                                                                  gcur_e, gcur_n, stg_e, stg_n);
    bucket_fill<<<NBE + NBN, 256, 0, stream>>>(off_e, off_n, stg_e, stg_n, idx_e, idx_n);
    dinv_kernel<<<(N_NODES + 255) / 256, 256, 0, stream>>>(off_n, idx_n, cnt_e, dinv);
    WPA wpa;
    wpa.W[0] = W1[0]; wpa.W[1] = W2[0]; wpa.W[2] = W1[1]; wpa.W[3] = W2[1];
    for (int m = 0; m < 4; ++m) { wpa.h[m] = Wp[m][0]; wpa.l[m] = Wp[m][1]; }
    wprep_all<<<dim3(256, 4), 256, 0, stream>>>(wpa);
    fsplit<<<(N_NODES * FT_DIM / 4 + 255) / 256, 256, 0, stream>>>((const float4*)X,
                                                                   (u4v*)Xb, N_NODES * FT_DIM / 4);

    // ---------------- layer 0 ----------------
    gather_e128<<<M_EDGES / 4, 256, 0, stream>>>(off_e, idx_e, Xb, Eb);
    gather_n128_planes<<<N_NODES / 4, 256, 0, stream>>>(off_n, idx_n, Eb, Ph);
    gemm128<FT_DIM><<<ggrid, 256, 0, stream>>>(Ph, Wp[0][0], Wp[0][1], b1[0], T,
                                               statsall + 0 * 512);
    bn_split_blk<<<N_NODES / 64, 256, 0, stream>>>(T, statsall + 0 * 512, g1[0], be1[0], Ahp);
    gemm128<HID><<<ggrid, 256, 0, stream>>>(Ahp, Wp[1][0], Wp[1][1], b2[0], T,
                                            statsall + 1 * 512);
    bn_rowmajor<<<(n4 + 255) / 256, 256, 0, stream>>>((const float4*)T, statsall + 1 * 512,
                                                      bng[0], bnb[0], (u4v*)Hb, n4);
    // shared edge pass: Eb (layer-1 pooling) + z (layer-0 readout head)
    gather_e256_z<true><<<M_EDGES / 4, 256, 0, stream>>>(off_e, idx_e, Hb, Eb, headW, zbuf);
    gather_z<true><<<N_NODES / 64, 256, 0, stream>>>(off_n, idx_n, zbuf, dinv, headb, onodes);
    gather_n256_planes<<<N_NODES / 4, 256, 0, stream>>>(off_n, idx_n, Eb, Ph);

    // ---------------- layer 1 ----------------
    gemm128<HID><<<ggrid, 256, 0, stream>>>(Ph, Wp[2][0], Wp[2][1], b1[1], T,
                                            statsall + 2 * 512);
    bn_split_blk<<<N_NODES / 64, 256, 0, stream>>>(T, statsall + 2 * 512, g1[1], be1[1], Ahp);
    gemm128<HID><<<ggrid, 256, 0, stream>>>(Ahp, Wp[3][0], Wp[3][1], b2[1], T,
                                            statsall + 3 * 512);
    bn_rowmajor<<<(n4 + 255) / 256, 256, 0, stream>>>((const float4*)T, statsall + 3 * 512,
                                                      bng[1], bnb[1], (u4v*)Hb, n4);
    gather_e256_z<false><<<M_EDGES / 4, 256, 0, stream>>>(off_e, idx_e, Hb, nullptr,
                                                          headW + (size_t)HID * NCLS, zbuf);
    gather_z<false><<<N_NODES / 64, 256, 0, stream>>>(off_n, idx_n, zbuf, dinv, nullptr, onodes);

    // ---------------- readout ----------------
    readout_accum<<<(N_NODES + 255) / 256, 256, 0, stream>>>(onodes, all_batch, racc, rcnt);
    readout_final<<<(NG * NCLS + 255) / 256, 256, 0, stream>>>(racc, rcnt, out);
}

// Round 11
// 559.035 us; speedup vs baseline: 1.4230x; 1.0147x over previous
//
#include <hip/hip_runtime.h>

#define N_NODES 40000
#define M_PAD   40064          // 313 * 128
#define M_EDGES 10000
#define NNZ_CNT 400000
#define FT_DIM  128
#define HID     256
#define NCLS    10
#define NG      128
#define EPSV    1e-5f
#define ROWSINV (1.0f / 40000.0f)

#define NBE 79    // edge buckets: key >> 7 (128 keys each)
#define NBN 157   // node buckets: key >> 8 (256 keys each)

typedef short s8v __attribute__((ext_vector_type(8)));
typedef unsigned short u8v __attribute__((ext_vector_type(8)));
typedef float f4v __attribute__((ext_vector_type(4)));
typedef unsigned short u4v __attribute__((ext_vector_type(4)));
typedef unsigned short u2v __attribute__((ext_vector_type(2)));

__device__ __forceinline__ unsigned short f2bf(float x) {
    unsigned int u = __float_as_uint(x);
    u += 0x7fffu + ((u >> 16) & 1u);
    return (unsigned short)(u >> 16);
}
__device__ __forceinline__ float bf2f(unsigned short h) {
    return __uint_as_float(((unsigned int)h) << 16);
}

// blocked-chunk element address (in shorts) for (r, k): layout [r/64][k/8][r%64] 16B chunks
__device__ __forceinline__ long ablk(int r, int k, int K) {
    return ((long)((r >> 6) * (K >> 3) + (k >> 3)) * 64 + (r & 63)) * 8 + (k & 7);
}

// ---------------- utility ----------------
__global__ void fzero(float* __restrict__ p, int n) {
    int i = blockIdx.x * 256 + threadIdx.x;
    if (i < n) p[i] = 0.f;
}

// ---------------- CSR build ----------------
__global__ void count_kernel(const int* __restrict__ ni, const int* __restrict__ ei,
                             int* __restrict__ cnt_e, int* __restrict__ cnt_n) {
    int i = blockIdx.x * 256 + threadIdx.x;
    if (i < NNZ_CNT) {
        atomicAdd(&cnt_e[ei[i]], 1);
        atomicAdd(&cnt_n[ni[i]], 1);
    }
}

__device__ void exscan_body(const int* __restrict__ in, int* __restrict__ out, int n) {
    __shared__ int wsum[16];
    __shared__ int carry_s;
    int tid = threadIdx.x, lane = tid & 63, w = tid >> 6;
    if (tid == 0) carry_s = 0;
    __syncthreads();
    for (int base = 0; base < n; base += 4096) {
        int i0 = base + tid * 4;
        int v[4];
#pragma unroll
        for (int t = 0; t < 4; ++t) v[t] = (i0 + t < n) ? in[i0 + t] : 0;
        int s = v[0] + v[1] + v[2] + v[3];
        int sc = s;
#pragma unroll
        for (int d = 1; d < 64; d <<= 1) {
            int t = __shfl_up(sc, d, 64);
            if (lane >= d) sc += t;
        }
        if (lane == 63) wsum[w] = sc;
        __syncthreads();
        if (tid < 64) {
            int ws = (lane < 16) ? wsum[lane] : 0;
            int wsc = ws;
#pragma unroll
            for (int d = 1; d < 16; d <<= 1) {
                int t = __shfl_up(wsc, d, 64);
                if (lane >= d) wsc += t;
            }
            if (lane < 16) wsum[lane] = wsc - ws;
        }
        __syncthreads();
        int carry = carry_s;
        int ex = carry + wsum[w] + (sc - s);
#pragma unroll
        for (int t = 0; t < 4; ++t) {
            if (i0 + t < n) out[i0 + t] = ex;
            ex += v[t];
        }
        __syncthreads();
        if (tid == 1023) carry_s = ex;
    }
    __syncthreads();
    if (tid == 0) out[n] = carry_s;
}

__global__ __launch_bounds__(1024) void exscan2(const int* __restrict__ ce, int* __restrict__ oe,
                                                const int* __restrict__ cn, int* __restrict__ on_,
                                                int* __restrict__ gcur_e, int* __restrict__ gcur_n) {
    int tid = threadIdx.x;
    if (blockIdx.x == 0) {
        exscan_body(ce, oe, M_EDGES);
        __syncthreads();
        for (int b = tid; b < NBE; b += 1024) gcur_e[b] = oe[b << 7];
    } else {
        exscan_body(cn, on_, N_NODES);
        __syncthreads();
        for (int b = tid; b < NBN; b += 1024) gcur_n[b] = on_[b << 8];
    }
}

// ---- partition: LDS multisplit by bucket, run-burst append into staging ----
template<int NB, int SH, bool EDGE>
__device__ void part_side(const int* __restrict__ key, const int* __restrict__ val,
                          int* __restrict__ gcur, unsigned* __restrict__ stg,
                          unsigned* buf, int* hist, int* loff, int* lcur, int* gbase,
                          int i0, int items) {
    int tid = threadIdx.x;
    for (int b = tid; b < NB; b += 256) hist[b] = 0;
    __syncthreads();
    for (int p = tid; p < items; p += 256) atomicAdd(&hist[key[i0 + p] >> SH], 1);
    __syncthreads();
    if (tid == 0) {
        int s = 0;
        for (int b = 0; b < NB; ++b) { loff[b] = s; s += hist[b]; }
    }
    __syncthreads();
    for (int b = tid; b < NB; b += 256) lcur[b] = loff[b];
    __syncthreads();
    for (int p = tid; p < items; p += 256) {
        int k = key[i0 + p], v = val[i0 + p];
        int pos = atomicAdd(&lcur[k >> SH], 1);
        buf[pos] = EDGE ? (((unsigned)k << 16) | (unsigned)v)
                        : (((unsigned)k << 14) | (unsigned)v);
    }
    __syncthreads();
    for (int b = tid; b < NB; b += 256) gbase[b] = atomicAdd(&gcur[b], hist[b]);
    __syncthreads();
    for (int p = tid; p < items; p += 256) {
        unsigned en = buf[p];
        int k = EDGE ? (int)(en >> 16) : (int)(en >> 14);
        int b = k >> SH;
        stg[gbase[b] + (p - loff[b])] = en;
    }
    __syncthreads();
}

__global__ __launch_bounds__(256) void partition_kernel(const int* __restrict__ ni,
        const int* __restrict__ ei, int* __restrict__ gcur_e, int* __restrict__ gcur_n,
        unsigned* __restrict__ stg_e, unsigned* __restrict__ stg_n) {
    __shared__ unsigned buf[8192];
    __shared__ int hist[160], loff[160], lcur[160], gbase[160];
    int i0 = blockIdx.x * 8192;
    int items = NNZ_CNT - i0;
    if (items > 8192) items = 8192;
    part_side<NBE, 7, true>(ei, ni, gcur_e, stg_e, buf, hist, loff, lcur, gbase, i0, items);
    part_side<NBN, 8, false>(ni, ei, gcur_n, stg_n, buf, hist, loff, lcur, gbase, i0, items);
}

__global__ __launch_bounds__(256) void bucket_fill(const int* __restrict__ off_e,
        const int* __restrict__ off_n, const unsigned* __restrict__ stg_e,
        const unsigned* __restrict__ stg_n, int* __restrict__ idx_e,
        int* __restrict__ idx_n) {
    __shared__ int cur[257];
    int tid = threadIdx.x;
    int b = blockIdx.x;
    if (b < NBE) {
        int k0 = b << 7, k1 = min(k0 + 128, M_EDGES), nk = k1 - k0;
        int base = off_e[k0];
        for (int i = tid; i <= nk; i += 256) cur[i] = off_e[k0 + i] - base;
        __syncthreads();
        int cnt = cur[nk];
        for (int p = tid; p < cnt; p += 256) {
            unsigned en = stg_e[base + p];
            int loc = atomicAdd(&cur[(int)(en >> 16) - k0], 1);
            idx_e[base + loc] = (int)(en & 0xFFFFu);
        }
    } else {
        b -= NBE;
        int k0 = b << 8, k1 = min(k0 + 256, N_NODES), nk = k1 - k0;
        int base = off_n[k0];
        for (int i = tid; i <= nk; i += 256) cur[i] = off_n[k0 + i] - base;
        __syncthreads();
        int cnt = cur[nk];
        for (int p = tid; p < cnt; p += 256) {
            unsigned en = stg_n[base + p];
            int loc = atomicAdd(&cur[(int)(en >> 14) - k0], 1);
            idx_n[base + loc] = (int)(en & 0x3FFFu);
        }
    }
}

__global__ void dinv_kernel(const int* __restrict__ off_n, const int* __restrict__ idx_n,
                            const int* __restrict__ cnt_e, float* __restrict__ dinv) {
    int n = blockIdx.x * 256 + threadIdx.x;
    if (n < N_NODES) {
        int s = off_n[n], e = off_n[n + 1];
        float p = 0.f;
        for (int j = s; j < e; ++j) p += (float)cnt_e[idx_n[j]];
        dinv[n] = (p > 0.f) ? 1.0f / p : 1.0f;
    }
}

// -------- weight prep (all 4 mats): W[K x 256] fp32 -> blocked hi/lo planes --------
struct WPA {
    const float* W[4];
    unsigned short* h[4];
    unsigned short* l[4];
};
__global__ void wprep_all(WPA p) {
    int m = blockIdx.y;
    int K = (m == 0) ? FT_DIM : HID;
    int i = blockIdx.x * 256 + threadIdx.x;
    if (i >= K * 256) return;
    int k = i >> 8, c = i & 255;
    float x = p.W[m][i];
    unsigned short hh = f2bf(x);
    long o = ((long)((c >> 6) * (K >> 3) + (k >> 3)) * 64 + (c & 63)) * 8 + (k & 7);
    p.h[m][o] = hh;
    p.l[m][o] = f2bf(x - bf2f(hh));
}

// ---------------- fp32 -> bf16 (round only, row-major) ----------------
__global__ void fsplit(const float4* __restrict__ src, u4v* __restrict__ h, int n4) {
    int i = blockIdx.x * 256 + threadIdx.x;
    if (i < n4) {
        float4 v = src[i];
        h[i] = (u4v){f2bf(v.x), f2bf(v.y), f2bf(v.z), f2bf(v.w)};
    }
}

// -------- relu(bn(x)) on bf16 src -> blocked single bf16 plane, BN finalize fused --------
__global__ __launch_bounds__(256) void bn_split_blk(const unsigned short* __restrict__ src,
        const float* __restrict__ stats, const float* __restrict__ g,
        const float* __restrict__ be, unsigned short* __restrict__ hOut) {
    __shared__ float sa[HID], sc_[HID];
    int tid = threadIdx.x;
    {
        float mean = stats[tid] * ROWSINV;
        float var = stats[HID + tid] * ROWSINV - mean * mean;
        float av = g[tid] * rsqrtf(var + EPSV);
        sa[tid] = av;
        sc_[tid] = be[tid] - mean * av;
    }
    __syncthreads();
    int r = tid >> 2, kqg = tid & 3;
    long row = (long)blockIdx.x * 64 + r;
    long cbase = ((long)blockIdx.x * 32) * 64 + r;
#pragma unroll
    for (int t = 0; t < 8; ++t) {
        int kq = kqg * 8 + t;
        u8v v = *(const u8v*)(src + row * HID + kq * 8);
        float4 a0 = *(const float4*)(sa + kq * 8);
        float4 a1 = *(const float4*)(sa + kq * 8 + 4);
        float4 c0 = *(const float4*)(sc_ + kq * 8);
        float4 c1 = *(const float4*)(sc_ + kq * 8 + 4);
        s8v h;
        h[0] = (short)f2bf(fmaxf(fmaf(a0.x, bf2f(v[0]), c0.x), 0.f));
        h[1] = (short)f2bf(fmaxf(fmaf(a0.y, bf2f(v[1]), c0.y), 0.f));
        h[2] = (short)f2bf(fmaxf(fmaf(a0.z, bf2f(v[2]), c0.z), 0.f));
        h[3] = (short)f2bf(fmaxf(fmaf(a0.w, bf2f(v[3]), c0.w), 0.f));
        h[4] = (short)f2bf(fmaxf(fmaf(a1.x, bf2f(v[4]), c1.x), 0.f));
        h[5] = (short)f2bf(fmaxf(fmaf(a1.y, bf2f(v[5]), c1.y), 0.f));
        h[6] = (short)f2bf(fmaxf(fmaf(a1.z, bf2f(v[6]), c1.z), 0.f));
        h[7] = (short)f2bf(fmaxf(fmaf(a1.w, bf2f(v[7]), c1.w), 0.f));
        *(s8v*)(hOut + (cbase + (long)kq * 64) * 8) = h;
    }
}

// -------- relu(bn(x)) on bf16 src -> row-major bf16, BN finalize fused --------
__global__ __launch_bounds__(256) void bn_rowmajor(const u8v* __restrict__ src,
        const float* __restrict__ stats, const float* __restrict__ g,
        const float* __restrict__ be, u8v* __restrict__ hOut, int n8) {
    __shared__ float sa[HID], sc_[HID];
    int tid = threadIdx.x;
    {
        float mean = stats[tid] * ROWSINV;
        float var = stats[HID + tid] * ROWSINV - mean * mean;
        float av = g[tid] * rsqrtf(var + EPSV);
        sa[tid] = av;
        sc_[tid] = be[tid] - mean * av;
    }
    __syncthreads();
    int i = blockIdx.x * 256 + tid;
    if (i >= n8) return;
    int col = (i << 3) & (HID - 1);
    u8v v = src[i];
    u8v o;
#pragma unroll
    for (int q = 0; q < 8; ++q)
        o[q] = f2bf(fmaxf(fmaf(sa[col + q], bf2f(v[q]), sc_[col + q]), 0.f));
    hOut[i] = o;
}

// ---------------- gathers ----------------
// edge gather d=128 (avg degree 40): 16 buffered loads in flight, 4B/lane, scalar idx
__global__ __launch_bounds__(256) void gather_e128(const int* __restrict__ off,
        const int* __restrict__ idx, const unsigned short* __restrict__ Y,
        unsigned short* __restrict__ outh) {
    int lane = threadIdx.x & 63;
    int r = blockIdx.x * 4 + (threadIdx.x >> 6);
    int f0 = lane * 2;
    int s = off[r], e = off[r + 1];
    float a[8][2] = {};
    int j = s;
    for (; j + 16 <= e; j += 16) {
        u2v g[16];
#pragma unroll
        for (int u = 0; u < 16; ++u) {
            int iv = __builtin_amdgcn_readfirstlane(idx[j + u]);
            g[u] = *(const u2v*)(Y + (long)iv * FT_DIM + f0);
        }
#pragma unroll
        for (int u = 0; u < 16; ++u) {
            a[u & 7][0] += bf2f(g[u][0]);
            a[u & 7][1] += bf2f(g[u][1]);
        }
    }
    for (; j + 8 <= e; j += 8) {
        u2v g[8];
#pragma unroll
        for (int u = 0; u < 8; ++u) {
            int iv = __builtin_amdgcn_readfirstlane(idx[j + u]);
            g[u] = *(const u2v*)(Y + (long)iv * FT_DIM + f0);
        }
#pragma unroll
        for (int u = 0; u < 8; ++u) {
            a[u][0] += bf2f(g[u][0]);
            a[u][1] += bf2f(g[u][1]);
        }
    }
    for (; j < e; ++j) {
        int iv = __builtin_amdgcn_readfirstlane(idx[j]);
        u2v g = *(const u2v*)(Y + (long)iv * FT_DIM + f0);
        a[0][0] += bf2f(g[0]);
        a[0][1] += bf2f(g[1]);
    }
    float s0 = 0.f, s1 = 0.f;
#pragma unroll
    for (int u = 0; u < 8; ++u) { s0 += a[u][0]; s1 += a[u][1]; }
    *(u2v*)(outh + (long)r * FT_DIM + f0) = (u2v){f2bf(s0), f2bf(s1)};
}

// node gather d=128 (avg degree 10): 4 chains, writes blocked single plane
__global__ __launch_bounds__(256) void gather_n128_planes(const int* __restrict__ off,
        const int* __restrict__ idx, const unsigned short* __restrict__ Y,
        unsigned short* __restrict__ Ph) {
    int lane = threadIdx.x & 63;
    int r = blockIdx.x * 4 + (threadIdx.x >> 6);
    int f0 = lane * 2;
    int s = off[r], e = off[r + 1];
    float a[4][2] = {};
    int j = s;
    for (; j + 4 <= e; j += 4) {
#pragma unroll
        for (int u = 0; u < 4; ++u) {
            int iv = __builtin_amdgcn_readfirstlane(idx[j + u]);
            u2v g = *(const u2v*)(Y + (long)iv * FT_DIM + f0);
            a[u][0] += bf2f(g[0]);
            a[u][1] += bf2f(g[1]);
        }
    }
    for (; j < e; ++j) {
        int iv = __builtin_amdgcn_readfirstlane(idx[j]);
        u2v g = *(const u2v*)(Y + (long)iv * FT_DIM + f0);
        a[0][0] += bf2f(g[0]);
        a[0][1] += bf2f(g[1]);
    }
    float s0 = a[0][0] + a[1][0] + a[2][0] + a[3][0];
    float s1 = a[0][1] + a[1][1] + a[2][1] + a[3][1];
    *(u2v*)(Ph + ablk(r, f0, FT_DIM)) = (u2v){f2bf(s0), f2bf(s1)};
}

// edge gather d=256: 16B/lane, half-wave = one row; 16 buffered loads (32 edges) per
// main iteration for MLP. Epilogue: z[e] = rowsum . Wh; optionally writes Eb.
template<bool WRITE_EB>
__global__ __launch_bounds__(256) void gather_e256_z(const int* __restrict__ off,
        const int* __restrict__ idx, const unsigned short* __restrict__ Y,
        unsigned short* __restrict__ Eb, const float* __restrict__ Wh,
        float* __restrict__ z) {
    int lane = threadIdx.x & 63;
    int r = blockIdx.x * 4 + (threadIdx.x >> 6);
    int hh = lane >> 5;
    int f0 = (lane & 31) * 8;
    int s = off[r], e = off[r + 1];
    float A[4][8] = {};
    int j = s;
    for (; j + 32 <= e; j += 32) {
        u8v g[16];
#pragma unroll
        for (int u = 0; u < 16; ++u) {
            int i0 = __builtin_amdgcn_readfirstlane(idx[j + 2 * u]);
            int i1 = __builtin_amdgcn_readfirstlane(idx[j + 2 * u + 1]);
            int iv = hh ? i1 : i0;
            g[u] = *(const u8v*)(Y + (long)iv * HID + f0);
        }
#pragma unroll
        for (int u = 0; u < 16; ++u)
#pragma unroll
            for (int v = 0; v < 8; ++v) A[u & 3][v] += bf2f(g[u][v]);
    }
    for (; j + 16 <= e; j += 16) {
        u8v g[8];
#pragma unroll
        for (int u = 0; u < 8; ++u) {
            int i0 = __builtin_amdgcn_readfirstlane(idx[j + 2 * u]);
            int i1 = __builtin_amdgcn_readfirstlane(idx[j + 2 * u + 1]);
            int iv = hh ? i1 : i0;
            g[u] = *(const u8v*)(Y + (long)iv * HID + f0);
        }
#pragma unroll
        for (int u = 0; u < 8; ++u)
#pragma unroll
            for (int v = 0; v < 8; ++v) A[u & 3][v] += bf2f(g[u][v]);
    }
    for (; j < e; j += 2) {
        int has1 = (j + 1 < e);
        int i0 = __builtin_amdgcn_readfirstlane(idx[j]);
        int i1 = __builtin_amdgcn_readfirstlane(idx[has1 ? j + 1 : j]);
        int iv = hh ? i1 : i0;
        u8v g = *(const u8v*)(Y + (long)iv * HID + f0);
        if (!hh || has1) {
#pragma unroll
            for (int v = 0; v < 8; ++v) A[0][v] += bf2f(g[v]);
        }
    }
    float sum[8];
#pragma unroll
    for (int v = 0; v < 8; ++v) {
        sum[v] = A[0][v] + A[1][v] + A[2][v] + A[3][v];
        sum[v] += __shfl_xor(sum[v], 32, 64);
    }
    if (WRITE_EB && hh == 0) {
        u8v o;
#pragma unroll
        for (int v = 0; v < 8; ++v) o[v] = f2bf(sum[v]);
        *(u8v*)(Eb + (long)r * HID + f0) = o;
    }
    const float* wp = Wh + (long)f0 * NCLS;
    float p[NCLS];
#pragma unroll
    for (int c = 0; c < NCLS; ++c) {
        float acc = 0.f;
#pragma unroll
        for (int v = 0; v < 8; ++v) acc += sum[v] * wp[v * NCLS + c];
        p[c] = acc;
    }
#pragma unroll
    for (int c = 0; c < NCLS; ++c) {
#pragma unroll
        for (int m = 1; m < 32; m <<= 1) p[c] += __shfl_xor(p[c], m, 64);
    }
    if (lane == 0) {
        float* zp = z + (long)r * 16;
        *(float4*)(zp)      = (float4){p[0], p[1], p[2], p[3]};
        *(float4*)(zp + 4)  = (float4){p[4], p[5], p[6], p[7]};
        *(float4*)(zp + 8)  = (float4){p[8], p[9], 0.f, 0.f};
        *(float4*)(zp + 12) = (float4){0.f, 0.f, 0.f, 0.f};
    }
}

// node gather d=256 (avg degree 10): 16B/lane half-pair, writes blocked single plane
__global__ __launch_bounds__(256) void gather_n256_planes(const int* __restrict__ off,
        const int* __restrict__ idx, const unsigned short* __restrict__ Y,
        unsigned short* __restrict__ Ph) {
    int lane = threadIdx.x & 63;
    int r = blockIdx.x * 4 + (threadIdx.x >> 6);
    int hh = lane >> 5;
    int f0 = (lane & 31) * 8;
    int s = off[r], e = off[r + 1];
    float A[2][8] = {};
    int j = s;
    for (; j + 8 <= e; j += 8) {
        u8v g[4];
#pragma unroll
        for (int u = 0; u < 4; ++u) {
            int i0 = __builtin_amdgcn_readfirstlane(idx[j + 2 * u]);
            int i1 = __builtin_amdgcn_readfirstlane(idx[j + 2 * u + 1]);
            int iv = hh ? i1 : i0;
            g[u] = *(const u8v*)(Y + (long)iv * HID + f0);
        }
#pragma unroll
        for (int u = 0; u < 4; ++u)
#pragma unroll
            for (int v = 0; v < 8; ++v) A[u & 1][v] += bf2f(g[u][v]);
    }
    for (; j < e; j += 2) {
        int has1 = (j + 1 < e);
        int i0 = __builtin_amdgcn_readfirstlane(idx[j]);
        int i1 = __builtin_amdgcn_readfirstlane(idx[has1 ? j + 1 : j]);
        int iv = hh ? i1 : i0;
        u8v g = *(const u8v*)(Y + (long)iv * HID + f0);
        if (!hh || has1) {
#pragma unroll
            for (int v = 0; v < 8; ++v) A[0][v] += bf2f(g[v]);
        }
    }
    s8v o;
#pragma unroll
    for (int v = 0; v < 8; ++v) {
        float sum = A[0][v] + A[1][v];
        sum += __shfl_xor(sum, 32, 64);
        o[v] = (short)f2bf(sum);
    }
    if (hh == 0) *(s8v*)(Ph + ablk(r, f0, HID)) = o;
}

// node readout over z rows (64B each): 4 threads per node, float4 per thread.
template<bool FIRST>
__global__ __launch_bounds__(256) void gather_z(const int* __restrict__ off,
        const int* __restrict__ idx, const float* __restrict__ z,
        const float* __restrict__ dinv, const float* __restrict__ hb,
        float* __restrict__ on) {
    int tid = threadIdx.x;
    int t = tid & 3;
    int n = blockIdx.x * 64 + (tid >> 2);
    int s = off[n], e = off[n + 1];
    float4 a0 = {0,0,0,0}, a1 = {0,0,0,0}, a2 = {0,0,0,0}, a3 = {0,0,0,0};
    int j = s;
    for (; j + 4 <= e; j += 4) {
        float4 g0 = *(const float4*)(z + (long)idx[j] * 16 + t * 4);
        float4 g1 = *(const float4*)(z + (long)idx[j + 1] * 16 + t * 4);
        float4 g2 = *(const float4*)(z + (long)idx[j + 2] * 16 + t * 4);
        float4 g3 = *(const float4*)(z + (long)idx[j + 3] * 16 + t * 4);
        a0.x += g0.x; a0.y += g0.y; a0.z += g0.z; a0.w += g0.w;
        a1.x += g1.x; a1.y += g1.y; a1.z += g1.z; a1.w += g1.w;
        a2.x += g2.x; a2.y += g2.y; a2.z += g2.z; a2.w += g2.w;
        a3.x += g3.x; a3.y += g3.y; a3.z += g3.z; a3.w += g3.w;
    }
    for (; j < e; ++j) {
        float4 g0 = *(const float4*)(z + (long)idx[j] * 16 + t * 4);
        a0.x += g0.x; a0.y += g0.y; a0.z += g0.z; a0.w += g0.w;
    }
    float di = dinv[n];
    float4 acc;
    acc.x = (a0.x + a1.x + a2.x + a3.x) * di;
    acc.y = (a0.y + a1.y + a2.y + a3.y) * di;
    acc.z = (a0.z + a1.z + a2.z + a3.z) * di;
    acc.w = (a0.w + a1.w + a2.w + a3.w) * di;
    float* op = on + (long)n * 16 + t * 4;
    if (FIRST) {
        float4 b;
#pragma unroll
        for (int k = 0; k < 4; ++k) {
            int c = t * 4 + k;
            ((float*)&b)[k] = (c < NCLS) ? hb[c] : 0.f;
        }
        *(float4*)op = (float4){acc.x + b.x, acc.y + b.y, acc.z + b.z, acc.w + b.w};
    } else {
        float4 old = *(float4*)op;
        *(float4*)op = (float4){old.x + acc.x, old.y + acc.y, old.z + acc.z, old.w + acc.w};
    }
}

// ---------------- single-A-plane MFMA GEMM, 128x128 tile, bf16 output ----------------
// Output Tb is bf16 (rounded); column stats accumulate the ROUNDED values so the
// following BN normalizes exactly the data it sees.
template<int K>
__global__ __launch_bounds__(256) void gemm128(const unsigned short* __restrict__ Ahg,
        const unsigned short* __restrict__ Bhg, const unsigned short* __restrict__ Blg,
        const float* __restrict__ bias, unsigned short* __restrict__ C,
        float* __restrict__ stats) {
    constexpr int KQ = K >> 3;
    __shared__ __align__(16) unsigned short Asl[16 * 512];   // 16 KB
    __shared__ __align__(16) unsigned short Bsl[32 * 512];   // 32 KB
    float* lsum = (float*)Asl;
    float* lsq  = lsum + 128;
    int tid = threadIdx.x;
    int lane = tid & 63, w = tid >> 6;
    int bx = blockIdx.x;
    int col0 = blockIdx.y * 128;
    int colblk0 = blockIdx.y * 2;
    int lm = lane & 15, lq = lane >> 4;
    int rbw = w >> 1;
    int rw = (w & 1) * 32;
    f4v acc[2][8];
#pragma unroll
    for (int i = 0; i < 2; ++i)
#pragma unroll
        for (int j = 0; j < 8; ++j) acc[i][j] = (f4v){0.f, 0.f, 0.f, 0.f};

    for (int ks = 0; ks < K / 64; ++ks) {
        int kq0 = ks * 8;
#pragma unroll
        for (int t = 0; t < 4; ++t) {
            int a = w * 4 + t;
            int rb = a >> 3, kqo = a & 7;
            const unsigned short* g = Ahg
                + ((long)((bx * 2 + rb) * KQ + kq0 + kqo) * 64 + lane) * 8;
            __builtin_amdgcn_global_load_lds(
                (const __attribute__((address_space(1))) void*)g,
                (__attribute__((address_space(3))) void*)(Asl + a * 512), 16, 0, 0);
        }
#pragma unroll
        for (int u = 0; u < 8; ++u) {
            int b = w * 8 + u;
            const unsigned short* g = ((b >> 4) ? Blg : Bhg)
                + ((long)((colblk0 + ((b >> 3) & 1)) * KQ + kq0 + (b & 7)) * 64 + lane) * 8;
            __builtin_amdgcn_global_load_lds(
                (const __attribute__((address_space(1))) void*)g,
                (__attribute__((address_space(3))) void*)(Bsl + b * 512), 16, 0, 0);
        }
        __syncthreads();
#pragma unroll
        for (int kk = 0; kk < 2; ++kk) {
            s8v ah[2];
#pragma unroll
            for (int i = 0; i < 2; ++i)
                ah[i] = *(const s8v*)&Asl[(rbw * 8 + kk * 4 + lq) * 512
                                          + (rw + i * 16 + lm) * 8];
#pragma unroll
            for (int j = 0; j < 8; ++j) {
                int cb = j >> 2;
                int c64 = (j & 3) * 16 + lm;
                s8v bh = *(const s8v*)&Bsl[(cb * 8 + kk * 4 + lq) * 512 + c64 * 8];
                s8v bl = *(const s8v*)&Bsl[(16 + cb * 8 + kk * 4 + lq) * 512 + c64 * 8];
#pragma unroll
                for (int i = 0; i < 2; ++i) {
                    acc[i][j] = __builtin_amdgcn_mfma_f32_16x16x32_bf16(ah[i], bl, acc[i][j], 0, 0, 0);
                    acc[i][j] = __builtin_amdgcn_mfma_f32_16x16x32_bf16(ah[i], bh, acc[i][j], 0, 0, 0);
                }
            }
        }
        __syncthreads();
    }
    if (tid < 128) { lsum[tid] = 0.f; lsq[tid] = 0.f; }
    __syncthreads();
#pragma unroll
    for (int j = 0; j < 8; ++j) {
        int lc = j * 16 + lm;
        int col = col0 + lc;
        float bsv = bias[col];
        float s = 0.f, sq = 0.f;
#pragma unroll
        for (int i = 0; i < 2; ++i) {
#pragma unroll
            for (int reg = 0; reg < 4; ++reg) {
                long row = (long)bx * 128 + rbw * 64 + rw + i * 16 + lq * 4 + reg;
                if (row < N_NODES) {
                    unsigned short hv = f2bf(acc[i][j][reg] + bsv);
                    float vr = bf2f(hv);
                    C[row * HID + col] = hv;
                    s += vr;
                    sq += vr * vr;
                }
            }
        }
        atomicAdd(&lsum[lc], s);
        atomicAdd(&lsq[lc], sq);
    }
    __syncthreads();
    if (tid < 128) {
        atomicAdd(&stats[col0 + tid], lsum[tid]);
        atomicAdd(&stats[HID + col0 + tid], lsq[tid]);
    }
}

// ---------------- readout (onodes stride 16) ----------------
__global__ __launch_bounds__(256) void readout_accum(const float* __restrict__ on,
                                                     const int* __restrict__ ab,
                                                     float* __restrict__ racc,
                                                     float* __restrict__ rcnt) {
    __shared__ float lacc[NG * NCLS];
    __shared__ float lcnt[NG];
    int tid = threadIdx.x;
    for (int i = tid; i < NG * NCLS; i += 256) lacc[i] = 0.f;
    if (tid < NG) lcnt[tid] = 0.f;
    __syncthreads();
    int n = blockIdx.x * 256 + tid;
    if (n < N_NODES) {
        int b = ab[n];
        atomicAdd(&lcnt[b], 1.0f);
        for (int c = 0; c < NCLS; ++c) atomicAdd(&lacc[b * NCLS + c], on[(long)n * 16 + c]);
    }
    __syncthreads();
    if (tid < NG && lcnt[tid] > 0.f) {
        atomicAdd(&rcnt[tid], lcnt[tid]);
        for (int c = 0; c < NCLS; ++c) atomicAdd(&racc[tid * NCLS + c], lacc[tid * NCLS + c]);
    }
}

__global__ void readout_final(const float* __restrict__ racc, const float* __restrict__ rcnt,
                              float* __restrict__ out) {
    int i = blockIdx.x * 256 + threadIdx.x;
    if (i < NG * NCLS) out[i] = racc[i] / fmaxf(rcnt[i / NCLS], 1.0f);
}

// ---------------- launch ----------------
extern "C" void kernel_launch(void* const* d_in, const int* in_sizes, int n_in,
                              void* d_out, int out_size, void* d_ws, size_t ws_size,
                              hipStream_t stream) {
    const float* X         = (const float*)d_in[0];
    const int*   node_idx  = (const int*)d_in[1];
    const int*   edge_idx  = (const int*)d_in[2];
    const int*   all_batch = (const int*)d_in[3];
    const float* W1[2]  = {(const float*)d_in[4],  (const float*)d_in[12]};
    const float* b1[2]  = {(const float*)d_in[5],  (const float*)d_in[13]};
    const float* g1[2]  = {(const float*)d_in[6],  (const float*)d_in[14]};
    const float* be1[2] = {(const float*)d_in[7],  (const float*)d_in[15]};
    const float* W2[2]  = {(const float*)d_in[8],  (const float*)d_in[16]};
    const float* b2[2]  = {(const float*)d_in[9],  (const float*)d_in[17]};
    const float* bng[2] = {(const float*)d_in[10], (const float*)d_in[18]};
    const float* bnb[2] = {(const float*)d_in[11], (const float*)d_in[19]};
    const float* headW  = (const float*)d_in[20];
    const float* headb  = (const float*)d_in[21];
    float* out = (float*)d_out;

    char* base = (char*)d_ws;
    size_t off = 0;
    auto alloc = [&](size_t bytes) -> void* {
        size_t o = (off + 255) & ~(size_t)255;
        off = o + bytes;
        return (void*)(base + o);
    };

    const int ZINTS = M_EDGES + N_NODES;
    const int ZTOT  = ZINTS + 4 * 2 * HID + NG * NCLS + NG;
    int* ibase  = (int*)alloc((size_t)ZTOT * 4);
    int* cnt_e  = ibase;
    int* cnt_n  = cnt_e + M_EDGES;
    float* statsall = (float*)(ibase + ZINTS);
    float* racc     = statsall + 4 * 2 * HID;
    float* rcnt     = racc + NG * NCLS;

    int* off_e  = (int*)alloc((M_EDGES + 1) * 4);
    int* off_n  = (int*)alloc((N_NODES + 1) * 4);
    int* gcur_e = (int*)alloc(NBE * 4);
    int* gcur_n = (int*)alloc(NBN * 4);
    int* idx_e  = (int*)alloc((size_t)NNZ_CNT * 4);
    int* idx_n  = (int*)alloc((size_t)NNZ_CNT * 4);
    unsigned* stg_e = (unsigned*)alloc((size_t)NNZ_CNT * 4);
    unsigned* stg_n = (unsigned*)alloc((size_t)NNZ_CNT * 4);
    float* dinv = (float*)alloc((size_t)N_NODES * 4);

    unsigned short* Xb = (unsigned short*)alloc((size_t)N_NODES * FT_DIM * 2);
    unsigned short* Eb = (unsigned short*)alloc((size_t)M_EDGES * HID * 2);
    unsigned short* Ph = (unsigned short*)alloc((size_t)M_PAD * HID * 2);
    unsigned short* Ahp = (unsigned short*)alloc((size_t)M_PAD * HID * 2);
    unsigned short* Hb  = (unsigned short*)alloc((size_t)N_NODES * HID * 2);
    unsigned short* Tb  = (unsigned short*)alloc((size_t)N_NODES * HID * 2);
    float* onodes = (float*)alloc((size_t)N_NODES * 16 * 4);
    float* zbuf   = (float*)alloc((size_t)M_EDGES * 16 * 4);
    unsigned short* Wp[4][2];
    int WK[4] = {FT_DIM, HID, HID, HID};
    for (int m = 0; m < 4; ++m) {
        Wp[m][0] = (unsigned short*)alloc((size_t)WK[m] * HID * 2);
        Wp[m][1] = (unsigned short*)alloc((size_t)WK[m] * HID * 2);
    }

    const int nnz_blocks = (NNZ_CNT + 255) / 256;
    const int n8 = N_NODES * HID / 8;
    const dim3 ggrid(M_PAD / 128, 2);

    // --- CSR build (bucketed counting sort) + degree norm + weight prep ---
    fzero<<<(ZTOT + 255) / 256, 256, 0, stream>>>((float*)ibase, ZTOT);
    count_kernel<<<nnz_blocks, 256, 0, stream>>>(node_idx, edge_idx, cnt_e, cnt_n);
    exscan2<<<2, 1024, 0, stream>>>(cnt_e, off_e, cnt_n, off_n, gcur_e, gcur_n);
    partition_kernel<<<(NNZ_CNT + 8191) / 8192, 256, 0, stream>>>(node_idx, edge_idx,
                                                                  gcur_e, gcur_n, stg_e, stg_n);
    bucket_fill<<<NBE + NBN, 256, 0, stream>>>(off_e, off_n, stg_e, stg_n, idx_e, idx_n);
    dinv_kernel<<<(N_NODES + 255) / 256, 256, 0, stream>>>(off_n, idx_n, cnt_e, dinv);
    WPA wpa;
    wpa.W[0] = W1[0]; wpa.W[1] = W2[0]; wpa.W[2] = W1[1]; wpa.W[3] = W2[1];
    for (int m = 0; m < 4; ++m) { wpa.h[m] = Wp[m][0]; wpa.l[m] = Wp[m][1]; }
    wprep_all<<<dim3(256, 4), 256, 0, stream>>>(wpa);
    fsplit<<<(N_NODES * FT_DIM / 4 + 255) / 256, 256, 0, stream>>>((const float4*)X,
                                                                   (u4v*)Xb, N_NODES * FT_DIM / 4);

    // ---------------- layer 0 ----------------
    gather_e128<<<M_EDGES / 4, 256, 0, stream>>>(off_e, idx_e, Xb, Eb);
    gather_n128_planes<<<N_NODES / 4, 256, 0, stream>>>(off_n, idx_n, Eb, Ph);
    gemm128<FT_DIM><<<ggrid, 256, 0, stream>>>(Ph, Wp[0][0], Wp[0][1], b1[0], Tb,
                                               statsall + 0 * 512);
    bn_split_blk<<<N_NODES / 64, 256, 0, stream>>>(Tb, statsall + 0 * 512, g1[0], be1[0], Ahp);
    gemm128<HID><<<ggrid, 256, 0, stream>>>(Ahp, Wp[1][0], Wp[1][1], b2[0], Tb,
                                            statsall + 1 * 512);
    bn_rowmajor<<<(n8 + 255) / 256, 256, 0, stream>>>((const u8v*)Tb, statsall + 1 * 512,
                                                      bng[0], bnb[0], (u8v*)Hb, n8);
    // shared edge pass: Eb (layer-1 pooling) + z (layer-0 readout head)
    gather_e256_z<true><<<M_EDGES / 4, 256, 0, stream>>>(off_e, idx_e, Hb, Eb, headW, zbuf);
    gather_z<true><<<N_NODES / 64, 256, 0, stream>>>(off_n, idx_n, zbuf, dinv, headb, onodes);
    gather_n256_planes<<<N_NODES / 4, 256, 0, stream>>>(off_n, idx_n, Eb, Ph);

    // ---------------- layer 1 ----------------
    gemm128<HID><<<ggrid, 256, 0, stream>>>(Ph, Wp[2][0], Wp[2][1], b1[1], Tb,
                                            statsall + 2 * 512);
    bn_split_blk<<<N_NODES / 64, 256, 0, stream>>>(Tb, statsall + 2 * 512, g1[1], be1[1], Ahp);
    gemm128<HID><<<ggrid, 256, 0, stream>>>(Ahp, Wp[3][0], Wp[3][1], b2[1], Tb,
                                            statsall + 3 * 512);
    bn_rowmajor<<<(n8 + 255) / 256, 256, 0, stream>>>((const u8v*)Tb, statsall + 3 * 512,
                                                      bng[1], bnb[1], (u8v*)Hb, n8);
    gather_e256_z<false><<<M_EDGES / 4, 256, 0, stream>>>(off_e, idx_e, Hb, nullptr,
                                                          headW + (size_t)HID * NCLS, zbuf);
    gather_z<false><<<N_NODES / 64, 256, 0, stream>>>(off_n, idx_n, zbuf, dinv, nullptr, onodes);

    // ---------------- readout ----------------
    readout_accum<<<(N_NODES + 255) / 256, 256, 0, stream>>>(onodes, all_batch, racc, rcnt);
    readout_final<<<(NG * NCLS + 255) / 256, 256, 0, stream>>>(racc, rcnt, out);
}